// Round 1
// baseline (9796.700 us; speedup 1.0000x reference)
//
#include <hip/hip_runtime.h>
#include <hip/hip_bf16.h>
#include <math.h>

#define Bn 4
#define Tn 1024
#define Dn 512
#define Hn 8
#define BHn 32
#define LDP 65   // padded LDS leading dim: 65 mod 32 = 1 -> <=2-way conflicts everywhere

// Newton-Schulz coefficients (6 iterations)
__constant__ float NS_Ac[6] = {3955.0f/1024.0f, 3735.0f/1024.0f, 3799.0f/1024.0f,
                               4019.0f/1024.0f, 2677.0f/1024.0f, 2172.0f/1024.0f};
__constant__ float NS_Bc[6] = {-8306.0f/1024.0f, -6681.0f/1024.0f, -6499.0f/1024.0f,
                               -6385.0f/1024.0f, -3029.0f/1024.0f, -1833.0f/1024.0f};
__constant__ float NS_Cc[6] = {5008.0f/1024.0f, 3463.0f/1024.0f, 3211.0f/1024.0f,
                               2906.0f/1024.0f, 1162.0f/1024.0f,  682.0f/1024.0f};

// ---------- helpers ----------

// Stage a 64x64 fp32 tile (src row stride = srcStride floats) into padded LDS [64][LDP].
__device__ __forceinline__ void stage_tile(float* __restrict__ dst, const float* __restrict__ src,
                                           int srcStride, int tid) {
#pragma unroll
  for (int i = 0; i < 4; ++i) {
    const int idx = tid + (i << 8);
    const int row = idx >> 4;
    const int c4  = (idx & 15) << 2;
    const float4 v = *reinterpret_cast<const float4*>(src + (size_t)row * srcStride + c4);
    float* p = dst + row * LDP + c4;
    p[0] = v.x; p[1] = v.y; p[2] = v.z; p[3] = v.w;
  }
}

// acc += A * B^T over 64 inner dim: acc[r][c] += sum_k a[i0+r][k] * b[j0+c][k]
__device__ __forceinline__ void mm_nt_acc(float (&acc)[4][4], const float* __restrict__ a,
                                          const float* __restrict__ b, int i0, int j0) {
#pragma unroll 4
  for (int k = 0; k < 64; ++k) {
    float av[4], bv[4];
#pragma unroll
    for (int r = 0; r < 4; ++r) av[r] = a[(i0 + r) * LDP + k];
#pragma unroll
    for (int c = 0; c < 4; ++c) bv[c] = b[(j0 + c) * LDP + k];
#pragma unroll
    for (int r = 0; r < 4; ++r)
#pragma unroll
      for (int c = 0; c < 4; ++c) acc[r][c] = fmaf(av[r], bv[c], acc[r][c]);
  }
}

// acc += A * B over 64 inner dim: acc[r][c] += sum_k a[i0+r][k] * b[k][j0+c]
__device__ __forceinline__ void mm_nn_acc(float (&acc)[4][4], const float* __restrict__ a,
                                          const float* __restrict__ b, int i0, int j0) {
#pragma unroll 4
  for (int k = 0; k < 64; ++k) {
    float av[4], bv[4];
#pragma unroll
    for (int r = 0; r < 4; ++r) av[r] = a[(i0 + r) * LDP + k];
#pragma unroll
    for (int c = 0; c < 4; ++c) bv[c] = b[k * LDP + j0 + c];
#pragma unroll
    for (int r = 0; r < 4; ++r)
#pragma unroll
      for (int c = 0; c < 4; ++c) acc[r][c] = fmaf(av[r], bv[c], acc[r][c]);
  }
}

// ---------- kernels ----------

// q/k/v/w projections: (4096 x 512) @ W^T, written as (b,h,t,e)
__global__ __launch_bounds__(256) void proj4_kernel(
    const float* __restrict__ x,
    const float* __restrict__ W0, const float* __restrict__ W1,
    const float* __restrict__ W2, const float* __restrict__ W3,
    float* __restrict__ o0, float* __restrict__ o1,
    float* __restrict__ o2, float* __restrict__ o3) {
  __shared__ float Xs[64 * LDP];
  __shared__ float Wsh[64 * LDP];
  const float* W; float* outp;
  switch (blockIdx.z) {
    case 0:  W = W0; outp = o0; break;
    case 1:  W = W1; outp = o1; break;
    case 2:  W = W2; outp = o2; break;
    default: W = W3; outp = o3; break;
  }
  const int tid = threadIdx.x;
  const int m0 = blockIdx.x * 64;
  const int n0 = blockIdx.y * 64;
  const int ty = tid >> 4, tx = tid & 15;
  const int i0 = ty * 4, j0 = tx * 4;
  float acc[4][4] = {};
  for (int kt = 0; kt < Dn; kt += 64) {
    stage_tile(Xs, x + (size_t)m0 * Dn + kt, Dn, tid);
    stage_tile(Wsh, W + (size_t)n0 * Dn + kt, Dn, tid);
    __syncthreads();
    mm_nt_acc(acc, Xs, Wsh, i0, j0);
    __syncthreads();
  }
#pragma unroll
  for (int r = 0; r < 4; ++r)
#pragma unroll
    for (int c = 0; c < 4; ++c) {
      const int m = m0 + i0 + r, n = n0 + j0 + c;
      const int b = m >> 10, t = m & 1023, h = n >> 6, e = n & 63;
      outp[(((size_t)(b * Hn + h)) * Tn + t) * 64 + e] = acc[r][c];
    }
}

// eta/theta projection: sigmoid(x @ Wp^T), Wp is (16,512)
#define XSTR 516
__global__ __launch_bounds__(256) void wp_kernel(const float* __restrict__ x,
                                                 const float* __restrict__ Wp,
                                                 float* __restrict__ eta,
                                                 float* __restrict__ theta) {
  __shared__ float xs[16 * XSTR];
  __shared__ float wps[16 * XSTR];
  const int tid = threadIdx.x;
  const int r0 = blockIdx.x * 16;
#pragma unroll
  for (int i = 0; i < 8; ++i) {
    const int idx = tid + (i << 8);       // 0..2047
    const int r = idx >> 7, c4 = (idx & 127) << 2;
    const float4 v = *reinterpret_cast<const float4*>(x + (size_t)(r0 + r) * Dn + c4);
    float* p = xs + r * XSTR + c4;
    p[0] = v.x; p[1] = v.y; p[2] = v.z; p[3] = v.w;
    const float4 wv = *reinterpret_cast<const float4*>(Wp + (size_t)r * Dn + c4);
    float* pw = wps + r * XSTR + c4;
    pw[0] = wv.x; pw[1] = wv.y; pw[2] = wv.z; pw[3] = wv.w;
  }
  __syncthreads();
  const int row = tid >> 4, col = tid & 15;
  float acc = 0.f;
#pragma unroll 8
  for (int k = 0; k < Dn; ++k) acc = fmaf(xs[row * XSTR + k], wps[col * XSTR + k], acc);
  const float sg = 1.f / (1.f + __expf(-acc));
  const int m = r0 + row, b = m >> 10, t = m & 1023, h = col >> 1;
  float* dst = (col & 1) ? theta : eta;
  dst[((size_t)(b * Hn + h)) * Tn + t] = sg;
}

// Per-row softmax stats (max, sum of exp) over s < t, flash-style.
__global__ __launch_bounds__(256) void rowstats_kernel(
    const float* __restrict__ wb, const float* __restrict__ kb,
    float* __restrict__ rowm, float* __restrict__ rowl) {
  __shared__ float Wt[64 * LDP];
  __shared__ float Ks[64 * LDP];
  __shared__ float Sc[64 * LDP];
  __shared__ float rm[64];
  __shared__ float rl[64];
  const int tb = blockIdx.x, bh = blockIdx.y;
  const int t0 = tb * 64;
  const int tid = threadIdx.x;
  const int ty = tid >> 4, tx = tid & 15, i0 = ty * 4, j0 = tx * 4;
  stage_tile(Wt, wb + ((size_t)bh * Tn + t0) * 64, 64, tid);
  if (tid < 64) { rm[tid] = -INFINITY; rl[tid] = 0.f; }
  __syncthreads();
  for (int sb = 0; sb <= tb; ++sb) {
    stage_tile(Ks, kb + ((size_t)bh * Tn + sb * 64) * 64, 64, tid);
    __syncthreads();
    float acc[4][4] = {};
    mm_nt_acc(acc, Wt, Ks, i0, j0);
#pragma unroll
    for (int r = 0; r < 4; ++r)
#pragma unroll
      for (int c = 0; c < 4; ++c) {
        const int rr = i0 + r, cc = j0 + c;
        const bool valid = (sb < tb) || (cc < rr);
        Sc[rr * LDP + cc] = valid ? acc[r][c] * 0.125f : -INFINITY;
      }
    __syncthreads();
    if (tid < 64) {
      const int r = tid;
      float tm = -INFINITY;
      for (int c = 0; c < 64; ++c) tm = fmaxf(tm, Sc[r * LDP + c]);
      if (tm > -3.0e38f) {
        const float mnew = fmaxf(rm[r], tm);
        float s = 0.f;
        for (int c = 0; c < 64; ++c) s += __expf(Sc[r * LDP + c] - mnew);
        rl[r] = rl[r] * __expf(rm[r] - mnew) + s;
        rm[r] = mnew;
      }
    }
    __syncthreads();
  }
  if (tid < 64) {
    rowm[(size_t)bh * Tn + t0 + tid] = rm[tid];
    const float l = rl[tid];
    rowl[(size_t)bh * Tn + t0 + tid] = (l == 0.f) ? 1.f : l;
  }
}

// Blocked forward substitution: (I + A) U = V, A recomputed from scores on the fly.
__global__ __launch_bounds__(256) void solve_kernel(
    const float* __restrict__ wb, const float* __restrict__ kb,
    const float* __restrict__ vb, const float* __restrict__ rowm,
    const float* __restrict__ rowl, float* __restrict__ Ub) {
  extern __shared__ float smem[];
  float* Uacc = smem;                 // 64*LDP
  float* Us   = Uacc + 64 * LDP;
  float* Ks   = Us   + 64 * LDP;
  float* Wt   = Ks   + 64 * LDP;
  float* Sc   = Wt   + 64 * LDP;
  float* rm   = Sc   + 64 * LDP;      // 64
  float* rl   = rm + 64;              // 64
  const int bh = blockIdx.x;
  const int tid = threadIdx.x;
  const int ty = tid >> 4, tx = tid & 15, i0 = ty * 4, j0 = tx * 4;
  for (int ib = 0; ib < 16; ++ib) {
    const int t0 = ib * 64;
    stage_tile(Uacc, vb + ((size_t)bh * Tn + t0) * 64, 64, tid);
    stage_tile(Wt,  wb + ((size_t)bh * Tn + t0) * 64, 64, tid);
    if (tid < 64) {
      rm[tid] = rowm[(size_t)bh * Tn + t0 + tid];
      rl[tid] = rowl[(size_t)bh * Tn + t0 + tid];
    }
    __syncthreads();
    for (int jb = 0; jb < ib; ++jb) {
      stage_tile(Ks, kb + ((size_t)bh * Tn + jb * 64) * 64, 64, tid);
      stage_tile(Us, Ub + ((size_t)bh * Tn + jb * 64) * 64, 64, tid);
      __syncthreads();
      float acc[4][4] = {};
      mm_nt_acc(acc, Wt, Ks, i0, j0);
#pragma unroll
      for (int r = 0; r < 4; ++r)
#pragma unroll
        for (int c = 0; c < 4; ++c) {
          const int rr = i0 + r;
          Sc[rr * LDP + j0 + c] = __expf(acc[r][c] * 0.125f - rm[rr]) / rl[rr];
        }
      __syncthreads();
      float acc2[4][4] = {};
      mm_nn_acc(acc2, Sc, Us, i0, j0);
#pragma unroll
      for (int r = 0; r < 4; ++r)
#pragma unroll
        for (int c = 0; c < 4; ++c) Uacc[(i0 + r) * LDP + j0 + c] -= acc2[r][c];
      __syncthreads();
    }
    // within-block strict-lower scores
    stage_tile(Ks, kb + ((size_t)bh * Tn + t0) * 64, 64, tid);
    __syncthreads();
    float acc[4][4] = {};
    mm_nt_acc(acc, Wt, Ks, i0, j0);
#pragma unroll
    for (int r = 0; r < 4; ++r)
#pragma unroll
      for (int c = 0; c < 4; ++c) {
        const int rr = i0 + r, cc = j0 + c;
        Sc[rr * LDP + cc] = (cc < rr) ? __expf(acc[r][c] * 0.125f - rm[rr]) / rl[rr] : 0.f;
      }
    __syncthreads();
    // sequential within-block solve: each lane owns one dv column (no cross-lane deps)
    if (tid < 64) {
      const int dv = tid;
      for (int r = 1; r < 64; ++r) {
        float s = 0.f;
        for (int c = 0; c < r; ++c) s = fmaf(Sc[r * LDP + c], Uacc[c * LDP + dv], s);
        Uacc[r * LDP + dv] -= s;
      }
    }
    __syncthreads();
#pragma unroll
    for (int i = 0; i < 16; ++i) {
      const int idx = tid + (i << 8);
      const int row = idx >> 6, col = idx & 63;
      Ub[((size_t)bh * Tn + t0 + row) * 64 + col] = Uacc[row * LDP + col];
    }
    __threadfence_block();
    __syncthreads();
  }
}

// Momentum scan over a time chunk: thread = one (bh, element), sequential over chunk.
__global__ __launch_bounds__(256) void mscan_kernel(
    const float* __restrict__ Ub, const float* __restrict__ kb,
    const float* __restrict__ theta, float* __restrict__ Mcarry,
    float* __restrict__ Mbuf, int t0, int Tc) {
  const int gid = blockIdx.x * 256 + threadIdx.x;     // BHn*4096 threads
  const int bh = gid >> 12, e = gid & 4095, dv = e >> 6, dk = e & 63;
  float M = Mcarry[gid];
  const float* Urow = Ub + (size_t)bh * Tn * 64;
  const float* krow = kb + (size_t)bh * Tn * 64;
  const float* th   = theta + (size_t)bh * Tn;
  for (int tl = 0; tl < Tc; ++tl) {
    const int t = t0 + tl;
    const float thv = th[t];
    const float g = Urow[(size_t)t * 64 + dv] * krow[(size_t)t * 64 + dk];
    M = thv * M + (1.f - thv) * g;
    Mbuf[((size_t)bh * Tc + tl) * 4096 + e] = M;
  }
  Mcarry[gid] = M;
}

// In-place Newton-Schulz (6 iters) on one 64x64 matrix per workgroup.
__global__ __launch_bounds__(256) void ns_kernel(float* __restrict__ Mbuf) {
  __shared__ float X[64 * LDP];
  __shared__ float A[64 * LDP];
  __shared__ float Bm[64 * LDP];
  __shared__ float red[4];
  float* src = Mbuf + (size_t)blockIdx.x * 4096;
  const int tid = threadIdx.x;
  float ss = 0.f;
#pragma unroll
  for (int i = 0; i < 16; ++i) {
    const int idx = tid + (i << 8);
    const float v = src[idx];
    X[(idx >> 6) * LDP + (idx & 63)] = v;
    ss += v * v;
  }
#pragma unroll
  for (int off = 32; off > 0; off >>= 1) ss += __shfl_down(ss, off, 64);
  if ((tid & 63) == 0) red[tid >> 6] = ss;
  __syncthreads();
  const float inv = 1.f / (sqrtf(red[0] + red[1] + red[2] + red[3]) + 1e-7f);
#pragma unroll
  for (int i = 0; i < 16; ++i) {
    const int idx = tid + (i << 8);
    X[(idx >> 6) * LDP + (idx & 63)] *= inv;
  }
  __syncthreads();
  const int ty = tid >> 4, tx = tid & 15, i0 = ty * 4, j0 = tx * 4;
#pragma unroll 1
  for (int it = 0; it < 6; ++it) {
    const float ca = NS_Ac[it], cb = NS_Bc[it], cc = NS_Cc[it];
    {
      float acc[4][4] = {};
      mm_nt_acc(acc, X, X, i0, j0);           // A = X X^T
#pragma unroll
      for (int r = 0; r < 4; ++r)
#pragma unroll
        for (int c = 0; c < 4; ++c) A[(i0 + r) * LDP + j0 + c] = acc[r][c];
    }
    __syncthreads();
    {
      float acc[4][4] = {};
      mm_nn_acc(acc, A, A, i0, j0);           // Bm = A @ A
#pragma unroll
      for (int r = 0; r < 4; ++r)
#pragma unroll
        for (int c = 0; c < 4; ++c) Bm[(i0 + r) * LDP + j0 + c] = acc[r][c];
    }
    __syncthreads();
#pragma unroll
    for (int r = 0; r < 4; ++r)               // Bm = b*A + c*Bm
#pragma unroll
      for (int c = 0; c < 4; ++c) {
        const int id = (i0 + r) * LDP + j0 + c;
        Bm[id] = cb * A[id] + cc * Bm[id];
      }
    __syncthreads();
    {
      float acc[4][4] = {};
      mm_nn_acc(acc, Bm, X, i0, j0);          // A = Bm @ X
#pragma unroll
      for (int r = 0; r < 4; ++r)
#pragma unroll
        for (int c = 0; c < 4; ++c) A[(i0 + r) * LDP + j0 + c] = acc[r][c];
    }
    __syncthreads();
#pragma unroll
    for (int r = 0; r < 4; ++r)               // X = a*X + A
#pragma unroll
      for (int c = 0; c < 4; ++c) {
        const int id = (i0 + r) * LDP + j0 + c;
        X[id] = ca * X[id] + A[id];
      }
    __syncthreads();
  }
#pragma unroll
  for (int i = 0; i < 16; ++i) {
    const int idx = tid + (i << 8);
    src[idx] = X[(idx >> 6) * LDP + (idx & 63)];
  }
}

// S prefix-sum over a chunk (in-place: Sp -> S_t), thread = one (bh, element).
__global__ __launch_bounds__(256) void sscan_kernel(
    const float* __restrict__ eta, float* __restrict__ Scarry,
    float* __restrict__ Mbuf, int t0, int Tc) {
  const int gid = blockIdx.x * 256 + threadIdx.x;
  const int bh = gid >> 12, e = gid & 4095;
  float S = Scarry[gid];
  const float* et = eta + (size_t)bh * Tn;
  for (int tl = 0; tl < Tc; ++tl) {
    const size_t idx = ((size_t)bh * Tc + tl) * 4096 + e;
    S += et[t0 + tl] * Mbuf[idx];
    Mbuf[idx] = S;
  }
  Scarry[gid] = S;
}

// o_t = S_t @ q_t per (bh, t)
__global__ __launch_bounds__(256) void outv_kernel(
    const float* __restrict__ Mbuf, const float* __restrict__ qb,
    float* __restrict__ ob, int t0, int Tc) {
  __shared__ float Sl[64 * LDP];
  __shared__ float qv[64];
  __shared__ float red[256];
  const int tl = blockIdx.x, bh = blockIdx.y;
  const int tid = threadIdx.x;
  const float* src = Mbuf + ((size_t)bh * Tc + tl) * 4096;
#pragma unroll
  for (int i = 0; i < 16; ++i) {
    const int idx = tid + (i << 8);
    Sl[(idx >> 6) * LDP + (idx & 63)] = src[idx];
  }
  if (tid < 64) qv[tid] = qb[((size_t)bh * Tn + t0 + tl) * 64 + tid];
  __syncthreads();
  const int dv = tid & 63, part = tid >> 6;
  float acc = 0.f;
#pragma unroll
  for (int k2 = 0; k2 < 16; ++k2) {
    const int kk = part * 16 + k2;
    acc = fmaf(Sl[dv * LDP + kk], qv[kk], acc);
  }
  red[tid] = acc;
  __syncthreads();
  if (tid < 64)
    ob[((size_t)bh * Tn + t0 + tl) * 64 + tid] =
        red[tid] + red[tid + 64] + red[tid + 128] + red[tid + 192];
}

// init carries from S0 / M0 (broadcast over batch)
__global__ __launch_bounds__(256) void init_carry_kernel(
    const float* __restrict__ S0, const float* __restrict__ M0,
    float* __restrict__ Scarry, float* __restrict__ Mcarry) {
  const int gid = blockIdx.x * 256 + threadIdx.x;   // 131072
  const int h = (gid >> 12) & 7, e = gid & 4095;
  Scarry[gid] = S0[h * 4096 + e];
  Mcarry[gid] = M0[h * 4096 + e];
}

// final: out = o_flat @ Wo^T, o_flat[m][kk] gathered from (b,h,t,dv) layout
__global__ __launch_bounds__(256) void out_gemm_kernel(
    const float* __restrict__ ob, const float* __restrict__ Wo,
    float* __restrict__ out) {
  __shared__ float As[64 * LDP];
  __shared__ float Bs[64 * LDP];
  const int tid = threadIdx.x;
  const int m0 = blockIdx.x * 64;
  const int n0 = blockIdx.y * 64;
  const int ty = tid >> 4, tx = tid & 15, i0 = ty * 4, j0 = tx * 4;
  float acc[4][4] = {};
  for (int kt = 0; kt < Dn; kt += 64) {
    const int h = kt >> 6;
#pragma unroll
    for (int i = 0; i < 4; ++i) {
      const int idx = tid + (i << 8);
      const int row = idx >> 4, c4 = (idx & 15) << 2;
      const int m = m0 + row, b = m >> 10, t = m & 1023;
      const float4 v = *reinterpret_cast<const float4*>(
          ob + ((size_t)(b * Hn + h) * Tn + t) * 64 + c4);
      float* p = As + row * LDP + c4;
      p[0] = v.x; p[1] = v.y; p[2] = v.z; p[3] = v.w;
    }
    stage_tile(Bs, Wo + (size_t)n0 * Dn + kt, Dn, tid);
    __syncthreads();
    mm_nt_acc(acc, As, Bs, i0, j0);
    __syncthreads();
  }
#pragma unroll
  for (int r = 0; r < 4; ++r)
#pragma unroll
    for (int c = 0; c < 4; ++c)
      out[(size_t)(m0 + i0 + r) * Dn + n0 + j0 + c] = acc[r][c];
}

// ---------- host ----------

extern "C" void kernel_launch(void* const* d_in, const int* in_sizes, int n_in,
                              void* d_out, int out_size, void* d_ws, size_t ws_size,
                              hipStream_t stream) {
  (void)in_sizes; (void)n_in; (void)out_size;
  const float* x  = (const float*)d_in[0];
  const float* Wq = (const float*)d_in[1];
  const float* Wk = (const float*)d_in[2];
  const float* Wv = (const float*)d_in[3];
  const float* Ww = (const float*)d_in[4];
  const float* Wp = (const float*)d_in[5];
  const float* Wo = (const float*)d_in[6];
  const float* S0 = (const float*)d_in[7];
  const float* M0 = (const float*)d_in[8];
  float* out = (float*)d_out;
  float* ws  = (float*)d_ws;

  size_t off = 0;
  float* qb  = ws + off; off += (size_t)BHn * Tn * 64;
  float* kb  = ws + off; off += (size_t)BHn * Tn * 64;
  float* vb  = ws + off; off += (size_t)BHn * Tn * 64;
  float* wb  = ws + off; off += (size_t)BHn * Tn * 64;
  float* Ub  = ws + off; off += (size_t)BHn * Tn * 64;
  float* ob  = ws + off; off += (size_t)BHn * Tn * 64;
  float* eta   = ws + off; off += (size_t)BHn * Tn;
  float* theta = ws + off; off += (size_t)BHn * Tn;
  float* rowm  = ws + off; off += (size_t)BHn * Tn;
  float* rowl  = ws + off; off += (size_t)BHn * Tn;
  float* Mcarry = ws + off; off += (size_t)BHn * 4096;
  float* Scarry = ws + off; off += (size_t)BHn * 4096;
  float* Mbuf   = ws + off;

  const size_t avail = ws_size / sizeof(float) - off;
  int Tc = 128;
  while (Tc > 8 && (size_t)BHn * Tc * 4096 > avail) Tc >>= 1;

  const int SOLVE_LDS = (5 * 64 * LDP + 128) * (int)sizeof(float);
  (void)hipFuncSetAttribute(reinterpret_cast<const void*>(solve_kernel),
                            hipFuncAttributeMaxDynamicSharedMemorySize, SOLVE_LDS);

  hipLaunchKernelGGL(init_carry_kernel, dim3(512), dim3(256), 0, stream, S0, M0, Scarry, Mcarry);
  hipLaunchKernelGGL(proj4_kernel, dim3(64, 8, 4), dim3(256), 0, stream,
                     x, Wq, Wk, Wv, Ww, qb, kb, vb, wb);
  hipLaunchKernelGGL(wp_kernel, dim3(256), dim3(256), 0, stream, x, Wp, eta, theta);
  hipLaunchKernelGGL(rowstats_kernel, dim3(16, 32), dim3(256), 0, stream, wb, kb, rowm, rowl);
  hipLaunchKernelGGL(solve_kernel, dim3(32), dim3(256), SOLVE_LDS, stream,
                     wb, kb, vb, rowm, rowl, Ub);

  for (int t0 = 0; t0 < Tn; t0 += Tc) {
    hipLaunchKernelGGL(mscan_kernel, dim3(512), dim3(256), 0, stream,
                       Ub, kb, theta, Mcarry, Mbuf, t0, Tc);
    hipLaunchKernelGGL(ns_kernel, dim3(BHn * Tc), dim3(256), 0, stream, Mbuf);
    hipLaunchKernelGGL(sscan_kernel, dim3(512), dim3(256), 0, stream,
                       eta, Scarry, Mbuf, t0, Tc);
    hipLaunchKernelGGL(outv_kernel, dim3(Tc, BHn), dim3(256), 0, stream,
                       Mbuf, qb, ob, t0, Tc);
  }

  hipLaunchKernelGGL(out_gemm_kernel, dim3(64, 8), dim3(256), 0, stream, ob, Wo, out);
}

// Round 2
// 2907.998 us; speedup vs baseline: 3.3689x; 3.3689x over previous
//
#include <hip/hip_runtime.h>
#include <hip/hip_bf16.h>
#include <math.h>

#define Bn 4
#define Tn 1024
#define Dn 512
#define Hn 8
#define BHn 32
#define LDP 65   // fp32 LDS stride (pad): 65 mod 32 = 1 -> <=2-way conflicts
#define LH 72    // fp16 LDS stride in halves: 144B rows -> 2-way conflicts on b128
#define LH8 9    // LH/8, stride in f16x8 units

typedef _Float16 f16x8 __attribute__((ext_vector_type(8)));
typedef _Float16 f16x4 __attribute__((ext_vector_type(4)));
typedef _Float16 f16x2 __attribute__((ext_vector_type(2)));
typedef float    f32x4 __attribute__((ext_vector_type(4)));

// Newton-Schulz coefficients (6 iterations)
__constant__ float NS_Ac[6] = {3955.0f/1024.0f, 3735.0f/1024.0f, 3799.0f/1024.0f,
                               4019.0f/1024.0f, 2677.0f/1024.0f, 2172.0f/1024.0f};
__constant__ float NS_Bc[6] = {-8306.0f/1024.0f, -6681.0f/1024.0f, -6499.0f/1024.0f,
                               -6385.0f/1024.0f, -3029.0f/1024.0f, -1833.0f/1024.0f};
__constant__ float NS_Cc[6] = {5008.0f/1024.0f, 3463.0f/1024.0f, 3211.0f/1024.0f,
                               2906.0f/1024.0f, 1162.0f/1024.0f,  682.0f/1024.0f};

__device__ __forceinline__ f32x4 mfma16(f16x8 a, f16x8 b, f32x4 c) {
  return __builtin_amdgcn_mfma_f32_16x16x32_f16(a, b, c, 0, 0, 0);
}

// ---------- fp32 helpers (projection / solve path) ----------

__device__ __forceinline__ void stage_tile(float* __restrict__ dst, const float* __restrict__ src,
                                           int srcStride, int tid) {
#pragma unroll
  for (int i = 0; i < 4; ++i) {
    const int idx = tid + (i << 8);
    const int row = idx >> 4;
    const int c4  = (idx & 15) << 2;
    const float4 v = *reinterpret_cast<const float4*>(src + (size_t)row * srcStride + c4);
    float* p = dst + row * LDP + c4;
    p[0] = v.x; p[1] = v.y; p[2] = v.z; p[3] = v.w;
  }
}

__device__ __forceinline__ void mm_nt_acc(float (&acc)[4][4], const float* __restrict__ a,
                                          const float* __restrict__ b, int i0, int j0) {
#pragma unroll 4
  for (int k = 0; k < 64; ++k) {
    float av[4], bv[4];
#pragma unroll
    for (int r = 0; r < 4; ++r) av[r] = a[(i0 + r) * LDP + k];
#pragma unroll
    for (int c = 0; c < 4; ++c) bv[c] = b[(j0 + c) * LDP + k];
#pragma unroll
    for (int r = 0; r < 4; ++r)
#pragma unroll
      for (int c = 0; c < 4; ++c) acc[r][c] = fmaf(av[r], bv[c], acc[r][c]);
  }
}

__device__ __forceinline__ void mm_nn_acc(float (&acc)[4][4], const float* __restrict__ a,
                                          const float* __restrict__ b, int i0, int j0) {
#pragma unroll 4
  for (int k = 0; k < 64; ++k) {
    float av[4], bv[4];
#pragma unroll
    for (int r = 0; r < 4; ++r) av[r] = a[(i0 + r) * LDP + k];
#pragma unroll
    for (int c = 0; c < 4; ++c) bv[c] = b[k * LDP + j0 + c];
#pragma unroll
    for (int r = 0; r < 4; ++r)
#pragma unroll
      for (int c = 0; c < 4; ++c) acc[r][c] = fmaf(av[r], bv[c], acc[r][c]);
  }
}

// unit-lower-triangular solve within a 64-block; Sc strict-lower, one wave, lane=dv column
__device__ __forceinline__ void tri_solve(const float* __restrict__ Sc,
                                          float* __restrict__ Uacc, int tid) {
  if (tid < 64) {
    const int dv = tid;
    for (int r2 = 1; r2 < 64; ++r2) {
      float s = 0.f;
      for (int c = 0; c < r2; ++c) s = fmaf(Sc[r2 * LDP + c], Uacc[c * LDP + dv], s);
      Uacc[r2 * LDP + dv] -= s;
    }
  }
}

// ---------- kernels ----------

// q/k/v/w projections: (4096 x 512) @ W^T, written as (b,h,t,e)
__global__ __launch_bounds__(256) void proj4_kernel(
    const float* __restrict__ x,
    const float* __restrict__ W0, const float* __restrict__ W1,
    const float* __restrict__ W2, const float* __restrict__ W3,
    float* __restrict__ o0, float* __restrict__ o1,
    float* __restrict__ o2, float* __restrict__ o3) {
  __shared__ float Xs[64 * LDP];
  __shared__ float Wsh[64 * LDP];
  const float* W; float* outp;
  switch (blockIdx.z) {
    case 0:  W = W0; outp = o0; break;
    case 1:  W = W1; outp = o1; break;
    case 2:  W = W2; outp = o2; break;
    default: W = W3; outp = o3; break;
  }
  const int tid = threadIdx.x;
  const int m0 = blockIdx.x * 64;
  const int n0 = blockIdx.y * 64;
  const int ty = tid >> 4, tx = tid & 15;
  const int i0 = ty * 4, j0 = tx * 4;
  float acc[4][4] = {};
  for (int kt = 0; kt < Dn; kt += 64) {
    stage_tile(Xs, x + (size_t)m0 * Dn + kt, Dn, tid);
    stage_tile(Wsh, W + (size_t)n0 * Dn + kt, Dn, tid);
    __syncthreads();
    mm_nt_acc(acc, Xs, Wsh, i0, j0);
    __syncthreads();
  }
#pragma unroll
  for (int r = 0; r < 4; ++r)
#pragma unroll
    for (int c = 0; c < 4; ++c) {
      const int m = m0 + i0 + r, n = n0 + j0 + c;
      const int b = m >> 10, t = m & 1023, h = n >> 6, e = n & 63;
      outp[(((size_t)(b * Hn + h)) * Tn + t) * 64 + e] = acc[r][c];
    }
}

// eta/theta projection: sigmoid(x @ Wp^T), Wp is (16,512)
#define XSTR 516
__global__ __launch_bounds__(256) void wp_kernel(const float* __restrict__ x,
                                                 const float* __restrict__ Wp,
                                                 float* __restrict__ eta,
                                                 float* __restrict__ theta) {
  __shared__ float xs[16 * XSTR];
  __shared__ float wps[16 * XSTR];
  const int tid = threadIdx.x;
  const int r0 = blockIdx.x * 16;
#pragma unroll
  for (int i = 0; i < 8; ++i) {
    const int idx = tid + (i << 8);
    const int r = idx >> 7, c4 = (idx & 127) << 2;
    const float4 v = *reinterpret_cast<const float4*>(x + (size_t)(r0 + r) * Dn + c4);
    float* p = xs + r * XSTR + c4;
    p[0] = v.x; p[1] = v.y; p[2] = v.z; p[3] = v.w;
    const float4 wv = *reinterpret_cast<const float4*>(Wp + (size_t)r * Dn + c4);
    float* pw = wps + r * XSTR + c4;
    pw[0] = wv.x; pw[1] = wv.y; pw[2] = wv.z; pw[3] = wv.w;
  }
  __syncthreads();
  const int row = tid >> 4, col = tid & 15;
  float acc = 0.f;
#pragma unroll 8
  for (int k = 0; k < Dn; ++k) acc = fmaf(xs[row * XSTR + k], wps[col * XSTR + k], acc);
  const float sg = 1.f / (1.f + __expf(-acc));
  const int m = r0 + row, b = m >> 10, t = m & 1023, h = col >> 1;
  float* dst = (col & 1) ? theta : eta;
  dst[((size_t)(b * Hn + h)) * Tn + t] = sg;
}

// Per-row softmax stats (max, sum of exp) over s < t, flash-style.
__global__ __launch_bounds__(256) void rowstats_kernel(
    const float* __restrict__ wb, const float* __restrict__ kb,
    float* __restrict__ rowm, float* __restrict__ rowl) {
  __shared__ float Wt[64 * LDP];
  __shared__ float Ks[64 * LDP];
  __shared__ float Sc[64 * LDP];
  __shared__ float rm[64];
  __shared__ float rl[64];
  const int tb = blockIdx.x, bh = blockIdx.y;
  const int t0 = tb * 64;
  const int tid = threadIdx.x;
  const int ty = tid >> 4, tx = tid & 15, i0 = ty * 4, j0 = tx * 4;
  stage_tile(Wt, wb + ((size_t)bh * Tn + t0) * 64, 64, tid);
  if (tid < 64) { rm[tid] = -INFINITY; rl[tid] = 0.f; }
  __syncthreads();
  for (int sb = 0; sb <= tb; ++sb) {
    stage_tile(Ks, kb + ((size_t)bh * Tn + sb * 64) * 64, 64, tid);
    __syncthreads();
    float acc[4][4] = {};
    mm_nt_acc(acc, Wt, Ks, i0, j0);
#pragma unroll
    for (int r = 0; r < 4; ++r)
#pragma unroll
      for (int c = 0; c < 4; ++c) {
        const int rr = i0 + r, cc = j0 + c;
        const bool valid = (sb < tb) || (cc < rr);
        Sc[rr * LDP + cc] = valid ? acc[r][c] * 0.125f : -INFINITY;
      }
    __syncthreads();
    if (tid < 64) {
      const int r = tid;
      float tm = -INFINITY;
      for (int c = 0; c < 64; ++c) tm = fmaxf(tm, Sc[r * LDP + c]);
      if (tm > -3.0e38f) {
        const float mnew = fmaxf(rm[r], tm);
        float s = 0.f;
        for (int c = 0; c < 64; ++c) s += __expf(Sc[r * LDP + c] - mnew);
        rl[r] = rl[r] * __expf(rm[r] - mnew) + s;
        rm[r] = mnew;
      }
    }
    __syncthreads();
  }
  if (tid < 64) {
    rowm[(size_t)bh * Tn + t0 + tid] = rm[tid];
    const float l = rl[tid];
    rowl[(size_t)bh * Tn + t0 + tid] = (l == 0.f) ? 1.f : l;
  }
}

// Ub := vb
__global__ __launch_bounds__(256) void copyU_kernel(const float* __restrict__ vb,
                                                    float* __restrict__ Ub) {
  const int gid = blockIdx.x * 256 + threadIdx.x;
  ((float4*)Ub)[gid] = ((const float4*)vb)[gid];
}

// diagonal solve of block 0 (rows 0..63), reads V directly
__global__ __launch_bounds__(256) void solve_diag0_kernel(
    const float* __restrict__ wb, const float* __restrict__ kb,
    const float* __restrict__ vb, const float* __restrict__ rowm,
    const float* __restrict__ rowl, float* __restrict__ Ub) {
  __shared__ float Wt[64 * LDP];
  __shared__ float Ks[64 * LDP];
  __shared__ float Uacc[64 * LDP];
  __shared__ float rm[64], rl[64];
  const int bh = blockIdx.x;
  const int tid = threadIdx.x;
  const int ty = tid >> 4, tx = tid & 15, i0 = ty * 4, j0 = tx * 4;
  stage_tile(Wt, wb + (size_t)bh * Tn * 64, 64, tid);
  stage_tile(Ks, kb + (size_t)bh * Tn * 64, 64, tid);
  stage_tile(Uacc, vb + (size_t)bh * Tn * 64, 64, tid);
  if (tid < 64) { rm[tid] = rowm[(size_t)bh * Tn + tid]; rl[tid] = rowl[(size_t)bh * Tn + tid]; }
  __syncthreads();
  float acc[4][4] = {};
  mm_nt_acc(acc, Wt, Ks, i0, j0);
  __syncthreads();
#pragma unroll
  for (int r = 0; r < 4; ++r)
#pragma unroll
    for (int c = 0; c < 4; ++c) {
      const int rr = i0 + r, cc = j0 + c;
      Ks[rr * LDP + cc] = (cc < rr) ? __expf(acc[r][c] * 0.125f - rm[rr]) / rl[rr] : 0.f;
    }
  __syncthreads();
  tri_solve(Ks, Uacc, tid);
  __syncthreads();
#pragma unroll
  for (int i = 0; i < 16; ++i) {
    const int idx = tid + (i << 8);
    const int row = idx >> 6, col = idx & 63;
    Ub[((size_t)bh * Tn + row) * 64 + col] = Uacc[row * LDP + col];
  }
}

// step ib: every future block f subtracts P[f,ib] @ U[ib]; block f==ib+1 also diag-solves
__global__ __launch_bounds__(256) void solve_step_kernel(
    const float* __restrict__ wb, const float* __restrict__ kb,
    const float* __restrict__ rowm, const float* __restrict__ rowl,
    float* __restrict__ Ub, int ib) {
  extern __shared__ float smem[];
  float* Wt   = smem;
  float* Ks   = Wt + 64 * LDP;
  float* Us   = Ks + 64 * LDP;
  float* Uacc = Us + 64 * LDP;
  float* rm   = Uacc + 64 * LDP;
  float* rl   = rm + 64;
  const int f  = ib + 1 + blockIdx.x;
  const int bh = blockIdx.y;
  const int tid = threadIdx.x;
  const int ty = tid >> 4, tx = tid & 15, i0 = ty * 4, j0 = tx * 4;
  stage_tile(Wt,   wb + ((size_t)bh * Tn + f  * 64) * 64, 64, tid);
  stage_tile(Ks,   kb + ((size_t)bh * Tn + ib * 64) * 64, 64, tid);
  stage_tile(Us,   Ub + ((size_t)bh * Tn + ib * 64) * 64, 64, tid);
  stage_tile(Uacc, Ub + ((size_t)bh * Tn + f  * 64) * 64, 64, tid);
  if (tid < 64) {
    rm[tid] = rowm[(size_t)bh * Tn + f * 64 + tid];
    rl[tid] = rowl[(size_t)bh * Tn + f * 64 + tid];
  }
  __syncthreads();
  float acc[4][4] = {};
  mm_nt_acc(acc, Wt, Ks, i0, j0);
  __syncthreads();                       // all reads of Ks done -> reuse as Sc
#pragma unroll
  for (int r = 0; r < 4; ++r)
#pragma unroll
    for (int c = 0; c < 4; ++c) {
      const int rr = i0 + r;
      Ks[rr * LDP + j0 + c] = __expf(acc[r][c] * 0.125f - rm[rr]) / rl[rr];
    }
  __syncthreads();
  float acc2[4][4] = {};
  mm_nn_acc(acc2, Ks, Us, i0, j0);
#pragma unroll
  for (int r = 0; r < 4; ++r)
#pragma unroll
    for (int c = 0; c < 4; ++c) Uacc[(i0 + r) * LDP + j0 + c] -= acc2[r][c];
  __syncthreads();
  if (f == ib + 1) {                     // block-uniform branch
    stage_tile(Us, kb + ((size_t)bh * Tn + f * 64) * 64, 64, tid);   // k rows of f
    __syncthreads();
    float acc3[4][4] = {};
    mm_nt_acc(acc3, Wt, Us, i0, j0);
    __syncthreads();
#pragma unroll
    for (int r = 0; r < 4; ++r)
#pragma unroll
      for (int c = 0; c < 4; ++c) {
        const int rr = i0 + r, cc = j0 + c;
        Ks[rr * LDP + cc] = (cc < rr) ? __expf(acc3[r][c] * 0.125f - rm[rr]) / rl[rr] : 0.f;
      }
    __syncthreads();
    tri_solve(Ks, Uacc, tid);
    __syncthreads();
  }
#pragma unroll
  for (int i = 0; i < 16; ++i) {
    const int idx = tid + (i << 8);
    const int row = idx >> 6, col = idx & 63;
    Ub[((size_t)bh * Tn + f * 64 + row) * 64 + col] = Uacc[row * LDP + col];
  }
}

// Momentum scan over a time chunk; writes fp16 M snapshots (2 elements/thread)
__global__ __launch_bounds__(256) void mscan_kernel(
    const float* __restrict__ Ub, const float* __restrict__ kb,
    const float* __restrict__ theta, float* __restrict__ Mcarry,
    _Float16* __restrict__ Mbuf, int t0, int Tc) {
  const int gid = blockIdx.x * 256 + threadIdx.x;   // BHn*2048
  const int bh = gid >> 11, p = gid & 2047;
  const int e0 = p * 2, dv = e0 >> 6, dk = e0 & 63;
  float2 M = ((const float2*)Mcarry)[gid];
  const float* Urow = Ub + (size_t)bh * Tn * 64;
  const float* krow = kb + (size_t)bh * Tn * 64;
  const float* th   = theta + (size_t)bh * Tn;
  for (int tl = 0; tl < Tc; ++tl) {
    const int t = t0 + tl;
    const float thv = th[t];
    const float u   = Urow[(size_t)t * 64 + dv];
    const float2 kv = *reinterpret_cast<const float2*>(krow + (size_t)t * 64 + dk);
    M.x = thv * M.x + (1.f - thv) * u * kv.x;
    M.y = thv * M.y + (1.f - thv) * u * kv.y;
    f16x2 w; w[0] = (_Float16)M.x; w[1] = (_Float16)M.y;
    *reinterpret_cast<f16x2*>(Mbuf + ((size_t)bh * Tc + tl) * 4096 + e0) = w;
  }
  ((float2*)Mcarry)[gid] = M;
}

// Newton-Schulz (6 iters) on one 64x64 fp16 matrix per workgroup, fp16 MFMA.
__global__ __launch_bounds__(256) void ns_kernel(_Float16* __restrict__ Mbuf) {
  __shared__ __align__(16) _Float16 Xs [64 * LH];
  __shared__ __align__(16) _Float16 XTs[64 * LH];
  __shared__ __align__(16) _Float16 As [64 * LH];
  __shared__ __align__(16) _Float16 Bms[64 * LH];
  __shared__ float red[4];
  _Float16* src = Mbuf + (size_t)blockIdx.x * 4096;
  const int tid  = threadIdx.x;
  const int wid  = tid >> 6, lane = tid & 63;
  const int r    = lane & 15, g = lane >> 4;
  const int i0   = wid * 16;

  // load fp16 M, fp32 Frobenius norm, write normalized X and X^T
  float vals[16];
  float ss = 0.f;
#pragma unroll
  for (int i = 0; i < 2; ++i) {
    const int q = tid + (i << 8);                    // 0..511
    f16x8 h = *reinterpret_cast<const f16x8*>(src + q * 8);
#pragma unroll
    for (int j = 0; j < 8; ++j) { float f = (float)h[j]; vals[i * 8 + j] = f; ss += f * f; }
  }
#pragma unroll
  for (int off = 32; off > 0; off >>= 1) ss += __shfl_down(ss, off, 64);
  if (lane == 0) red[wid] = ss;
  __syncthreads();
  const float inv = 1.f / (sqrtf(red[0] + red[1] + red[2] + red[3]) + 1e-7f);
#pragma unroll
  for (int i = 0; i < 2; ++i) {
    const int q = tid + (i << 8);
    const int row = q >> 3, c0 = (q & 7) * 8;
    f16x8 h;
#pragma unroll
    for (int j = 0; j < 8; ++j) h[j] = (_Float16)(vals[i * 8 + j] * inv);
    *reinterpret_cast<f16x8*>(Xs + row * LH + c0) = h;
#pragma unroll
    for (int j = 0; j < 8; ++j) XTs[(c0 + j) * LH + row] = h[j];
  }
  __syncthreads();

  const f16x8* X8  = reinterpret_cast<const f16x8*>(Xs);
  const f16x8* XT8 = reinterpret_cast<const f16x8*>(XTs);
  const f16x8* A8  = reinterpret_cast<const f16x8*>(As);
  const f16x8* B8  = reinterpret_cast<const f16x8*>(Bms);

#pragma unroll 1
  for (int it = 0; it < 6; ++it) {
    const float ca = NS_Ac[it], cb = NS_Bc[it], cc = NS_Cc[it];
    // A = X X^T  (NT: both operands are rows of X)
#pragma unroll
    for (int jb = 0; jb < 4; ++jb) {
      const int j0 = jb * 16;
      f32x4 acc = {0.f, 0.f, 0.f, 0.f};
      acc = mfma16(X8[(i0 + r) * LH8 + g],     X8[(j0 + r) * LH8 + g],     acc);
      acc = mfma16(X8[(i0 + r) * LH8 + 4 + g], X8[(j0 + r) * LH8 + 4 + g], acc);
#pragma unroll
      for (int reg = 0; reg < 4; ++reg)
        As[(i0 + g * 4 + reg) * LH + j0 + r] = (_Float16)acc[reg];
    }
    __syncthreads();
    // A2 = A A^T (A symmetric) ; Bm = cb*A + cc*A2
#pragma unroll
    for (int jb = 0; jb < 4; ++jb) {
      const int j0 = jb * 16;
      f32x4 acc = {0.f, 0.f, 0.f, 0.f};
      acc = mfma16(A8[(i0 + r) * LH8 + g],     A8[(j0 + r) * LH8 + g],     acc);
      acc = mfma16(A8[(i0 + r) * LH8 + 4 + g], A8[(j0 + r) * LH8 + 4 + g], acc);
#pragma unroll
      for (int reg = 0; reg < 4; ++reg) {
        const int idx = (i0 + g * 4 + reg) * LH + j0 + r;
        Bms[idx] = (_Float16)(cb * (float)As[idx] + cc * acc[reg]);
      }
    }
    __syncthreads();
    // D = Bm @ X  (NT: B-operand from X^T rows) ; X' = ca*X + D
    f32x4 dfr[4];
    float xold[4][4];
#pragma unroll
    for (int jb = 0; jb < 4; ++jb) {
      const int j0 = jb * 16;
      f32x4 acc = {0.f, 0.f, 0.f, 0.f};
      acc = mfma16(B8[(i0 + r) * LH8 + g],     XT8[(j0 + r) * LH8 + g],     acc);
      acc = mfma16(B8[(i0 + r) * LH8 + 4 + g], XT8[(j0 + r) * LH8 + 4 + g], acc);
      dfr[jb] = acc;
#pragma unroll
      for (int reg = 0; reg < 4; ++reg)
        xold[jb][reg] = (float)Xs[(i0 + g * 4 + reg) * LH + j0 + r];
    }
    __syncthreads();                      // all reads of Xs/XTs done before overwrite
    if (it == 5) {
#pragma unroll
      for (int jb = 0; jb < 4; ++jb)
#pragma unroll
        for (int reg = 0; reg < 4; ++reg)
          Xs[(i0 + g * 4 + reg) * LH + jb * 16 + r] =
              (_Float16)(ca * xold[jb][reg] + dfr[jb][reg]);
    } else {
#pragma unroll
      for (int jb = 0; jb < 4; ++jb) {
        f16x4 pack;
#pragma unroll
        for (int reg = 0; reg < 4; ++reg) {
          const _Float16 h = (_Float16)(ca * xold[jb][reg] + dfr[jb][reg]);
          Xs[(i0 + g * 4 + reg) * LH + jb * 16 + r] = h;
          pack[reg] = h;
        }
        *reinterpret_cast<f16x4*>(XTs + (jb * 16 + r) * LH + i0 + g * 4) = pack;
      }
    }
    __syncthreads();
  }
  // coalesced fp16 store
#pragma unroll
  for (int i = 0; i < 2; ++i) {
    const int q = tid + (i << 8);
    const int row = q >> 3, c0 = (q & 7) * 8;
    *reinterpret_cast<f16x8*>(src + q * 8) =
        *reinterpret_cast<const f16x8*>(Xs + row * LH + c0);
  }
}

// fused: S += eta_t * Sp_t (registers) ; o_t = S @ q_t. Block owns 16 dv rows.
__global__ __launch_bounds__(256) void sscan_outv_kernel(
    const float* __restrict__ eta, const float* __restrict__ qb,
    float* __restrict__ Scarry, const _Float16* __restrict__ Mbuf,
    float* __restrict__ ob, int t0, int Tc) {
  __shared__ float qs[64];
  __shared__ float red[256];
  const int dv0 = blockIdx.x * 16;
  const int bh  = blockIdx.y;
  const int tid = threadIdx.x;
  const int dvl = tid >> 4, dk0 = (tid & 15) * 4;
  const size_t cbase = (size_t)bh * 4096 + (dv0 + dvl) * 64 + dk0;
  float4 S = *reinterpret_cast<const float4*>(Scarry + cbase);
  for (int tl = 0; tl < Tc; ++tl) {
    const int t = t0 + tl;
    if (tid < 64) qs[tid] = qb[((size_t)bh * Tn + t) * 64 + tid];
    const float ev = eta[(size_t)bh * Tn + t];
    __syncthreads();
    const _Float16* sp = Mbuf + ((size_t)bh * Tc + tl) * 4096 + (dv0 + dvl) * 64 + dk0;
    f16x4 h = *reinterpret_cast<const f16x4*>(sp);
    S.x += ev * (float)h[0];
    S.y += ev * (float)h[1];
    S.z += ev * (float)h[2];
    S.w += ev * (float)h[3];
    float acc = S.x * qs[dk0] + S.y * qs[dk0 + 1] + S.z * qs[dk0 + 2] + S.w * qs[dk0 + 3];
    red[tid] = acc;
    __syncthreads();
    if (tid < 16) {
      float s = 0.f;
#pragma unroll
      for (int p2 = 0; p2 < 16; ++p2) s += red[tid * 16 + p2];
      ob[((size_t)bh * Tn + t) * 64 + dv0 + tid] = s;
    }
  }
  *reinterpret_cast<float4*>(Scarry + cbase) = S;
}

// init carries from S0 / M0 (broadcast over batch)
__global__ __launch_bounds__(256) void init_carry_kernel(
    const float* __restrict__ S0, const float* __restrict__ M0,
    float* __restrict__ Scarry, float* __restrict__ Mcarry) {
  const int gid = blockIdx.x * 256 + threadIdx.x;   // 131072
  const int h = (gid >> 12) & 7, e = gid & 4095;
  Scarry[gid] = S0[h * 4096 + e];
  Mcarry[gid] = M0[h * 4096 + e];
}

// final: out = o_flat @ Wo^T
__global__ __launch_bounds__(256) void out_gemm_kernel(
    const float* __restrict__ ob, const float* __restrict__ Wo,
    float* __restrict__ out) {
  __shared__ float As[64 * LDP];
  __shared__ float Bs[64 * LDP];
  const int tid = threadIdx.x;
  const int m0 = blockIdx.x * 64;
  const int n0 = blockIdx.y * 64;
  const int ty = tid >> 4, tx = tid & 15, i0 = ty * 4, j0 = tx * 4;
  float acc[4][4] = {};
  for (int kt = 0; kt < Dn; kt += 64) {
    const int h = kt >> 6;
#pragma unroll
    for (int i = 0; i < 4; ++i) {
      const int idx = tid + (i << 8);
      const int row = idx >> 4, c4 = (idx & 15) << 2;
      const int m = m0 + row, b = m >> 10, t = m & 1023;
      const float4 v = *reinterpret_cast<const float4*>(
          ob + ((size_t)(b * Hn + h) * Tn + t) * 64 + c4);
      float* p = As + row * LDP + c4;
      p[0] = v.x; p[1] = v.y; p[2] = v.z; p[3] = v.w;
    }
    stage_tile(Bs, Wo + (size_t)n0 * Dn + kt, Dn, tid);
    __syncthreads();
    mm_nt_acc(acc, As, Bs, i0, j0);
    __syncthreads();
  }
#pragma unroll
  for (int r = 0; r < 4; ++r)
#pragma unroll
    for (int c = 0; c < 4; ++c)
      out[(size_t)(m0 + i0 + r) * Dn + n0 + j0 + c] = acc[r][c];
}

// ---------- host ----------

extern "C" void kernel_launch(void* const* d_in, const int* in_sizes, int n_in,
                              void* d_out, int out_size, void* d_ws, size_t ws_size,
                              hipStream_t stream) {
  (void)in_sizes; (void)n_in; (void)out_size;
  const float* x  = (const float*)d_in[0];
  const float* Wq = (const float*)d_in[1];
  const float* Wk = (const float*)d_in[2];
  const float* Wv = (const float*)d_in[3];
  const float* Ww = (const float*)d_in[4];
  const float* Wp = (const float*)d_in[5];
  const float* Wo = (const float*)d_in[6];
  const float* S0 = (const float*)d_in[7];
  const float* M0 = (const float*)d_in[8];
  float* out = (float*)d_out;
  float* ws  = (float*)d_ws;

  size_t off = 0;
  float* qb  = ws + off; off += (size_t)BHn * Tn * 64;
  float* kb  = ws + off; off += (size_t)BHn * Tn * 64;
  float* vb  = ws + off; off += (size_t)BHn * Tn * 64;
  float* wb  = ws + off; off += (size_t)BHn * Tn * 64;
  float* Ub  = ws + off; off += (size_t)BHn * Tn * 64;
  float* ob  = ws + off; off += (size_t)BHn * Tn * 64;
  float* eta   = ws + off; off += (size_t)BHn * Tn;
  float* theta = ws + off; off += (size_t)BHn * Tn;
  float* rowm  = ws + off; off += (size_t)BHn * Tn;
  float* rowl  = ws + off; off += (size_t)BHn * Tn;
  float* Mcarry = ws + off; off += (size_t)BHn * 4096;
  float* Scarry = ws + off; off += (size_t)BHn * 4096;
  _Float16* Mbuf = (_Float16*)(ws + off);

  const size_t avail = ws_size / sizeof(float) - off;
  int Tc = 256;
  while (Tc > 8 && (size_t)BHn * Tc * 2048 > avail) Tc >>= 1;  // fp16: 2048 floats per (bh,t)

  const int SOLVE_LDS = (4 * 64 * LDP + 128) * (int)sizeof(float);
  (void)hipFuncSetAttribute(reinterpret_cast<const void*>(solve_step_kernel),
                            hipFuncAttributeMaxDynamicSharedMemorySize, SOLVE_LDS);

  hipLaunchKernelGGL(init_carry_kernel, dim3(512), dim3(256), 0, stream, S0, M0, Scarry, Mcarry);
  hipLaunchKernelGGL(proj4_kernel, dim3(64, 8, 4), dim3(256), 0, stream,
                     x, Wq, Wk, Wv, Ww, qb, kb, vb, wb);
  hipLaunchKernelGGL(wp_kernel, dim3(256), dim3(256), 0, stream, x, Wp, eta, theta);
  hipLaunchKernelGGL(rowstats_kernel, dim3(16, 32), dim3(256), 0, stream, wb, kb, rowm, rowl);
  hipLaunchKernelGGL(copyU_kernel, dim3(2048), dim3(256), 0, stream, vb, Ub);
  hipLaunchKernelGGL(solve_diag0_kernel, dim3(32), dim3(256), 0, stream,
                     wb, kb, vb, rowm, rowl, Ub);
  for (int ib = 0; ib < 15; ++ib) {
    hipLaunchKernelGGL(solve_step_kernel, dim3(15 - ib, 32), dim3(256), SOLVE_LDS, stream,
                       wb, kb, rowm, rowl, Ub, ib);
  }

  for (int t0 = 0; t0 < Tn; t0 += Tc) {
    hipLaunchKernelGGL(mscan_kernel, dim3(256), dim3(256), 0, stream,
                       Ub, kb, theta, Mcarry, Mbuf, t0, Tc);
    hipLaunchKernelGGL(ns_kernel, dim3(BHn * Tc), dim3(256), 0, stream, Mbuf);
    hipLaunchKernelGGL(sscan_outv_kernel, dim3(4, 32), dim3(256), 0, stream,
                       eta, qb, Scarry, Mbuf, ob, t0, Tc);
  }

  hipLaunchKernelGGL(out_gemm_kernel, dim3(64, 8), dim3(256), 0, stream, ob, Wo, out);
}

// Round 3
// 2318.080 us; speedup vs baseline: 4.2262x; 1.2545x over previous
//
#include <hip/hip_runtime.h>
#include <hip/hip_bf16.h>
#include <math.h>

#define Bn 4
#define Tn 1024
#define Dn 512
#define Hn 8
#define BHn 32
#define LDP 65   // fp32 LDS stride (pad): 65 mod 32 = 1 -> <=2-way conflicts
#define LH 72    // fp16 LDS stride in halves: 144B rows -> 2-way conflicts on b128
#define LH8 9    // LH/8, stride in f16x8 units

typedef _Float16 f16x8 __attribute__((ext_vector_type(8)));
typedef _Float16 f16x4 __attribute__((ext_vector_type(4)));
typedef _Float16 f16x2 __attribute__((ext_vector_type(2)));
typedef float    f32x4 __attribute__((ext_vector_type(4)));

// Newton-Schulz coefficients (6 iterations)
__constant__ float NS_Ac[6] = {3955.0f/1024.0f, 3735.0f/1024.0f, 3799.0f/1024.0f,
                               4019.0f/1024.0f, 2677.0f/1024.0f, 2172.0f/1024.0f};
__constant__ float NS_Bc[6] = {-8306.0f/1024.0f, -6681.0f/1024.0f, -6499.0f/1024.0f,
                               -6385.0f/1024.0f, -3029.0f/1024.0f, -1833.0f/1024.0f};
__constant__ float NS_Cc[6] = {5008.0f/1024.0f, 3463.0f/1024.0f, 3211.0f/1024.0f,
                               2906.0f/1024.0f, 1162.0f/1024.0f,  682.0f/1024.0f};

__device__ __forceinline__ f32x4 mfma16(f16x8 a, f16x8 b, f32x4 c) {
  return __builtin_amdgcn_mfma_f32_16x16x32_f16(a, b, c, 0, 0, 0);
}

// ---------- fp32 helpers (projection / solve path) ----------

__device__ __forceinline__ void stage_tile(float* __restrict__ dst, const float* __restrict__ src,
                                           int srcStride, int tid) {
#pragma unroll
  for (int i = 0; i < 4; ++i) {
    const int idx = tid + (i << 8);
    const int row = idx >> 4;
    const int c4  = (idx & 15) << 2;
    const float4 v = *reinterpret_cast<const float4*>(src + (size_t)row * srcStride + c4);
    float* p = dst + row * LDP + c4;
    p[0] = v.x; p[1] = v.y; p[2] = v.z; p[3] = v.w;
  }
}

__device__ __forceinline__ void mm_nt_acc(float (&acc)[4][4], const float* __restrict__ a,
                                          const float* __restrict__ b, int i0, int j0) {
#pragma unroll 4
  for (int k = 0; k < 64; ++k) {
    float av[4], bv[4];
#pragma unroll
    for (int r = 0; r < 4; ++r) av[r] = a[(i0 + r) * LDP + k];
#pragma unroll
    for (int c = 0; c < 4; ++c) bv[c] = b[(j0 + c) * LDP + k];
#pragma unroll
    for (int r = 0; r < 4; ++r)
#pragma unroll
      for (int c = 0; c < 4; ++c) acc[r][c] = fmaf(av[r], bv[c], acc[r][c]);
  }
}

__device__ __forceinline__ void mm_nn_acc(float (&acc)[4][4], const float* __restrict__ a,
                                          const float* __restrict__ b, int i0, int j0) {
#pragma unroll 4
  for (int k = 0; k < 64; ++k) {
    float av[4], bv[4];
#pragma unroll
    for (int r = 0; r < 4; ++r) av[r] = a[(i0 + r) * LDP + k];
#pragma unroll
    for (int c = 0; c < 4; ++c) bv[c] = b[k * LDP + j0 + c];
#pragma unroll
    for (int r = 0; r < 4; ++r)
#pragma unroll
      for (int c = 0; c < 4; ++c) acc[r][c] = fmaf(av[r], bv[c], acc[r][c]);
  }
}

// unit-lower-triangular solve within a 64-block; Sc strict-lower, one wave, lane=dv column
__device__ __forceinline__ void tri_solve(const float* __restrict__ Sc,
                                          float* __restrict__ Uacc, int tid) {
  if (tid < 64) {
    const int dv = tid;
    for (int r2 = 1; r2 < 64; ++r2) {
      float s = 0.f;
      for (int c = 0; c < r2; ++c) s = fmaf(Sc[r2 * LDP + c], Uacc[c * LDP + dv], s);
      Uacc[r2 * LDP + dv] -= s;
    }
  }
}

// ---------- kernels ----------

// q/k/v/w projections: (4096 x 512) @ W^T, written as (b,h,t,e)
__global__ __launch_bounds__(256) void proj4_kernel(
    const float* __restrict__ x,
    const float* __restrict__ W0, const float* __restrict__ W1,
    const float* __restrict__ W2, const float* __restrict__ W3,
    float* __restrict__ o0, float* __restrict__ o1,
    float* __restrict__ o2, float* __restrict__ o3) {
  __shared__ float Xs[64 * LDP];
  __shared__ float Wsh[64 * LDP];
  const float* W; float* outp;
  switch (blockIdx.z) {
    case 0:  W = W0; outp = o0; break;
    case 1:  W = W1; outp = o1; break;
    case 2:  W = W2; outp = o2; break;
    default: W = W3; outp = o3; break;
  }
  const int tid = threadIdx.x;
  const int m0 = blockIdx.x * 64;
  const int n0 = blockIdx.y * 64;
  const int ty = tid >> 4, tx = tid & 15;
  const int i0 = ty * 4, j0 = tx * 4;
  float acc[4][4] = {};
  for (int kt = 0; kt < Dn; kt += 64) {
    stage_tile(Xs, x + (size_t)m0 * Dn + kt, Dn, tid);
    stage_tile(Wsh, W + (size_t)n0 * Dn + kt, Dn, tid);
    __syncthreads();
    mm_nt_acc(acc, Xs, Wsh, i0, j0);
    __syncthreads();
  }
#pragma unroll
  for (int r = 0; r < 4; ++r)
#pragma unroll
    for (int c = 0; c < 4; ++c) {
      const int m = m0 + i0 + r, n = n0 + j0 + c;
      const int b = m >> 10, t = m & 1023, h = n >> 6, e = n & 63;
      outp[(((size_t)(b * Hn + h)) * Tn + t) * 64 + e] = acc[r][c];
    }
}

// eta/theta projection: sigmoid(x @ Wp^T), Wp is (16,512)
#define XSTR 516
__global__ __launch_bounds__(256) void wp_kernel(const float* __restrict__ x,
                                                 const float* __restrict__ Wp,
                                                 float* __restrict__ eta,
                                                 float* __restrict__ theta) {
  __shared__ float xs[16 * XSTR];
  __shared__ float wps[16 * XSTR];
  const int tid = threadIdx.x;
  const int r0 = blockIdx.x * 16;
#pragma unroll
  for (int i = 0; i < 8; ++i) {
    const int idx = tid + (i << 8);
    const int r = idx >> 7, c4 = (idx & 127) << 2;
    const float4 v = *reinterpret_cast<const float4*>(x + (size_t)(r0 + r) * Dn + c4);
    float* p = xs + r * XSTR + c4;
    p[0] = v.x; p[1] = v.y; p[2] = v.z; p[3] = v.w;
    const float4 wv = *reinterpret_cast<const float4*>(Wp + (size_t)r * Dn + c4);
    float* pw = wps + r * XSTR + c4;
    pw[0] = wv.x; pw[1] = wv.y; pw[2] = wv.z; pw[3] = wv.w;
  }
  __syncthreads();
  const int row = tid >> 4, col = tid & 15;
  float acc = 0.f;
#pragma unroll 8
  for (int k = 0; k < Dn; ++k) acc = fmaf(xs[row * XSTR + k], wps[col * XSTR + k], acc);
  const float sg = 1.f / (1.f + __expf(-acc));
  const int m = r0 + row, b = m >> 10, t = m & 1023, h = col >> 1;
  float* dst = (col & 1) ? theta : eta;
  dst[((size_t)(b * Hn + h)) * Tn + t] = sg;
}

// Per-row softmax stats (max, sum of exp) over s < t, flash-style.
__global__ __launch_bounds__(256) void rowstats_kernel(
    const float* __restrict__ wb, const float* __restrict__ kb,
    float* __restrict__ rowm, float* __restrict__ rowl) {
  __shared__ float Wt[64 * LDP];
  __shared__ float Ks[64 * LDP];
  __shared__ float Sc[64 * LDP];
  __shared__ float rm[64];
  __shared__ float rl[64];
  const int tb = blockIdx.x, bh = blockIdx.y;
  const int t0 = tb * 64;
  const int tid = threadIdx.x;
  const int ty = tid >> 4, tx = tid & 15, i0 = ty * 4, j0 = tx * 4;
  stage_tile(Wt, wb + ((size_t)bh * Tn + t0) * 64, 64, tid);
  if (tid < 64) { rm[tid] = -INFINITY; rl[tid] = 0.f; }
  __syncthreads();
  for (int sb = 0; sb <= tb; ++sb) {
    stage_tile(Ks, kb + ((size_t)bh * Tn + sb * 64) * 64, 64, tid);
    __syncthreads();
    float acc[4][4] = {};
    mm_nt_acc(acc, Wt, Ks, i0, j0);
#pragma unroll
    for (int r = 0; r < 4; ++r)
#pragma unroll
      for (int c = 0; c < 4; ++c) {
        const int rr = i0 + r, cc = j0 + c;
        const bool valid = (sb < tb) || (cc < rr);
        Sc[rr * LDP + cc] = valid ? acc[r][c] * 0.125f : -INFINITY;
      }
    __syncthreads();
    if (tid < 64) {
      const int r = tid;
      float tm = -INFINITY;
      for (int c = 0; c < 64; ++c) tm = fmaxf(tm, Sc[r * LDP + c]);
      if (tm > -3.0e38f) {
        const float mnew = fmaxf(rm[r], tm);
        float s = 0.f;
        for (int c = 0; c < 64; ++c) s += __expf(Sc[r * LDP + c] - mnew);
        rl[r] = rl[r] * __expf(rm[r] - mnew) + s;
        rm[r] = mnew;
      }
    }
    __syncthreads();
  }
  if (tid < 64) {
    rowm[(size_t)bh * Tn + t0 + tid] = rm[tid];
    const float l = rl[tid];
    rowl[(size_t)bh * Tn + t0 + tid] = (l == 0.f) ? 1.f : l;
  }
}

// Ub := vb
__global__ __launch_bounds__(256) void copyU_kernel(const float* __restrict__ vb,
                                                    float* __restrict__ Ub) {
  const int gid = blockIdx.x * 256 + threadIdx.x;
  ((float4*)Ub)[gid] = ((const float4*)vb)[gid];
}

// diagonal solve of block 0 (rows 0..63), reads V directly
__global__ __launch_bounds__(256) void solve_diag0_kernel(
    const float* __restrict__ wb, const float* __restrict__ kb,
    const float* __restrict__ vb, const float* __restrict__ rowm,
    const float* __restrict__ rowl, float* __restrict__ Ub) {
  __shared__ float Wt[64 * LDP];
  __shared__ float Ks[64 * LDP];
  __shared__ float Uacc[64 * LDP];
  __shared__ float rm[64], rl[64];
  const int bh = blockIdx.x;
  const int tid = threadIdx.x;
  const int ty = tid >> 4, tx = tid & 15, i0 = ty * 4, j0 = tx * 4;
  stage_tile(Wt, wb + (size_t)bh * Tn * 64, 64, tid);
  stage_tile(Ks, kb + (size_t)bh * Tn * 64, 64, tid);
  stage_tile(Uacc, vb + (size_t)bh * Tn * 64, 64, tid);
  if (tid < 64) { rm[tid] = rowm[(size_t)bh * Tn + tid]; rl[tid] = rowl[(size_t)bh * Tn + tid]; }
  __syncthreads();
  float acc[4][4] = {};
  mm_nt_acc(acc, Wt, Ks, i0, j0);
  __syncthreads();
#pragma unroll
  for (int r = 0; r < 4; ++r)
#pragma unroll
    for (int c = 0; c < 4; ++c) {
      const int rr = i0 + r, cc = j0 + c;
      Ks[rr * LDP + cc] = (cc < rr) ? __expf(acc[r][c] * 0.125f - rm[rr]) / rl[rr] : 0.f;
    }
  __syncthreads();
  tri_solve(Ks, Uacc, tid);
  __syncthreads();
#pragma unroll
  for (int i = 0; i < 16; ++i) {
    const int idx = tid + (i << 8);
    const int row = idx >> 6, col = idx & 63;
    Ub[((size_t)bh * Tn + row) * 64 + col] = Uacc[row * LDP + col];
  }
}

// step ib: every future block f subtracts P[f,ib] @ U[ib]; block f==ib+1 also diag-solves
__global__ __launch_bounds__(256) void solve_step_kernel(
    const float* __restrict__ wb, const float* __restrict__ kb,
    const float* __restrict__ rowm, const float* __restrict__ rowl,
    float* __restrict__ Ub, int ib) {
  extern __shared__ float smem[];
  float* Wt   = smem;
  float* Ks   = Wt + 64 * LDP;
  float* Us   = Ks + 64 * LDP;
  float* Uacc = Us + 64 * LDP;
  float* rm   = Uacc + 64 * LDP;
  float* rl   = rm + 64;
  const int f  = ib + 1 + blockIdx.x;
  const int bh = blockIdx.y;
  const int tid = threadIdx.x;
  const int ty = tid >> 4, tx = tid & 15, i0 = ty * 4, j0 = tx * 4;
  stage_tile(Wt,   wb + ((size_t)bh * Tn + f  * 64) * 64, 64, tid);
  stage_tile(Ks,   kb + ((size_t)bh * Tn + ib * 64) * 64, 64, tid);
  stage_tile(Us,   Ub + ((size_t)bh * Tn + ib * 64) * 64, 64, tid);
  stage_tile(Uacc, Ub + ((size_t)bh * Tn + f  * 64) * 64, 64, tid);
  if (tid < 64) {
    rm[tid] = rowm[(size_t)bh * Tn + f * 64 + tid];
    rl[tid] = rowl[(size_t)bh * Tn + f * 64 + tid];
  }
  __syncthreads();
  float acc[4][4] = {};
  mm_nt_acc(acc, Wt, Ks, i0, j0);
  __syncthreads();                       // all reads of Ks done -> reuse as Sc
#pragma unroll
  for (int r = 0; r < 4; ++r)
#pragma unroll
    for (int c = 0; c < 4; ++c) {
      const int rr = i0 + r;
      Ks[rr * LDP + j0 + c] = __expf(acc[r][c] * 0.125f - rm[rr]) / rl[rr];
    }
  __syncthreads();
  float acc2[4][4] = {};
  mm_nn_acc(acc2, Ks, Us, i0, j0);
#pragma unroll
  for (int r = 0; r < 4; ++r)
#pragma unroll
    for (int c = 0; c < 4; ++c) Uacc[(i0 + r) * LDP + j0 + c] -= acc2[r][c];
  __syncthreads();
  if (f == ib + 1) {                     // block-uniform branch
    stage_tile(Us, kb + ((size_t)bh * Tn + f * 64) * 64, 64, tid);   // k rows of f
    __syncthreads();
    float acc3[4][4] = {};
    mm_nt_acc(acc3, Wt, Us, i0, j0);
    __syncthreads();
#pragma unroll
    for (int r = 0; r < 4; ++r)
#pragma unroll
      for (int c = 0; c < 4; ++c) {
        const int rr = i0 + r, cc = j0 + c;
        Ks[rr * LDP + cc] = (cc < rr) ? __expf(acc3[r][c] * 0.125f - rm[rr]) / rl[rr] : 0.f;
      }
    __syncthreads();
    tri_solve(Ks, Uacc, tid);
    __syncthreads();
  }
#pragma unroll
  for (int i = 0; i < 16; ++i) {
    const int idx = tid + (i << 8);
    const int row = idx >> 6, col = idx & 63;
    Ub[((size_t)bh * Tn + f * 64 + row) * 64 + col] = Uacc[row * LDP + col];
  }
}

// Momentum scan over a time chunk; writes fp16 M snapshots (2 elements/thread)
__global__ __launch_bounds__(256) void mscan_kernel(
    const float* __restrict__ Ub, const float* __restrict__ kb,
    const float* __restrict__ theta, float* __restrict__ Mcarry,
    _Float16* __restrict__ Mbuf, int t0, int Tc) {
  const int gid = blockIdx.x * 256 + threadIdx.x;   // BHn*2048
  const int bh = gid >> 11, p = gid & 2047;
  const int e0 = p * 2, dv = e0 >> 6, dk = e0 & 63;
  float2 M = ((const float2*)Mcarry)[gid];
  const float* Urow = Ub + (size_t)bh * Tn * 64;
  const float* krow = kb + (size_t)bh * Tn * 64;
  const float* th   = theta + (size_t)bh * Tn;
  for (int tl = 0; tl < Tc; ++tl) {
    const int t = t0 + tl;
    const float thv = th[t];
    const float u   = Urow[(size_t)t * 64 + dv];
    const float2 kv = *reinterpret_cast<const float2*>(krow + (size_t)t * 64 + dk);
    M.x = thv * M.x + (1.f - thv) * u * kv.x;
    M.y = thv * M.y + (1.f - thv) * u * kv.y;
    f16x2 w; w[0] = (_Float16)M.x; w[1] = (_Float16)M.y;
    *reinterpret_cast<f16x2*>(Mbuf + ((size_t)bh * Tc + tl) * 4096 + e0) = w;
  }
  ((float2*)Mcarry)[gid] = M;
}

// Newton-Schulz (6 iters) on one 64x64 fp16 matrix per workgroup, fp16 MFMA.
__global__ __launch_bounds__(256) void ns_kernel(_Float16* __restrict__ Mbuf) {
  __shared__ __align__(16) _Float16 Xs [64 * LH];
  __shared__ __align__(16) _Float16 XTs[64 * LH];
  __shared__ __align__(16) _Float16 As [64 * LH];
  __shared__ __align__(16) _Float16 Bms[64 * LH];
  __shared__ float red[4];
  _Float16* src = Mbuf + (size_t)blockIdx.x * 4096;
  const int tid  = threadIdx.x;
  const int wid  = tid >> 6, lane = tid & 63;
  const int r    = lane & 15, g = lane >> 4;
  const int i0   = wid * 16;

  // load fp16 M, fp32 Frobenius norm, write normalized X and X^T
  float vals[16];
  float ss = 0.f;
#pragma unroll
  for (int i = 0; i < 2; ++i) {
    const int q = tid + (i << 8);                    // 0..511
    f16x8 h = *reinterpret_cast<const f16x8*>(src + q * 8);
#pragma unroll
    for (int j = 0; j < 8; ++j) { float f = (float)h[j]; vals[i * 8 + j] = f; ss += f * f; }
  }
#pragma unroll
  for (int off = 32; off > 0; off >>= 1) ss += __shfl_down(ss, off, 64);
  if (lane == 0) red[wid] = ss;
  __syncthreads();
  const float inv = 1.f / (sqrtf(red[0] + red[1] + red[2] + red[3]) + 1e-7f);
#pragma unroll
  for (int i = 0; i < 2; ++i) {
    const int q = tid + (i << 8);
    const int row = q >> 3, c0 = (q & 7) * 8;
    f16x8 h;
#pragma unroll
    for (int j = 0; j < 8; ++j) h[j] = (_Float16)(vals[i * 8 + j] * inv);
    *reinterpret_cast<f16x8*>(Xs + row * LH + c0) = h;
#pragma unroll
    for (int j = 0; j < 8; ++j) XTs[(c0 + j) * LH + row] = h[j];
  }
  __syncthreads();

  const f16x8* X8  = reinterpret_cast<const f16x8*>(Xs);
  const f16x8* XT8 = reinterpret_cast<const f16x8*>(XTs);
  const f16x8* A8  = reinterpret_cast<const f16x8*>(As);
  const f16x8* B8  = reinterpret_cast<const f16x8*>(Bms);

#pragma unroll 1
  for (int it = 0; it < 6; ++it) {
    const float ca = NS_Ac[it], cb = NS_Bc[it], cc = NS_Cc[it];
    // A = X X^T  (NT: both operands are rows of X)
#pragma unroll
    for (int jb = 0; jb < 4; ++jb) {
      const int j0 = jb * 16;
      f32x4 acc = {0.f, 0.f, 0.f, 0.f};
      acc = mfma16(X8[(i0 + r) * LH8 + g],     X8[(j0 + r) * LH8 + g],     acc);
      acc = mfma16(X8[(i0 + r) * LH8 + 4 + g], X8[(j0 + r) * LH8 + 4 + g], acc);
#pragma unroll
      for (int reg = 0; reg < 4; ++reg)
        As[(i0 + g * 4 + reg) * LH + j0 + r] = (_Float16)acc[reg];
    }
    __syncthreads();
    // A2 = A A^T (A symmetric) ; Bm = cb*A + cc*A2
#pragma unroll
    for (int jb = 0; jb < 4; ++jb) {
      const int j0 = jb * 16;
      f32x4 acc = {0.f, 0.f, 0.f, 0.f};
      acc = mfma16(A8[(i0 + r) * LH8 + g],     A8[(j0 + r) * LH8 + g],     acc);
      acc = mfma16(A8[(i0 + r) * LH8 + 4 + g], A8[(j0 + r) * LH8 + 4 + g], acc);
#pragma unroll
      for (int reg = 0; reg < 4; ++reg) {
        const int idx = (i0 + g * 4 + reg) * LH + j0 + r;
        Bms[idx] = (_Float16)(cb * (float)As[idx] + cc * acc[reg]);
      }
    }
    __syncthreads();
    // D = Bm @ X  (NT: B-operand from X^T rows) ; X' = ca*X + D
    f32x4 dfr[4];
    float xold[4][4];
#pragma unroll
    for (int jb = 0; jb < 4; ++jb) {
      const int j0 = jb * 16;
      f32x4 acc = {0.f, 0.f, 0.f, 0.f};
      acc = mfma16(B8[(i0 + r) * LH8 + g],     XT8[(j0 + r) * LH8 + g],     acc);
      acc = mfma16(B8[(i0 + r) * LH8 + 4 + g], XT8[(j0 + r) * LH8 + 4 + g], acc);
      dfr[jb] = acc;
#pragma unroll
      for (int reg = 0; reg < 4; ++reg)
        xold[jb][reg] = (float)Xs[(i0 + g * 4 + reg) * LH + j0 + r];
    }
    __syncthreads();                      // all reads of Xs/XTs done before overwrite
    if (it == 5) {
#pragma unroll
      for (int jb = 0; jb < 4; ++jb)
#pragma unroll
        for (int reg = 0; reg < 4; ++reg)
          Xs[(i0 + g * 4 + reg) * LH + jb * 16 + r] =
              (_Float16)(ca * xold[jb][reg] + dfr[jb][reg]);
    } else {
#pragma unroll
      for (int jb = 0; jb < 4; ++jb) {
        f16x4 pack;
#pragma unroll
        for (int reg = 0; reg < 4; ++reg) {
          const _Float16 h = (_Float16)(ca * xold[jb][reg] + dfr[jb][reg]);
          Xs[(i0 + g * 4 + reg) * LH + jb * 16 + r] = h;
          pack[reg] = h;
        }
        *reinterpret_cast<f16x4*>(XTs + (jb * 16 + r) * LH + i0 + g * 4) = pack;
      }
    }
    __syncthreads();
  }
  // coalesced fp16 store
#pragma unroll
  for (int i = 0; i < 2; ++i) {
    const int q = tid + (i << 8);
    const int row = q >> 3, c0 = (q & 7) * 8;
    *reinterpret_cast<f16x8*>(src + q * 8) =
        *reinterpret_cast<const f16x8*>(Xs + row * LH + c0);
  }
}

// P1: G_j = sum over 16-step subchunk of eta_s * Sp_s (fp32 regs, coalesced streams)
__global__ __launch_bounds__(256) void gsum_kernel(
    const float* __restrict__ eta, const _Float16* __restrict__ Mbuf,
    float* __restrict__ Gbuf, int t0, int Tc) {
  const int j = blockIdx.x, bh = blockIdx.y, tid = threadIdx.x;
  const int nsub = Tc >> 4;
  float acc[16] = {};
#pragma unroll 1
  for (int i = 0; i < 16; ++i) {
    const int tl = j * 16 + i;
    const float ev = eta[(size_t)bh * Tn + t0 + tl];
    const _Float16* sp = Mbuf + ((size_t)bh * Tc + tl) * 4096;
    const f16x8 h0 = *reinterpret_cast<const f16x8*>(sp + tid * 8);
    const f16x8 h1 = *reinterpret_cast<const f16x8*>(sp + 2048 + tid * 8);
#pragma unroll
    for (int u = 0; u < 8; ++u) {
      acc[u]     += ev * (float)h0[u];
      acc[8 + u] += ev * (float)h1[u];
    }
  }
  float* g = Gbuf + ((size_t)bh * nsub + j) * 4096;
#pragma unroll
  for (int u = 0; u < 2; ++u) {
    float4 w0 = {acc[u*4], acc[u*4+1], acc[u*4+2], acc[u*4+3]};
    *reinterpret_cast<float4*>(g + tid * 8 + u * 4) = w0;
    float4 w1 = {acc[8+u*4], acc[8+u*4+1], acc[8+u*4+2], acc[8+u*4+3]};
    *reinterpret_cast<float4*>(g + 2048 + tid * 8 + u * 4) = w1;
  }
}

// P2: scan G over subchunks -> Sbase_j (S at subchunk start); updates Scarry
__global__ __launch_bounds__(256) void sbase_kernel(
    float* __restrict__ Scarry, const float* __restrict__ Gbuf,
    float* __restrict__ Sbase, int Tc) {
  const int gid = blockIdx.x * 256 + threadIdx.x;   // BHn*4096
  const int bh = gid >> 12, e = gid & 4095;
  const int nsub = Tc >> 4;
  float S = Scarry[gid];
  for (int j = 0; j < nsub; ++j) {
    const size_t idx = ((size_t)bh * nsub + j) * 4096 + e;
    Sbase[idx] = S;
    S += Gbuf[idx];
  }
  Scarry[gid] = S;
}

// P3: per (subchunk, bh): S in registers (4x4 tile/thread), 16 sequential steps:
// S += eta*Sp ; o_t = S q_t via shfl_xor reduce over tx. Zero LDS/barriers.
__global__ __launch_bounds__(256) void outv2_kernel(
    const float* __restrict__ eta, const float* __restrict__ qb,
    const float* __restrict__ Sbase, const _Float16* __restrict__ Mbuf,
    float* __restrict__ ob, int t0, int Tc) {
  const int j = blockIdx.x, bh = blockIdx.y, tid = threadIdx.x;
  const int nsub = Tc >> 4;
  const int ty = tid >> 4, tx = tid & 15;
  const int dv0 = ty * 4, dk0 = tx * 4;
  float S[4][4];
  const float* sb = Sbase + ((size_t)bh * nsub + j) * 4096;
#pragma unroll
  for (int r = 0; r < 4; ++r) {
    const float4 v = *reinterpret_cast<const float4*>(sb + (dv0 + r) * 64 + dk0);
    S[r][0] = v.x; S[r][1] = v.y; S[r][2] = v.z; S[r][3] = v.w;
  }
#pragma unroll 1
  for (int i = 0; i < 16; ++i) {
    const int tl = j * 16 + i, t = t0 + tl;
    const float ev = eta[(size_t)bh * Tn + t];
    const float4 q4 = *reinterpret_cast<const float4*>(qb + ((size_t)bh * Tn + t) * 64 + dk0);
    const _Float16* sp = Mbuf + ((size_t)bh * Tc + tl) * 4096;
    float part[4];
#pragma unroll
    for (int r = 0; r < 4; ++r) {
      const f16x4 h = *reinterpret_cast<const f16x4*>(sp + (dv0 + r) * 64 + dk0);
      S[r][0] += ev * (float)h[0];
      S[r][1] += ev * (float)h[1];
      S[r][2] += ev * (float)h[2];
      S[r][3] += ev * (float)h[3];
      part[r] = S[r][0] * q4.x + S[r][1] * q4.y + S[r][2] * q4.z + S[r][3] * q4.w;
    }
#pragma unroll
    for (int m = 1; m < 16; m <<= 1)
#pragma unroll
      for (int r = 0; r < 4; ++r) part[r] += __shfl_xor(part[r], m, 64);
    if (tx == 0) {
      float4 o4 = {part[0], part[1], part[2], part[3]};
      *reinterpret_cast<float4*>(ob + ((size_t)bh * Tn + t) * 64 + dv0) = o4;
    }
  }
}

// init carries from S0 / M0 (broadcast over batch)
__global__ __launch_bounds__(256) void init_carry_kernel(
    const float* __restrict__ S0, const float* __restrict__ M0,
    float* __restrict__ Scarry, float* __restrict__ Mcarry) {
  const int gid = blockIdx.x * 256 + threadIdx.x;   // 131072
  const int h = (gid >> 12) & 7, e = gid & 4095;
  Scarry[gid] = S0[h * 4096 + e];
  Mcarry[gid] = M0[h * 4096 + e];
}

// final: out = o_flat @ Wo^T
__global__ __launch_bounds__(256) void out_gemm_kernel(
    const float* __restrict__ ob, const float* __restrict__ Wo,
    float* __restrict__ out) {
  __shared__ float As[64 * LDP];
  __shared__ float Bs[64 * LDP];
  const int tid = threadIdx.x;
  const int m0 = blockIdx.x * 64;
  const int n0 = blockIdx.y * 64;
  const int ty = tid >> 4, tx = tid & 15, i0 = ty * 4, j0 = tx * 4;
  float acc[4][4] = {};
  for (int kt = 0; kt < Dn; kt += 64) {
    const int h = kt >> 6;
#pragma unroll
    for (int i = 0; i < 4; ++i) {
      const int idx = tid + (i << 8);
      const int row = idx >> 4, c4 = (idx & 15) << 2;
      const int m = m0 + row, b = m >> 10, t = m & 1023;
      const float4 v = *reinterpret_cast<const float4*>(
          ob + ((size_t)(b * Hn + h) * Tn + t) * 64 + c4);
      float* p = As + row * LDP + c4;
      p[0] = v.x; p[1] = v.y; p[2] = v.z; p[3] = v.w;
    }
    stage_tile(Bs, Wo + (size_t)n0 * Dn + kt, Dn, tid);
    __syncthreads();
    mm_nt_acc(acc, As, Bs, i0, j0);
    __syncthreads();
  }
#pragma unroll
  for (int r = 0; r < 4; ++r)
#pragma unroll
    for (int c = 0; c < 4; ++c)
      out[(size_t)(m0 + i0 + r) * Dn + n0 + j0 + c] = acc[r][c];
}

// ---------- host ----------

extern "C" void kernel_launch(void* const* d_in, const int* in_sizes, int n_in,
                              void* d_out, int out_size, void* d_ws, size_t ws_size,
                              hipStream_t stream) {
  (void)in_sizes; (void)n_in; (void)out_size;
  const float* x  = (const float*)d_in[0];
  const float* Wq = (const float*)d_in[1];
  const float* Wk = (const float*)d_in[2];
  const float* Wv = (const float*)d_in[3];
  const float* Ww = (const float*)d_in[4];
  const float* Wp = (const float*)d_in[5];
  const float* Wo = (const float*)d_in[6];
  const float* S0 = (const float*)d_in[7];
  const float* M0 = (const float*)d_in[8];
  float* out = (float*)d_out;
  float* ws  = (float*)d_ws;

  size_t off = 0;
  float* qb  = ws + off; off += (size_t)BHn * Tn * 64;
  float* kb  = ws + off; off += (size_t)BHn * Tn * 64;
  float* vb  = ws + off; off += (size_t)BHn * Tn * 64;
  float* wb  = ws + off; off += (size_t)BHn * Tn * 64;
  float* Ub  = ws + off; off += (size_t)BHn * Tn * 64;
  float* ob  = ws + off; off += (size_t)BHn * Tn * 64;
  float* eta   = ws + off; off += (size_t)BHn * Tn;
  float* theta = ws + off; off += (size_t)BHn * Tn;
  float* rowm  = ws + off; off += (size_t)BHn * Tn;
  float* rowl  = ws + off; off += (size_t)BHn * Tn;
  float* Mcarry = ws + off; off += (size_t)BHn * 4096;
  float* Scarry = ws + off; off += (size_t)BHn * 4096;

  const size_t avail0 = ws_size / sizeof(float) - off;
  int Tc = 256;
  // need: Mbuf fp16 (BHn*Tc*2048 floats) + Gbuf + Sbase (2 * BHn*(Tc/16)*4096 floats)
  while (Tc > 16 && (size_t)BHn * Tc * 2048 + 2 * (size_t)BHn * (Tc / 16) * 4096 > avail0)
    Tc >>= 1;
  const int nsub = Tc >> 4;

  float* Gbuf  = ws + off; off += (size_t)BHn * nsub * 4096;
  float* Sbase = ws + off; off += (size_t)BHn * nsub * 4096;
  _Float16* Mbuf = (_Float16*)(ws + off);

  const int SOLVE_LDS = (4 * 64 * LDP + 128) * (int)sizeof(float);
  (void)hipFuncSetAttribute(reinterpret_cast<const void*>(solve_step_kernel),
                            hipFuncAttributeMaxDynamicSharedMemorySize, SOLVE_LDS);

  hipLaunchKernelGGL(init_carry_kernel, dim3(512), dim3(256), 0, stream, S0, M0, Scarry, Mcarry);
  hipLaunchKernelGGL(proj4_kernel, dim3(64, 8, 4), dim3(256), 0, stream,
                     x, Wq, Wk, Wv, Ww, qb, kb, vb, wb);
  hipLaunchKernelGGL(wp_kernel, dim3(256), dim3(256), 0, stream, x, Wp, eta, theta);
  hipLaunchKernelGGL(rowstats_kernel, dim3(16, 32), dim3(256), 0, stream, wb, kb, rowm, rowl);
  hipLaunchKernelGGL(copyU_kernel, dim3(2048), dim3(256), 0, stream, vb, Ub);
  hipLaunchKernelGGL(solve_diag0_kernel, dim3(32), dim3(256), 0, stream,
                     wb, kb, vb, rowm, rowl, Ub);
  for (int ib = 0; ib < 15; ++ib) {
    hipLaunchKernelGGL(solve_step_kernel, dim3(15 - ib, 32), dim3(256), SOLVE_LDS, stream,
                       wb, kb, rowm, rowl, Ub, ib);
  }

  for (int t0 = 0; t0 < Tn; t0 += Tc) {
    hipLaunchKernelGGL(mscan_kernel, dim3(256), dim3(256), 0, stream,
                       Ub, kb, theta, Mcarry, Mbuf, t0, Tc);
    hipLaunchKernelGGL(ns_kernel, dim3(BHn * Tc), dim3(256), 0, stream, Mbuf);
    hipLaunchKernelGGL(gsum_kernel, dim3(nsub, BHn), dim3(256), 0, stream,
                       eta, Mbuf, Gbuf, t0, Tc);
    hipLaunchKernelGGL(sbase_kernel, dim3(512), dim3(256), 0, stream, Scarry, Gbuf, Sbase, Tc);
    hipLaunchKernelGGL(outv2_kernel, dim3(nsub, BHn), dim3(256), 0, stream,
                       eta, qb, Sbase, Mbuf, ob, t0, Tc);
  }

  hipLaunchKernelGGL(out_gemm_kernel, dim3(64, 8), dim3(256), 0, stream, ob, Wo, out);
}

// Round 4
// 1936.746 us; speedup vs baseline: 5.0583x; 1.1969x over previous
//
#include <hip/hip_runtime.h>
#include <hip/hip_bf16.h>
#include <math.h>

#define Bn 4
#define Tn 1024
#define Dn 512
#define Hn 8
#define BHn 32
#define LDP 65   // fp32 LDS stride (pad): 65 mod 32 = 1 -> <=2-way conflicts
#define LH 72    // fp16 LDS stride in halves: 144B rows, 16B-aligned

typedef _Float16 f16x8 __attribute__((ext_vector_type(8)));
typedef _Float16 f16x4 __attribute__((ext_vector_type(4)));
typedef _Float16 f16x2 __attribute__((ext_vector_type(2)));
typedef float    f32x4 __attribute__((ext_vector_type(4)));

// Newton-Schulz coefficients (6 iterations)
__constant__ float NS_Ac[6] = {3955.0f/1024.0f, 3735.0f/1024.0f, 3799.0f/1024.0f,
                               4019.0f/1024.0f, 2677.0f/1024.0f, 2172.0f/1024.0f};
__constant__ float NS_Bc[6] = {-8306.0f/1024.0f, -6681.0f/1024.0f, -6499.0f/1024.0f,
                               -6385.0f/1024.0f, -3029.0f/1024.0f, -1833.0f/1024.0f};
__constant__ float NS_Cc[6] = {5008.0f/1024.0f, 3463.0f/1024.0f, 3211.0f/1024.0f,
                               2906.0f/1024.0f, 1162.0f/1024.0f,  682.0f/1024.0f};

__device__ __forceinline__ f32x4 mfma16(f16x4 a, f16x4 b, f32x4 c) {
  return __builtin_amdgcn_mfma_f32_16x16x16f16(a, b, c, 0, 0, 0);
}

__device__ __forceinline__ f16x4 cvt4(f32x4 a) {
  f16x4 h;
  h[0] = (_Float16)a[0]; h[1] = (_Float16)a[1];
  h[2] = (_Float16)a[2]; h[3] = (_Float16)a[3];
  return h;
}

// ---------- fp32 helpers (projection / solve path) ----------

__device__ __forceinline__ void stage_tile(float* __restrict__ dst, const float* __restrict__ src,
                                           int srcStride, int tid) {
#pragma unroll
  for (int i = 0; i < 4; ++i) {
    const int idx = tid + (i << 8);
    const int row = idx >> 4;
    const int c4  = (idx & 15) << 2;
    const float4 v = *reinterpret_cast<const float4*>(src + (size_t)row * srcStride + c4);
    float* p = dst + row * LDP + c4;
    p[0] = v.x; p[1] = v.y; p[2] = v.z; p[3] = v.w;
  }
}

__device__ __forceinline__ void mm_nt_acc(float (&acc)[4][4], const float* __restrict__ a,
                                          const float* __restrict__ b, int i0, int j0) {
#pragma unroll 4
  for (int k = 0; k < 64; ++k) {
    float av[4], bv[4];
#pragma unroll
    for (int r = 0; r < 4; ++r) av[r] = a[(i0 + r) * LDP + k];
#pragma unroll
    for (int c = 0; c < 4; ++c) bv[c] = b[(j0 + c) * LDP + k];
#pragma unroll
    for (int r = 0; r < 4; ++r)
#pragma unroll
      for (int c = 0; c < 4; ++c) acc[r][c] = fmaf(av[r], bv[c], acc[r][c]);
  }
}

__device__ __forceinline__ void mm_nn_acc(float (&acc)[4][4], const float* __restrict__ a,
                                          const float* __restrict__ b, int i0, int j0) {
#pragma unroll 4
  for (int k = 0; k < 64; ++k) {
    float av[4], bv[4];
#pragma unroll
    for (int r = 0; r < 4; ++r) av[r] = a[(i0 + r) * LDP + k];
#pragma unroll
    for (int c = 0; c < 4; ++c) bv[c] = b[k * LDP + j0 + c];
#pragma unroll
    for (int r = 0; r < 4; ++r)
#pragma unroll
      for (int c = 0; c < 4; ++c) acc[r][c] = fmaf(av[r], bv[c], acc[r][c]);
  }
}

// unit-lower-triangular solve within a 64-block; Sc strict-lower, one wave, lane=dv column
__device__ __forceinline__ void tri_solve(const float* __restrict__ Sc,
                                          float* __restrict__ Uacc, int tid) {
  if (tid < 64) {
    const int dv = tid;
    for (int r2 = 1; r2 < 64; ++r2) {
      float s = 0.f;
      for (int c = 0; c < r2; ++c) s = fmaf(Sc[r2 * LDP + c], Uacc[c * LDP + dv], s);
      Uacc[r2 * LDP + dv] -= s;
    }
  }
}

// ---------- kernels ----------

// q/k/v/w projections: (4096 x 512) @ W^T, written as (b,h,t,e)
__global__ __launch_bounds__(256) void proj4_kernel(
    const float* __restrict__ x,
    const float* __restrict__ W0, const float* __restrict__ W1,
    const float* __restrict__ W2, const float* __restrict__ W3,
    float* __restrict__ o0, float* __restrict__ o1,
    float* __restrict__ o2, float* __restrict__ o3) {
  __shared__ float Xs[64 * LDP];
  __shared__ float Wsh[64 * LDP];
  const float* W; float* outp;
  switch (blockIdx.z) {
    case 0:  W = W0; outp = o0; break;
    case 1:  W = W1; outp = o1; break;
    case 2:  W = W2; outp = o2; break;
    default: W = W3; outp = o3; break;
  }
  const int tid = threadIdx.x;
  const int m0 = blockIdx.x * 64;
  const int n0 = blockIdx.y * 64;
  const int ty = tid >> 4, tx = tid & 15;
  const int i0 = ty * 4, j0 = tx * 4;
  float acc[4][4] = {};
  for (int kt = 0; kt < Dn; kt += 64) {
    stage_tile(Xs, x + (size_t)m0 * Dn + kt, Dn, tid);
    stage_tile(Wsh, W + (size_t)n0 * Dn + kt, Dn, tid);
    __syncthreads();
    mm_nt_acc(acc, Xs, Wsh, i0, j0);
    __syncthreads();
  }
#pragma unroll
  for (int r = 0; r < 4; ++r)
#pragma unroll
    for (int c = 0; c < 4; ++c) {
      const int m = m0 + i0 + r, n = n0 + j0 + c;
      const int b = m >> 10, t = m & 1023, h = n >> 6, e = n & 63;
      outp[(((size_t)(b * Hn + h)) * Tn + t) * 64 + e] = acc[r][c];
    }
}

// eta/theta projection: sigmoid(x @ Wp^T), Wp is (16,512)
#define XSTR 516
__global__ __launch_bounds__(256) void wp_kernel(const float* __restrict__ x,
                                                 const float* __restrict__ Wp,
                                                 float* __restrict__ eta,
                                                 float* __restrict__ theta) {
  __shared__ float xs[16 * XSTR];
  __shared__ float wps[16 * XSTR];
  const int tid = threadIdx.x;
  const int r0 = blockIdx.x * 16;
#pragma unroll
  for (int i = 0; i < 8; ++i) {
    const int idx = tid + (i << 8);
    const int r = idx >> 7, c4 = (idx & 127) << 2;
    const float4 v = *reinterpret_cast<const float4*>(x + (size_t)(r0 + r) * Dn + c4);
    float* p = xs + r * XSTR + c4;
    p[0] = v.x; p[1] = v.y; p[2] = v.z; p[3] = v.w;
    const float4 wv = *reinterpret_cast<const float4*>(Wp + (size_t)r * Dn + c4);
    float* pw = wps + r * XSTR + c4;
    pw[0] = wv.x; pw[1] = wv.y; pw[2] = wv.z; pw[3] = wv.w;
  }
  __syncthreads();
  const int row = tid >> 4, col = tid & 15;
  float acc = 0.f;
#pragma unroll 8
  for (int k = 0; k < Dn; ++k) acc = fmaf(xs[row * XSTR + k], wps[col * XSTR + k], acc);
  const float sg = 1.f / (1.f + __expf(-acc));
  const int m = r0 + row, b = m >> 10, t = m & 1023, h = col >> 1;
  float* dst = (col & 1) ? theta : eta;
  dst[((size_t)(b * Hn + h)) * Tn + t] = sg;
}

// Per-row softmax stats (max, sum of exp) over s < t, flash-style.
__global__ __launch_bounds__(256) void rowstats_kernel(
    const float* __restrict__ wb, const float* __restrict__ kb,
    float* __restrict__ rowm, float* __restrict__ rowl) {
  __shared__ float Wt[64 * LDP];
  __shared__ float Ks[64 * LDP];
  __shared__ float Sc[64 * LDP];
  __shared__ float rm[64];
  __shared__ float rl[64];
  const int tb = blockIdx.x, bh = blockIdx.y;
  const int t0 = tb * 64;
  const int tid = threadIdx.x;
  const int ty = tid >> 4, tx = tid & 15, i0 = ty * 4, j0 = tx * 4;
  stage_tile(Wt, wb + ((size_t)bh * Tn + t0) * 64, 64, tid);
  if (tid < 64) { rm[tid] = -INFINITY; rl[tid] = 0.f; }
  __syncthreads();
  for (int sb = 0; sb <= tb; ++sb) {
    stage_tile(Ks, kb + ((size_t)bh * Tn + sb * 64) * 64, 64, tid);
    __syncthreads();
    float acc[4][4] = {};
    mm_nt_acc(acc, Wt, Ks, i0, j0);
#pragma unroll
    for (int r = 0; r < 4; ++r)
#pragma unroll
      for (int c = 0; c < 4; ++c) {
        const int rr = i0 + r, cc = j0 + c;
        const bool valid = (sb < tb) || (cc < rr);
        Sc[rr * LDP + cc] = valid ? acc[r][c] * 0.125f : -INFINITY;
      }
    __syncthreads();
    if (tid < 64) {
      const int r = tid;
      float tm = -INFINITY;
      for (int c = 0; c < 64; ++c) tm = fmaxf(tm, Sc[r * LDP + c]);
      if (tm > -3.0e38f) {
        const float mnew = fmaxf(rm[r], tm);
        float s = 0.f;
        for (int c = 0; c < 64; ++c) s += __expf(Sc[r * LDP + c] - mnew);
        rl[r] = rl[r] * __expf(rm[r] - mnew) + s;
        rm[r] = mnew;
      }
    }
    __syncthreads();
  }
  if (tid < 64) {
    rowm[(size_t)bh * Tn + t0 + tid] = rm[tid];
    const float l = rl[tid];
    rowl[(size_t)bh * Tn + t0 + tid] = (l == 0.f) ? 1.f : l;
  }
}

// Ub := vb
__global__ __launch_bounds__(256) void copyU_kernel(const float* __restrict__ vb,
                                                    float* __restrict__ Ub) {
  const int gid = blockIdx.x * 256 + threadIdx.x;
  ((float4*)Ub)[gid] = ((const float4*)vb)[gid];
}

// diagonal solve of block 0 (rows 0..63), reads V directly
__global__ __launch_bounds__(256) void solve_diag0_kernel(
    const float* __restrict__ wb, const float* __restrict__ kb,
    const float* __restrict__ vb, const float* __restrict__ rowm,
    const float* __restrict__ rowl, float* __restrict__ Ub) {
  __shared__ float Wt[64 * LDP];
  __shared__ float Ks[64 * LDP];
  __shared__ float Uacc[64 * LDP];
  __shared__ float rm[64], rl[64];
  const int bh = blockIdx.x;
  const int tid = threadIdx.x;
  const int ty = tid >> 4, tx = tid & 15, i0 = ty * 4, j0 = tx * 4;
  stage_tile(Wt, wb + (size_t)bh * Tn * 64, 64, tid);
  stage_tile(Ks, kb + (size_t)bh * Tn * 64, 64, tid);
  stage_tile(Uacc, vb + (size_t)bh * Tn * 64, 64, tid);
  if (tid < 64) { rm[tid] = rowm[(size_t)bh * Tn + tid]; rl[tid] = rowl[(size_t)bh * Tn + tid]; }
  __syncthreads();
  float acc[4][4] = {};
  mm_nt_acc(acc, Wt, Ks, i0, j0);
  __syncthreads();
#pragma unroll
  for (int r = 0; r < 4; ++r)
#pragma unroll
    for (int c = 0; c < 4; ++c) {
      const int rr = i0 + r, cc = j0 + c;
      Ks[rr * LDP + cc] = (cc < rr) ? __expf(acc[r][c] * 0.125f - rm[rr]) / rl[rr] : 0.f;
    }
  __syncthreads();
  tri_solve(Ks, Uacc, tid);
  __syncthreads();
#pragma unroll
  for (int i = 0; i < 16; ++i) {
    const int idx = tid + (i << 8);
    const int row = idx >> 6, col = idx & 63;
    Ub[((size_t)bh * Tn + row) * 64 + col] = Uacc[row * LDP + col];
  }
}

// step ib: every future block f subtracts P[f,ib] @ U[ib]; block f==ib+1 also diag-solves
__global__ __launch_bounds__(256) void solve_step_kernel(
    const float* __restrict__ wb, const float* __restrict__ kb,
    const float* __restrict__ rowm, const float* __restrict__ rowl,
    float* __restrict__ Ub, int ib) {
  extern __shared__ float smem[];
  float* Wt   = smem;
  float* Ks   = Wt + 64 * LDP;
  float* Us   = Ks + 64 * LDP;
  float* Uacc = Us + 64 * LDP;
  float* rm   = Uacc + 64 * LDP;
  float* rl   = rm + 64;
  const int f  = ib + 1 + blockIdx.x;
  const int bh = blockIdx.y;
  const int tid = threadIdx.x;
  const int ty = tid >> 4, tx = tid & 15, i0 = ty * 4, j0 = tx * 4;
  stage_tile(Wt,   wb + ((size_t)bh * Tn + f  * 64) * 64, 64, tid);
  stage_tile(Ks,   kb + ((size_t)bh * Tn + ib * 64) * 64, 64, tid);
  stage_tile(Us,   Ub + ((size_t)bh * Tn + ib * 64) * 64, 64, tid);
  stage_tile(Uacc, Ub + ((size_t)bh * Tn + f  * 64) * 64, 64, tid);
  if (tid < 64) {
    rm[tid] = rowm[(size_t)bh * Tn + f * 64 + tid];
    rl[tid] = rowl[(size_t)bh * Tn + f * 64 + tid];
  }
  __syncthreads();
  float acc[4][4] = {};
  mm_nt_acc(acc, Wt, Ks, i0, j0);
  __syncthreads();                       // all reads of Ks done -> reuse as Sc
#pragma unroll
  for (int r = 0; r < 4; ++r)
#pragma unroll
    for (int c = 0; c < 4; ++c) {
      const int rr = i0 + r;
      Ks[rr * LDP + j0 + c] = __expf(acc[r][c] * 0.125f - rm[rr]) / rl[rr];
    }
  __syncthreads();
  float acc2[4][4] = {};
  mm_nn_acc(acc2, Ks, Us, i0, j0);
#pragma unroll
  for (int r = 0; r < 4; ++r)
#pragma unroll
    for (int c = 0; c < 4; ++c) Uacc[(i0 + r) * LDP + j0 + c] -= acc2[r][c];
  __syncthreads();
  if (f == ib + 1) {                     // block-uniform branch
    stage_tile(Us, kb + ((size_t)bh * Tn + f * 64) * 64, 64, tid);   // k rows of f
    __syncthreads();
    float acc3[4][4] = {};
    mm_nt_acc(acc3, Wt, Us, i0, j0);
    __syncthreads();
#pragma unroll
    for (int r = 0; r < 4; ++r)
#pragma unroll
      for (int c = 0; c < 4; ++c) {
        const int rr = i0 + r, cc = j0 + c;
        Ks[rr * LDP + cc] = (cc < rr) ? __expf(acc3[r][c] * 0.125f - rm[rr]) / rl[rr] : 0.f;
      }
    __syncthreads();
    tri_solve(Ks, Uacc, tid);
    __syncthreads();
  }
#pragma unroll
  for (int i = 0; i < 16; ++i) {
    const int idx = tid + (i << 8);
    const int row = idx >> 6, col = idx & 63;
    Ub[((size_t)bh * Tn + f * 64 + row) * 64 + col] = Uacc[row * LDP + col];
  }
}

// Momentum scan over a time chunk; writes fp16 M snapshots (2 elements/thread)
__global__ __launch_bounds__(256) void mscan_kernel(
    const float* __restrict__ Ub, const float* __restrict__ kb,
    const float* __restrict__ theta, float* __restrict__ Mcarry,
    _Float16* __restrict__ Mbuf, int t0, int Tc) {
  const int gid = blockIdx.x * 256 + threadIdx.x;   // BHn*2048
  const int bh = gid >> 11, p = gid & 2047;
  const int e0 = p * 2, dv = e0 >> 6, dk = e0 & 63;
  float2 M = ((const float2*)Mcarry)[gid];
  const float* Urow = Ub + (size_t)bh * Tn * 64;
  const float* krow = kb + (size_t)bh * Tn * 64;
  const float* th   = theta + (size_t)bh * Tn;
  for (int tl = 0; tl < Tc; ++tl) {
    const int t = t0 + tl;
    const float thv = th[t];
    const float u   = Urow[(size_t)t * 64 + dv];
    const float2 kv = *reinterpret_cast<const float2*>(krow + (size_t)t * 64 + dk);
    M.x = thv * M.x + (1.f - thv) * u * kv.x;
    M.y = thv * M.y + (1.f - thv) * u * kv.y;
    f16x2 w; w[0] = (_Float16)M.x; w[1] = (_Float16)M.y;
    *reinterpret_cast<f16x2*>(Mbuf + ((size_t)bh * Tc + tl) * 4096 + e0) = w;
  }
  ((float2*)Mcarry)[gid] = M;
}

// Newton-Schulz (6 iters), ONE WAVE per 64x64 matrix, fully register-resident.
// Uses mfma_f32_16x16x16f16 and the acc<->frag layout identity:
//   acc of NT(P,Q) == frag layout of (P Q^T)^T = Q P^T  (lane-local convert).
// A = X X^T and Bm' = a I + b A + c A^2 are symmetric, so operand frags come
// straight from acc converts. X^T frags re-derived via identity-MFMA (exact).
__global__ __launch_bounds__(256, 2) void ns_kernel(_Float16* __restrict__ Mbuf) {
  __shared__ __align__(16) _Float16 Ms[4][64 * LH];
  const int tid  = threadIdx.x;
  const int wid  = tid >> 6, lane = tid & 63;
  const int r    = lane & 15, g = lane >> 4;
  _Float16* src = Mbuf + ((size_t)blockIdx.x * 4 + wid) * 4096;
  _Float16* lds = Ms[wid];

  // ---- load (coalesced), Frobenius norm, scale, stage rows to LDS ----
  f16x8 ld[8];
  float ss = 0.f;
#pragma unroll
  for (int c = 0; c < 8; ++c) {
    ld[c] = *reinterpret_cast<const f16x8*>(src + c * 512 + lane * 8);
#pragma unroll
    for (int j = 0; j < 8; ++j) { const float f = (float)ld[c][j]; ss += f * f; }
  }
#pragma unroll
  for (int off = 32; off > 0; off >>= 1) ss += __shfl_xor(ss, off, 64);
  const float inv = 1.f / (sqrtf(ss) + 1e-7f);
  const int lrow = (lane >> 3), lcol = (lane & 7) * 8;
#pragma unroll
  for (int c = 0; c < 8; ++c) {
    f16x8 h;
#pragma unroll
    for (int j = 0; j < 8; ++j) h[j] = (_Float16)((float)ld[c][j] * inv);
    *reinterpret_cast<f16x8*>(lds + (c * 8 + lrow) * LH + lcol) = h;
  }
  __syncthreads();

  // ---- X row-frags ----
  f16x4 Xf[4][4];   // [tile-row i][k-chunk kc]: row i*16+r, cols kc*16+4g..+3
#pragma unroll
  for (int i = 0; i < 4; ++i)
#pragma unroll
    for (int kc = 0; kc < 4; ++kc)
      Xf[i][kc] = *reinterpret_cast<const f16x4*>(lds + (i * 16 + r) * LH + kc * 16 + 4 * g);

  // identity frag (B-operand rows of I): elem d = (r == 4g+d)
  const int dd = r - 4 * g;
  f16x4 If;
  If[0] = (dd == 0) ? (_Float16)1.f : (_Float16)0.f;
  If[1] = (dd == 1) ? (_Float16)1.f : (_Float16)0.f;
  If[2] = (dd == 2) ? (_Float16)1.f : (_Float16)0.f;
  If[3] = (dd == 3) ? (_Float16)1.f : (_Float16)0.f;
  float Iw[4];
  Iw[0] = (float)If[0]; Iw[1] = (float)If[1]; Iw[2] = (float)If[2]; Iw[3] = (float)If[3];

  // XTf = frags of X^T via identity MFMA (exact)
  f16x4 XTf[4][4];
#pragma unroll
  for (int i = 0; i < 4; ++i)
#pragma unroll
    for (int j = 0; j < 4; ++j) {
      f32x4 t = mfma16(Xf[i][j], If, (f32x4){0.f, 0.f, 0.f, 0.f});
      XTf[j][i] = cvt4(t);
    }

  f16x4 Ff[4][4];    // A frags, then Bm' frags
  f32x4 acc[4][4];

#pragma unroll 1
  for (int it = 0; it < 6; ++it) {
    const float ca = NS_Ac[it], cb = NS_Bc[it], cc = NS_Cc[it];
    // m1: acc = X X^T (= A, symmetric)
#pragma unroll
    for (int i = 0; i < 4; ++i)
#pragma unroll
      for (int j = 0; j < 4; ++j) {
        f32x4 a = {0.f, 0.f, 0.f, 0.f};
#pragma unroll
        for (int kc = 0; kc < 4; ++kc) a = mfma16(Xf[i][kc], Xf[j][kc], a);
        acc[i][j] = a;
      }
    // Af from acc (A symmetric: acc[i][j] = frag[j][kc=i] of A)
#pragma unroll
    for (int i = 0; i < 4; ++i)
#pragma unroll
      for (int j = 0; j < 4; ++j) Ff[j][i] = cvt4(acc[i][j]);
    // m2: acc = c*(A A^T + (b/c) A) = b A + c A^2 ; then add a on diagonal
    const float bc = cb / cc;
#pragma unroll
    for (int i = 0; i < 4; ++i)
#pragma unroll
      for (int j = 0; j < 4; ++j) {
        f32x4 a = acc[i][j];
        a[0] *= bc; a[1] *= bc; a[2] *= bc; a[3] *= bc;
#pragma unroll
        for (int kc = 0; kc < 4; ++kc) a = mfma16(Ff[i][kc], Ff[j][kc], a);
        a[0] *= cc; a[1] *= cc; a[2] *= cc; a[3] *= cc;
        acc[i][j] = a;
      }
#pragma unroll
    for (int i = 0; i < 4; ++i) {   // Bm' = Bm + a I  (diagonal tiles only)
#pragma unroll
      for (int d = 0; d < 4; ++d) acc[i][i][d] = fmaf(ca, Iw[d], acc[i][i][d]);
    }
    // Bm' frags (symmetric)
#pragma unroll
    for (int i = 0; i < 4; ++i)
#pragma unroll
      for (int j = 0; j < 4; ++j) Ff[j][i] = cvt4(acc[i][j]);
    // m3: acc = NT(XTf, Bmf) = X^T Bm' ; acc[i][j] = frag[j][kc=i] of Bm' X = X'
#pragma unroll
    for (int i = 0; i < 4; ++i)
#pragma unroll
      for (int j = 0; j < 4; ++j) {
        f32x4 a = {0.f, 0.f, 0.f, 0.f};
#pragma unroll
        for (int kc = 0; kc < 4; ++kc) a = mfma16(XTf[i][kc], Ff[j][kc], a);
        acc[i][j] = a;
      }
#pragma unroll
    for (int i = 0; i < 4; ++i)
#pragma unroll
      for (int j = 0; j < 4; ++j) Xf[j][i] = cvt4(acc[i][j]);
    // refresh XTf from new X (exact identity transpose); skip on last iter
    if (it < 5) {
#pragma unroll
      for (int i = 0; i < 4; ++i)
#pragma unroll
        for (int j = 0; j < 4; ++j) {
          f32x4 t = mfma16(Xf[i][j], If, (f32x4){0.f, 0.f, 0.f, 0.f});
          XTf[j][i] = cvt4(t);
        }
    }
  }

  // ---- store result (frags -> LDS rows -> coalesced global) ----
  __syncthreads();
#pragma unroll
  for (int i = 0; i < 4; ++i)
#pragma unroll
    for (int kc = 0; kc < 4; ++kc)
      *reinterpret_cast<f16x4*>(lds + (i * 16 + r) * LH + kc * 16 + 4 * g) = Xf[i][kc];
  __syncthreads();
#pragma unroll
  for (int c = 0; c < 8; ++c) {
    const f16x8 h = *reinterpret_cast<const f16x8*>(lds + (c * 8 + lrow) * LH + lcol);
    *reinterpret_cast<f16x8*>(src + c * 512 + lane * 8) = h;
  }
}

// P1: G_j = sum over 16-step subchunk of eta_s * Sp_s (fp32 regs, coalesced streams)
__global__ __launch_bounds__(256) void gsum_kernel(
    const float* __restrict__ eta, const _Float16* __restrict__ Mbuf,
    float* __restrict__ Gbuf, int t0, int Tc) {
  const int j = blockIdx.x, bh = blockIdx.y, tid = threadIdx.x;
  const int nsub = Tc >> 4;
  float acc[16] = {};
#pragma unroll 1
  for (int i = 0; i < 16; ++i) {
    const int tl = j * 16 + i;
    const float ev = eta[(size_t)bh * Tn + t0 + tl];
    const _Float16* sp = Mbuf + ((size_t)bh * Tc + tl) * 4096;
    const f16x8 h0 = *reinterpret_cast<const f16x8*>(sp + tid * 8);
    const f16x8 h1 = *reinterpret_cast<const f16x8*>(sp + 2048 + tid * 8);
#pragma unroll
    for (int u = 0; u < 8; ++u) {
      acc[u]     += ev * (float)h0[u];
      acc[8 + u] += ev * (float)h1[u];
    }
  }
  float* g = Gbuf + ((size_t)bh * nsub + j) * 4096;
#pragma unroll
  for (int u = 0; u < 2; ++u) {
    float4 w0 = {acc[u*4], acc[u*4+1], acc[u*4+2], acc[u*4+3]};
    *reinterpret_cast<float4*>(g + tid * 8 + u * 4) = w0;
    float4 w1 = {acc[8+u*4], acc[8+u*4+1], acc[8+u*4+2], acc[8+u*4+3]};
    *reinterpret_cast<float4*>(g + 2048 + tid * 8 + u * 4) = w1;
  }
}

// P2: scan G over subchunks -> Sbase_j (S at subchunk start); updates Scarry
__global__ __launch_bounds__(256) void sbase_kernel(
    float* __restrict__ Scarry, const float* __restrict__ Gbuf,
    float* __restrict__ Sbase, int Tc) {
  const int gid = blockIdx.x * 256 + threadIdx.x;   // BHn*4096
  const int bh = gid >> 12, e = gid & 4095;
  const int nsub = Tc >> 4;
  float S = Scarry[gid];
  for (int j = 0; j < nsub; ++j) {
    const size_t idx = ((size_t)bh * nsub + j) * 4096 + e;
    Sbase[idx] = S;
    S += Gbuf[idx];
  }
  Scarry[gid] = S;
}

// P3: per (subchunk, bh): S in registers (4x4 tile/thread), 16 sequential steps:
// S += eta*Sp ; o_t = S q_t via shfl_xor reduce over tx. Zero LDS/barriers.
__global__ __launch_bounds__(256) void outv2_kernel(
    const float* __restrict__ eta, const float* __restrict__ qb,
    const float* __restrict__ Sbase, const _Float16* __restrict__ Mbuf,
    float* __restrict__ ob, int t0, int Tc) {
  const int j = blockIdx.x, bh = blockIdx.y, tid = threadIdx.x;
  const int nsub = Tc >> 4;
  const int ty = tid >> 4, tx = tid & 15;
  const int dv0 = ty * 4, dk0 = tx * 4;
  float S[4][4];
  const float* sb = Sbase + ((size_t)bh * nsub + j) * 4096;
#pragma unroll
  for (int r = 0; r < 4; ++r) {
    const float4 v = *reinterpret_cast<const float4*>(sb + (dv0 + r) * 64 + dk0);
    S[r][0] = v.x; S[r][1] = v.y; S[r][2] = v.z; S[r][3] = v.w;
  }
#pragma unroll 1
  for (int i = 0; i < 16; ++i) {
    const int tl = j * 16 + i, t = t0 + tl;
    const float ev = eta[(size_t)bh * Tn + t];
    const float4 q4 = *reinterpret_cast<const float4*>(qb + ((size_t)bh * Tn + t) * 64 + dk0);
    const _Float16* sp = Mbuf + ((size_t)bh * Tc + tl) * 4096;
    float part[4];
#pragma unroll
    for (int r = 0; r < 4; ++r) {
      const f16x4 h = *reinterpret_cast<const f16x4*>(sp + (dv0 + r) * 64 + dk0);
      S[r][0] += ev * (float)h[0];
      S[r][1] += ev * (float)h[1];
      S[r][2] += ev * (float)h[2];
      S[r][3] += ev * (float)h[3];
      part[r] = S[r][0] * q4.x + S[r][1] * q4.y + S[r][2] * q4.z + S[r][3] * q4.w;
    }
#pragma unroll
    for (int m = 1; m < 16; m <<= 1)
#pragma unroll
      for (int r = 0; r < 4; ++r) part[r] += __shfl_xor(part[r], m, 64);
    if (tx == 0) {
      float4 o4 = {part[0], part[1], part[2], part[3]};
      *reinterpret_cast<float4*>(ob + ((size_t)bh * Tn + t) * 64 + dv0) = o4;
    }
  }
}

// init carries from S0 / M0 (broadcast over batch)
__global__ __launch_bounds__(256) void init_carry_kernel(
    const float* __restrict__ S0, const float* __restrict__ M0,
    float* __restrict__ Scarry, float* __restrict__ Mcarry) {
  const int gid = blockIdx.x * 256 + threadIdx.x;   // 131072
  const int h = (gid >> 12) & 7, e = gid & 4095;
  Scarry[gid] = S0[h * 4096 + e];
  Mcarry[gid] = M0[h * 4096 + e];
}

// final: out = o_flat @ Wo^T
__global__ __launch_bounds__(256) void out_gemm_kernel(
    const float* __restrict__ ob, const float* __restrict__ Wo,
    float* __restrict__ out) {
  __shared__ float As[64 * LDP];
  __shared__ float Bs[64 * LDP];
  const int tid = threadIdx.x;
  const int m0 = blockIdx.x * 64;
  const int n0 = blockIdx.y * 64;
  const int ty = tid >> 4, tx = tid & 15, i0 = ty * 4, j0 = tx * 4;
  float acc[4][4] = {};
  for (int kt = 0; kt < Dn; kt += 64) {
    const int h = kt >> 6;
#pragma unroll
    for (int i = 0; i < 4; ++i) {
      const int idx = tid + (i << 8);
      const int row = idx >> 4, c4 = (idx & 15) << 2;
      const int m = m0 + row, b = m >> 10, t = m & 1023;
      const float4 v = *reinterpret_cast<const float4*>(
          ob + ((size_t)(b * Hn + h) * Tn + t) * 64 + c4);
      float* p = As + row * LDP + c4;
      p[0] = v.x; p[1] = v.y; p[2] = v.z; p[3] = v.w;
    }
    stage_tile(Bs, Wo + (size_t)n0 * Dn + kt, Dn, tid);
    __syncthreads();
    mm_nt_acc(acc, As, Bs, i0, j0);
    __syncthreads();
  }
#pragma unroll
  for (int r = 0; r < 4; ++r)
#pragma unroll
    for (int c = 0; c < 4; ++c)
      out[(size_t)(m0 + i0 + r) * Dn + n0 + j0 + c] = acc[r][c];
}

// ---------- host ----------

extern "C" void kernel_launch(void* const* d_in, const int* in_sizes, int n_in,
                              void* d_out, int out_size, void* d_ws, size_t ws_size,
                              hipStream_t stream) {
  (void)in_sizes; (void)n_in; (void)out_size;
  const float* x  = (const float*)d_in[0];
  const float* Wq = (const float*)d_in[1];
  const float* Wk = (const float*)d_in[2];
  const float* Wv = (const float*)d_in[3];
  const float* Ww = (const float*)d_in[4];
  const float* Wp = (const float*)d_in[5];
  const float* Wo = (const float*)d_in[6];
  const float* S0 = (const float*)d_in[7];
  const float* M0 = (const float*)d_in[8];
  float* out = (float*)d_out;
  float* ws  = (float*)d_ws;

  size_t off = 0;
  float* qb  = ws + off; off += (size_t)BHn * Tn * 64;
  float* kb  = ws + off; off += (size_t)BHn * Tn * 64;
  float* vb  = ws + off; off += (size_t)BHn * Tn * 64;
  float* wb  = ws + off; off += (size_t)BHn * Tn * 64;
  float* Ub  = ws + off; off += (size_t)BHn * Tn * 64;
  float* ob  = ws + off; off += (size_t)BHn * Tn * 64;
  float* eta   = ws + off; off += (size_t)BHn * Tn;
  float* theta = ws + off; off += (size_t)BHn * Tn;
  float* rowm  = ws + off; off += (size_t)BHn * Tn;
  float* rowl  = ws + off; off += (size_t)BHn * Tn;
  float* Mcarry = ws + off; off += (size_t)BHn * 4096;
  float* Scarry = ws + off; off += (size_t)BHn * 4096;

  const size_t avail0 = ws_size / sizeof(float) - off;
  int Tc = 256;
  // need: Mbuf fp16 (BHn*Tc*2048 floats) + Gbuf + Sbase (2 * BHn*(Tc/16)*4096 floats)
  while (Tc > 16 && (size_t)BHn * Tc * 2048 + 2 * (size_t)BHn * (Tc / 16) * 4096 > avail0)
    Tc >>= 1;
  const int nsub = Tc >> 4;

  float* Gbuf  = ws + off; off += (size_t)BHn * nsub * 4096;
  float* Sbase = ws + off; off += (size_t)BHn * nsub * 4096;
  _Float16* Mbuf = (_Float16*)(ws + off);

  const int SOLVE_LDS = (4 * 64 * LDP + 128) * (int)sizeof(float);
  (void)hipFuncSetAttribute(reinterpret_cast<const void*>(solve_step_kernel),
                            hipFuncAttributeMaxDynamicSharedMemorySize, SOLVE_LDS);

  hipLaunchKernelGGL(init_carry_kernel, dim3(512), dim3(256), 0, stream, S0, M0, Scarry, Mcarry);
  hipLaunchKernelGGL(proj4_kernel, dim3(64, 8, 4), dim3(256), 0, stream,
                     x, Wq, Wk, Wv, Ww, qb, kb, vb, wb);
  hipLaunchKernelGGL(wp_kernel, dim3(256), dim3(256), 0, stream, x, Wp, eta, theta);
  hipLaunchKernelGGL(rowstats_kernel, dim3(16, 32), dim3(256), 0, stream, wb, kb, rowm, rowl);
  hipLaunchKernelGGL(copyU_kernel, dim3(2048), dim3(256), 0, stream, vb, Ub);
  hipLaunchKernelGGL(solve_diag0_kernel, dim3(32), dim3(256), 0, stream,
                     wb, kb, vb, rowm, rowl, Ub);
  for (int ib = 0; ib < 15; ++ib) {
    hipLaunchKernelGGL(solve_step_kernel, dim3(15 - ib, 32), dim3(256), SOLVE_LDS, stream,
                       wb, kb, rowm, rowl, Ub, ib);
  }

  for (int t0 = 0; t0 < Tn; t0 += Tc) {
    hipLaunchKernelGGL(mscan_kernel, dim3(256), dim3(256), 0, stream,
                       Ub, kb, theta, Mcarry, Mbuf, t0, Tc);
    hipLaunchKernelGGL(ns_kernel, dim3(BHn * Tc / 4), dim3(256), 0, stream, Mbuf);
    hipLaunchKernelGGL(gsum_kernel, dim3(nsub, BHn), dim3(256), 0, stream,
                       eta, Mbuf, Gbuf, t0, Tc);
    hipLaunchKernelGGL(sbase_kernel, dim3(512), dim3(256), 0, stream, Scarry, Gbuf, Sbase, Tc);
    hipLaunchKernelGGL(outv2_kernel, dim3(nsub, BHn), dim3(256), 0, stream,
                       eta, qb, Sbase, Mbuf, ob, t0, Tc);
  }

  hipLaunchKernelGGL(out_gemm_kernel, dim3(64, 8), dim3(256), 0, stream, ob, Wo, out);
}

// Round 5
// 1782.508 us; speedup vs baseline: 5.4960x; 1.0865x over previous
//
#include <hip/hip_runtime.h>
#include <hip/hip_bf16.h>
#include <math.h>

#define Bn 4
#define Tn 1024
#define Dn 512
#define Hn 8
#define BHn 32
#define LDP 65   // fp32 LDS stride (pad): 65 mod 32 = 1 -> <=2-way conflicts
#define LH 72    // fp16 LDS stride in halves: 144B rows, 8B-aligned frag slots

typedef _Float16 f16x8 __attribute__((ext_vector_type(8)));
typedef _Float16 f16x4 __attribute__((ext_vector_type(4)));
typedef _Float16 f16x2 __attribute__((ext_vector_type(2)));
typedef float    f32x4 __attribute__((ext_vector_type(4)));

// Newton-Schulz coefficients (6 iterations)
__constant__ float NS_Ac[6] = {3955.0f/1024.0f, 3735.0f/1024.0f, 3799.0f/1024.0f,
                               4019.0f/1024.0f, 2677.0f/1024.0f, 2172.0f/1024.0f};
__constant__ float NS_Bc[6] = {-8306.0f/1024.0f, -6681.0f/1024.0f, -6499.0f/1024.0f,
                               -6385.0f/1024.0f, -3029.0f/1024.0f, -1833.0f/1024.0f};
__constant__ float NS_Cc[6] = {5008.0f/1024.0f, 3463.0f/1024.0f, 3211.0f/1024.0f,
                               2906.0f/1024.0f, 1162.0f/1024.0f,  682.0f/1024.0f};

__device__ __forceinline__ f32x4 mfma16(f16x4 a, f16x4 b, f32x4 c) {
  return __builtin_amdgcn_mfma_f32_16x16x16f16(a, b, c, 0, 0, 0);
}

__device__ __forceinline__ f16x4 cvt4(f32x4 a) {
  f16x4 h;
  h[0] = (_Float16)a[0]; h[1] = (_Float16)a[1];
  h[2] = (_Float16)a[2]; h[3] = (_Float16)a[3];
  return h;
}

// ---------- fp32 helpers (solve path) ----------

__device__ __forceinline__ void stage_tile(float* __restrict__ dst, const float* __restrict__ src,
                                           int srcStride, int tid) {
#pragma unroll
  for (int i = 0; i < 4; ++i) {
    const int idx = tid + (i << 8);
    const int row = idx >> 4;
    const int c4  = (idx & 15) << 2;
    const float4 v = *reinterpret_cast<const float4*>(src + (size_t)row * srcStride + c4);
    float* p = dst + row * LDP + c4;
    p[0] = v.x; p[1] = v.y; p[2] = v.z; p[3] = v.w;
  }
}

// fp32 global tile -> fp16 LDS tile [64][LH]
__device__ __forceinline__ void stage_tile_h(_Float16* __restrict__ dst,
                                             const float* __restrict__ src,
                                             int srcStride, int tid) {
#pragma unroll
  for (int i = 0; i < 4; ++i) {
    const int idx = tid + (i << 8);
    const int row = idx >> 4;
    const int c4  = (idx & 15) << 2;
    const float4 v = *reinterpret_cast<const float4*>(src + (size_t)row * srcStride + c4);
    f16x4 h;
    h[0] = (_Float16)v.x; h[1] = (_Float16)v.y; h[2] = (_Float16)v.z; h[3] = (_Float16)v.w;
    *reinterpret_cast<f16x4*>(dst + row * LH + c4) = h;
  }
}

__device__ __forceinline__ void mm_nt_acc(float (&acc)[4][4], const float* __restrict__ a,
                                          const float* __restrict__ b, int i0, int j0) {
#pragma unroll 4
  for (int k = 0; k < 64; ++k) {
    float av[4], bv[4];
#pragma unroll
    for (int r = 0; r < 4; ++r) av[r] = a[(i0 + r) * LDP + k];
#pragma unroll
    for (int c = 0; c < 4; ++c) bv[c] = b[(j0 + c) * LDP + k];
#pragma unroll
    for (int r = 0; r < 4; ++r)
#pragma unroll
      for (int c = 0; c < 4; ++c) acc[r][c] = fmaf(av[r], bv[c], acc[r][c]);
  }
}

__device__ __forceinline__ void mm_nn_acc(float (&acc)[4][4], const float* __restrict__ a,
                                          const float* __restrict__ b, int i0, int j0) {
#pragma unroll 4
  for (int k = 0; k < 64; ++k) {
    float av[4], bv[4];
#pragma unroll
    for (int r = 0; r < 4; ++r) av[r] = a[(i0 + r) * LDP + k];
#pragma unroll
    for (int c = 0; c < 4; ++c) bv[c] = b[k * LDP + j0 + c];
#pragma unroll
    for (int r = 0; r < 4; ++r)
#pragma unroll
      for (int c = 0; c < 4; ++c) acc[r][c] = fmaf(av[r], bv[c], acc[r][c]);
  }
}

// unit-lower-triangular solve within a 64-block; Sc strict-lower, one wave, lane=dv column
__device__ __forceinline__ void tri_solve(const float* __restrict__ Sc,
                                          float* __restrict__ Uacc, int tid) {
  if (tid < 64) {
    const int dv = tid;
    for (int r2 = 1; r2 < 64; ++r2) {
      float s = 0.f;
      for (int c = 0; c < r2; ++c) s = fmaf(Sc[r2 * LDP + c], Uacc[c * LDP + dv], s);
      Uacc[r2 * LDP + dv] -= s;
    }
  }
}

// ---------- kernels ----------

// q/k/v/w projections via fp16 MFMA: (4096 x 512) @ W^T, written as (b,h,t,e)
__global__ __launch_bounds__(256) void proj4_kernel(
    const float* __restrict__ x,
    const float* __restrict__ W0, const float* __restrict__ W1,
    const float* __restrict__ W2, const float* __restrict__ W3,
    float* __restrict__ o0, float* __restrict__ o1,
    float* __restrict__ o2, float* __restrict__ o3) {
  __shared__ __align__(16) _Float16 Af[64 * LH];
  __shared__ __align__(16) _Float16 Bf[64 * LH];
  const float* W; float* outp;
  switch (blockIdx.z) {
    case 0:  W = W0; outp = o0; break;
    case 1:  W = W1; outp = o1; break;
    case 2:  W = W2; outp = o2; break;
    default: W = W3; outp = o3; break;
  }
  const int tid = threadIdx.x;
  const int m0 = blockIdx.x * 64;
  const int n0 = blockIdx.y * 64;
  const int wid = tid >> 6, lane = tid & 63;
  const int r = lane & 15, g = lane >> 4;
  f32x4 acc[4] = {};
  for (int kt = 0; kt < Dn; kt += 64) {
    stage_tile_h(Af, x + (size_t)m0 * Dn + kt, Dn, tid);
    stage_tile_h(Bf, W + (size_t)n0 * Dn + kt, Dn, tid);
    __syncthreads();
    f16x4 a4[4];
#pragma unroll
    for (int kc = 0; kc < 4; ++kc)
      a4[kc] = *reinterpret_cast<const f16x4*>(Af + (16 * wid + r) * LH + kc * 16 + 4 * g);
#pragma unroll
    for (int jb = 0; jb < 4; ++jb)
#pragma unroll
      for (int kc = 0; kc < 4; ++kc)
        acc[jb] = mfma16(a4[kc],
                         *reinterpret_cast<const f16x4*>(Bf + (16 * jb + r) * LH + kc * 16 + 4 * g),
                         acc[jb]);
    __syncthreads();
  }
#pragma unroll
  for (int jb = 0; jb < 4; ++jb)
#pragma unroll
    for (int d = 0; d < 4; ++d) {
      const int m = m0 + 16 * wid + 4 * g + d;
      const int n = n0 + 16 * jb + r;
      const int b = m >> 10, t = m & 1023, h = n >> 6, e = n & 63;
      outp[(((size_t)(b * Hn + h)) * Tn + t) * 64 + e] = acc[jb][d];
    }
}

// eta/theta projection: sigmoid(x @ Wp^T), Wp is (16,512)
#define XSTR 516
__global__ __launch_bounds__(256) void wp_kernel(const float* __restrict__ x,
                                                 const float* __restrict__ Wp,
                                                 float* __restrict__ eta,
                                                 float* __restrict__ theta) {
  __shared__ float xs[16 * XSTR];
  __shared__ float wps[16 * XSTR];
  const int tid = threadIdx.x;
  const int r0 = blockIdx.x * 16;
#pragma unroll
  for (int i = 0; i < 8; ++i) {
    const int idx = tid + (i << 8);
    const int r = idx >> 7, c4 = (idx & 127) << 2;
    const float4 v = *reinterpret_cast<const float4*>(x + (size_t)(r0 + r) * Dn + c4);
    float* p = xs + r * XSTR + c4;
    p[0] = v.x; p[1] = v.y; p[2] = v.z; p[3] = v.w;
    const float4 wv = *reinterpret_cast<const float4*>(Wp + (size_t)r * Dn + c4);
    float* pw = wps + r * XSTR + c4;
    pw[0] = wv.x; pw[1] = wv.y; pw[2] = wv.z; pw[3] = wv.w;
  }
  __syncthreads();
  const int row = tid >> 4, col = tid & 15;
  float acc = 0.f;
#pragma unroll 8
  for (int k = 0; k < Dn; ++k) acc = fmaf(xs[row * XSTR + k], wps[col * XSTR + k], acc);
  const float sg = 1.f / (1.f + __expf(-acc));
  const int m = r0 + row, b = m >> 10, t = m & 1023, h = col >> 1;
  float* dst = (col & 1) ? theta : eta;
  dst[((size_t)(b * Hn + h)) * Tn + t] = sg;
}

// Per-row softmax stats (max, sum of exp) over s < t, flash-style.
__global__ __launch_bounds__(256) void rowstats_kernel(
    const float* __restrict__ wb, const float* __restrict__ kb,
    float* __restrict__ rowm, float* __restrict__ rowl) {
  __shared__ float Wt[64 * LDP];
  __shared__ float Ks[64 * LDP];
  __shared__ float Sc[64 * LDP];
  __shared__ float rm[64];
  __shared__ float rl[64];
  const int tb = blockIdx.x, bh = blockIdx.y;
  const int t0 = tb * 64;
  const int tid = threadIdx.x;
  const int ty = tid >> 4, tx = tid & 15, i0 = ty * 4, j0 = tx * 4;
  stage_tile(Wt, wb + ((size_t)bh * Tn + t0) * 64, 64, tid);
  if (tid < 64) { rm[tid] = -INFINITY; rl[tid] = 0.f; }
  __syncthreads();
  for (int sb = 0; sb <= tb; ++sb) {
    stage_tile(Ks, kb + ((size_t)bh * Tn + sb * 64) * 64, 64, tid);
    __syncthreads();
    float acc[4][4] = {};
    mm_nt_acc(acc, Wt, Ks, i0, j0);
#pragma unroll
    for (int r = 0; r < 4; ++r)
#pragma unroll
      for (int c = 0; c < 4; ++c) {
        const int rr = i0 + r, cc = j0 + c;
        const bool valid = (sb < tb) || (cc < rr);
        Sc[rr * LDP + cc] = valid ? acc[r][c] * 0.125f : -INFINITY;
      }
    __syncthreads();
    if (tid < 64) {
      const int r = tid;
      float tm = -INFINITY;
      for (int c = 0; c < 64; ++c) tm = fmaxf(tm, Sc[r * LDP + c]);
      if (tm > -3.0e38f) {
        const float mnew = fmaxf(rm[r], tm);
        float s = 0.f;
        for (int c = 0; c < 64; ++c) s += __expf(Sc[r * LDP + c] - mnew);
        rl[r] = rl[r] * __expf(rm[r] - mnew) + s;
        rm[r] = mnew;
      }
    }
    __syncthreads();
  }
  if (tid < 64) {
    rowm[(size_t)bh * Tn + t0 + tid] = rm[tid];
    const float l = rl[tid];
    rowl[(size_t)bh * Tn + t0 + tid] = (l == 0.f) ? 1.f : l;
  }
}

// Ub := vb
__global__ __launch_bounds__(256) void copyU_kernel(const float* __restrict__ vb,
                                                    float* __restrict__ Ub) {
  const int gid = blockIdx.x * 256 + threadIdx.x;
  ((float4*)Ub)[gid] = ((const float4*)vb)[gid];
}

// diagonal solve of block 0 (rows 0..63), reads V directly
__global__ __launch_bounds__(256) void solve_diag0_kernel(
    const float* __restrict__ wb, const float* __restrict__ kb,
    const float* __restrict__ vb, const float* __restrict__ rowm,
    const float* __restrict__ rowl, float* __restrict__ Ub) {
  __shared__ float Wt[64 * LDP];
  __shared__ float Ks[64 * LDP];
  __shared__ float Uacc[64 * LDP];
  __shared__ float rm[64], rl[64];
  const int bh = blockIdx.x;
  const int tid = threadIdx.x;
  const int ty = tid >> 4, tx = tid & 15, i0 = ty * 4, j0 = tx * 4;
  stage_tile(Wt, wb + (size_t)bh * Tn * 64, 64, tid);
  stage_tile(Ks, kb + (size_t)bh * Tn * 64, 64, tid);
  stage_tile(Uacc, vb + (size_t)bh * Tn * 64, 64, tid);
  if (tid < 64) { rm[tid] = rowm[(size_t)bh * Tn + tid]; rl[tid] = rowl[(size_t)bh * Tn + tid]; }
  __syncthreads();
  float acc[4][4] = {};
  mm_nt_acc(acc, Wt, Ks, i0, j0);
  __syncthreads();
#pragma unroll
  for (int r = 0; r < 4; ++r)
#pragma unroll
    for (int c = 0; c < 4; ++c) {
      const int rr = i0 + r, cc = j0 + c;
      Ks[rr * LDP + cc] = (cc < rr) ? __expf(acc[r][c] * 0.125f - rm[rr]) / rl[rr] : 0.f;
    }
  __syncthreads();
  tri_solve(Ks, Uacc, tid);
  __syncthreads();
#pragma unroll
  for (int i = 0; i < 16; ++i) {
    const int idx = tid + (i << 8);
    const int row = idx >> 6, col = idx & 63;
    Ub[((size_t)bh * Tn + row) * 64 + col] = Uacc[row * LDP + col];
  }
}

// step ib: every future block f subtracts P[f,ib] @ U[ib]; block f==ib+1 also diag-solves
__global__ __launch_bounds__(256) void solve_step_kernel(
    const float* __restrict__ wb, const float* __restrict__ kb,
    const float* __restrict__ rowm, const float* __restrict__ rowl,
    float* __restrict__ Ub, int ib) {
  extern __shared__ float smem[];
  float* Wt   = smem;
  float* Ks   = Wt + 64 * LDP;
  float* Us   = Ks + 64 * LDP;
  float* Uacc = Us + 64 * LDP;
  float* rm   = Uacc + 64 * LDP;
  float* rl   = rm + 64;
  const int f  = ib + 1 + blockIdx.x;
  const int bh = blockIdx.y;
  const int tid = threadIdx.x;
  const int ty = tid >> 4, tx = tid & 15, i0 = ty * 4, j0 = tx * 4;
  stage_tile(Wt,   wb + ((size_t)bh * Tn + f  * 64) * 64, 64, tid);
  stage_tile(Ks,   kb + ((size_t)bh * Tn + ib * 64) * 64, 64, tid);
  stage_tile(Us,   Ub + ((size_t)bh * Tn + ib * 64) * 64, 64, tid);
  stage_tile(Uacc, Ub + ((size_t)bh * Tn + f  * 64) * 64, 64, tid);
  if (tid < 64) {
    rm[tid] = rowm[(size_t)bh * Tn + f * 64 + tid];
    rl[tid] = rowl[(size_t)bh * Tn + f * 64 + tid];
  }
  __syncthreads();
  float acc[4][4] = {};
  mm_nt_acc(acc, Wt, Ks, i0, j0);
  __syncthreads();                       // all reads of Ks done -> reuse as Sc
#pragma unroll
  for (int r = 0; r < 4; ++r)
#pragma unroll
    for (int c = 0; c < 4; ++c) {
      const int rr = i0 + r;
      Ks[rr * LDP + j0 + c] = __expf(acc[r][c] * 0.125f - rm[rr]) / rl[rr];
    }
  __syncthreads();
  float acc2[4][4] = {};
  mm_nn_acc(acc2, Ks, Us, i0, j0);
#pragma unroll
  for (int r = 0; r < 4; ++r)
#pragma unroll
    for (int c = 0; c < 4; ++c) Uacc[(i0 + r) * LDP + j0 + c] -= acc2[r][c];
  __syncthreads();
  if (f == ib + 1) {                     // block-uniform branch
    stage_tile(Us, kb + ((size_t)bh * Tn + f * 64) * 64, 64, tid);   // k rows of f
    __syncthreads();
    float acc3[4][4] = {};
    mm_nt_acc(acc3, Wt, Us, i0, j0);
    __syncthreads();
#pragma unroll
    for (int r = 0; r < 4; ++r)
#pragma unroll
      for (int c = 0; c < 4; ++c) {
        const int rr = i0 + r, cc = j0 + c;
        Ks[rr * LDP + cc] = (cc < rr) ? __expf(acc3[r][c] * 0.125f - rm[rr]) / rl[rr] : 0.f;
      }
    __syncthreads();
    tri_solve(Ks, Uacc, tid);
    __syncthreads();
  }
#pragma unroll
  for (int i = 0; i < 16; ++i) {
    const int idx = tid + (i << 8);
    const int row = idx >> 6, col = idx & 63;
    Ub[((size_t)bh * Tn + f * 64 + row) * 64 + col] = Uacc[row * LDP + col];
  }
}

// Momentum scan over a time chunk; 1 element/thread, writes fp16 M snapshots
__global__ __launch_bounds__(256) void mscan_kernel(
    const float* __restrict__ Ub, const float* __restrict__ kb,
    const float* __restrict__ theta, float* __restrict__ Mcarry,
    _Float16* __restrict__ Mbuf, int t0, int Tc) {
  const int gid = blockIdx.x * 256 + threadIdx.x;   // BHn*4096
  const int bh = gid >> 12, e = gid & 4095;
  const int dv = e >> 6, dk = e & 63;
  float M = Mcarry[gid];
  const float* Urow = Ub + (size_t)bh * Tn * 64;
  const float* krow = kb + (size_t)bh * Tn * 64;
  const float* th   = theta + (size_t)bh * Tn;
  for (int tl = 0; tl < Tc; ++tl) {
    const int t = t0 + tl;
    const float thv = th[t];
    const float g = Urow[(size_t)t * 64 + dv] * krow[(size_t)t * 64 + dk];
    M = thv * M + (1.f - thv) * g;
    Mbuf[((size_t)bh * Tc + tl) * 4096 + e] = (_Float16)M;
  }
  Mcarry[gid] = M;
}

// Newton-Schulz (6 iters), ONE WAVE per 64x64 matrix, register-resident.
// In-place frag transpose (Xf dead after m1) keeps peak regs ~145 -> 3 blocks/CU.
__global__ __launch_bounds__(256, 3) void ns_kernel(_Float16* __restrict__ Mbuf) {
  __shared__ __align__(16) _Float16 Ms[4][64 * LH];
  const int tid  = threadIdx.x;
  const int wid  = tid >> 6, lane = tid & 63;
  const int r    = lane & 15, g = lane >> 4;
  _Float16* src = Mbuf + ((size_t)blockIdx.x * 4 + wid) * 4096;
  _Float16* lds = Ms[wid];
  const int lrow = (lane >> 3), lcol = (lane & 7) * 8;

  // ---- load (coalesced), Frobenius norm accum, stage UNscaled to LDS ----
  float ss = 0.f;
#pragma unroll
  for (int c = 0; c < 8; ++c) {
    const f16x8 h = *reinterpret_cast<const f16x8*>(src + c * 512 + lane * 8);
#pragma unroll
    for (int j = 0; j < 8; ++j) { const float f = (float)h[j]; ss += f * f; }
    *reinterpret_cast<f16x8*>(lds + (c * 8 + lrow) * LH + lcol) = h;
  }
#pragma unroll
  for (int off = 32; off > 0; off >>= 1) ss += __shfl_xor(ss, off, 64);
  const float inv = 1.f / (sqrtf(ss) + 1e-7f);

  // ---- X row-frags (scale in fp32 during load) ----
  f16x4 Xf[4][4];   // [tile-row i][k-chunk kc]; later holds X^T frags in place
#pragma unroll
  for (int i = 0; i < 4; ++i)
#pragma unroll
    for (int kc = 0; kc < 4; ++kc) {
      f16x4 h = *reinterpret_cast<const f16x4*>(lds + (i * 16 + r) * LH + kc * 16 + 4 * g);
#pragma unroll
      for (int d = 0; d < 4; ++d) h[d] = (_Float16)((float)h[d] * inv);
      Xf[i][kc] = h;
    }

  // identity frag: elem d = (r == 4g+d)
  const int dd = r - 4 * g;
  f16x4 If;
  If[0] = (dd == 0) ? (_Float16)1.f : (_Float16)0.f;
  If[1] = (dd == 1) ? (_Float16)1.f : (_Float16)0.f;
  If[2] = (dd == 2) ? (_Float16)1.f : (_Float16)0.f;
  If[3] = (dd == 3) ? (_Float16)1.f : (_Float16)0.f;
  float Iw[4];
  Iw[0] = (float)If[0]; Iw[1] = (float)If[1]; Iw[2] = (float)If[2]; Iw[3] = (float)If[3];

  f16x4 Ff[4][4];    // A frags, then Bm' frags
  f32x4 acc[4][4];

#pragma unroll 1
  for (int it = 0; it < 6; ++it) {
    const float ca = NS_Ac[it], cb = NS_Bc[it], cc = NS_Cc[it];
    // m1: acc = X X^T (= A, symmetric)
#pragma unroll
    for (int i = 0; i < 4; ++i)
#pragma unroll
      for (int j = 0; j < 4; ++j) {
        f32x4 a = {0.f, 0.f, 0.f, 0.f};
#pragma unroll
        for (int kc = 0; kc < 4; ++kc) a = mfma16(Xf[i][kc], Xf[j][kc], a);
        acc[i][j] = a;
      }
    // A frags (A symmetric: acc[i][j] in C-layout == rowfrags of tile (j,i))
#pragma unroll
    for (int i = 0; i < 4; ++i)
#pragma unroll
      for (int j = 0; j < 4; ++j) Ff[j][i] = cvt4(acc[i][j]);
    // in-place transpose: Xf := X^T frags (Xf dead after m1)
#pragma unroll
    for (int i = 0; i < 4; ++i) {
      {
        const f32x4 t = mfma16(Xf[i][i], If, (f32x4){0.f, 0.f, 0.f, 0.f});
        Xf[i][i] = cvt4(t);
      }
#pragma unroll
      for (int j = i + 1; j < 4; ++j) {
        const f32x4 t1 = mfma16(Xf[i][j], If, (f32x4){0.f, 0.f, 0.f, 0.f});
        const f32x4 t2 = mfma16(Xf[j][i], If, (f32x4){0.f, 0.f, 0.f, 0.f});
        Xf[j][i] = cvt4(t1);
        Xf[i][j] = cvt4(t2);
      }
    }
    // m2: acc = cc*(A A^T + (cb/cc) A) = cb A + cc A^2 ; += ca I on diagonal
    const float bc = cb / cc;
#pragma unroll
    for (int i = 0; i < 4; ++i)
#pragma unroll
      for (int j = 0; j < 4; ++j) {
        f32x4 a = acc[i][j];
        a[0] *= bc; a[1] *= bc; a[2] *= bc; a[3] *= bc;
#pragma unroll
        for (int kc = 0; kc < 4; ++kc) a = mfma16(Ff[i][kc], Ff[j][kc], a);
        a[0] *= cc; a[1] *= cc; a[2] *= cc; a[3] *= cc;
        acc[i][j] = a;
      }
#pragma unroll
    for (int i = 0; i < 4; ++i) {
#pragma unroll
      for (int d = 0; d < 4; ++d) acc[i][i][d] = fmaf(ca, Iw[d], acc[i][i][d]);
    }
    // Bm' frags (symmetric)
#pragma unroll
    for (int i = 0; i < 4; ++i)
#pragma unroll
      for (int j = 0; j < 4; ++j) Ff[j][i] = cvt4(acc[i][j]);
    // m3: acc = NT(XT, Bm') = X^T Bm' ; C-layout == rowfrags of Bm' X = X'
#pragma unroll
    for (int i = 0; i < 4; ++i)
#pragma unroll
      for (int j = 0; j < 4; ++j) {
        f32x4 a = {0.f, 0.f, 0.f, 0.f};
#pragma unroll
        for (int kc = 0; kc < 4; ++kc) a = mfma16(Xf[i][kc], Ff[j][kc], a);
        acc[i][j] = a;
      }
#pragma unroll
    for (int i = 0; i < 4; ++i)
#pragma unroll
      for (int j = 0; j < 4; ++j) Xf[j][i] = cvt4(acc[i][j]);
  }

  // ---- store result (frags -> LDS rows -> coalesced global) ----
#pragma unroll
  for (int i = 0; i < 4; ++i)
#pragma unroll
    for (int kc = 0; kc < 4; ++kc)
      *reinterpret_cast<f16x4*>(lds + (i * 16 + r) * LH + kc * 16 + 4 * g) = Xf[i][kc];
#pragma unroll
  for (int c = 0; c < 8; ++c) {
    const f16x8 h = *reinterpret_cast<const f16x8*>(lds + (c * 8 + lrow) * LH + lcol);
    *reinterpret_cast<f16x8*>(src + c * 512 + lane * 8) = h;
  }
}

// P1: G_j = sum over 16-step subchunk of eta_s * Sp_s (fp32 regs, coalesced streams)
__global__ __launch_bounds__(256) void gsum_kernel(
    const float* __restrict__ eta, const _Float16* __restrict__ Mbuf,
    float* __restrict__ Gbuf, int t0, int Tc) {
  const int j = blockIdx.x, bh = blockIdx.y, tid = threadIdx.x;
  const int nsub = Tc >> 4;
  float acc[16] = {};
#pragma unroll 1
  for (int i = 0; i < 16; ++i) {
    const int tl = j * 16 + i;
    const float ev = eta[(size_t)bh * Tn + t0 + tl];
    const _Float16* sp = Mbuf + ((size_t)bh * Tc + tl) * 4096;
    const f16x8 h0 = *reinterpret_cast<const f16x8*>(sp + tid * 8);
    const f16x8 h1 = *reinterpret_cast<const f16x8*>(sp + 2048 + tid * 8);
#pragma unroll
    for (int u = 0; u < 8; ++u) {
      acc[u]     += ev * (float)h0[u];
      acc[8 + u] += ev * (float)h1[u];
    }
  }
  float* g = Gbuf + ((size_t)bh * nsub + j) * 4096;
#pragma unroll
  for (int u = 0; u < 2; ++u) {
    float4 w0 = {acc[u*4], acc[u*4+1], acc[u*4+2], acc[u*4+3]};
    *reinterpret_cast<float4*>(g + tid * 8 + u * 4) = w0;
    float4 w1 = {acc[8+u*4], acc[8+u*4+1], acc[8+u*4+2], acc[8+u*4+3]};
    *reinterpret_cast<float4*>(g + 2048 + tid * 8 + u * 4) = w1;
  }
}

// P2: scan G over subchunks -> Sbase_j (S at subchunk start); updates Scarry
__global__ __launch_bounds__(256) void sbase_kernel(
    float* __restrict__ Scarry, const float* __restrict__ Gbuf,
    float* __restrict__ Sbase, int Tc) {
  const int gid = blockIdx.x * 256 + threadIdx.x;   // BHn*4096
  const int bh = gid >> 12, e = gid & 4095;
  const int nsub = Tc >> 4;
  float S = Scarry[gid];
  for (int j = 0; j < nsub; ++j) {
    const size_t idx = ((size_t)bh * nsub + j) * 4096 + e;
    Sbase[idx] = S;
    S += Gbuf[idx];
  }
  Scarry[gid] = S;
}

// P3: per (subchunk, bh): S in registers (4x4 tile/thread), 16 sequential steps:
// S += eta*Sp ; o_t = S q_t via shfl_xor reduce over tx. Zero LDS/barriers.
__global__ __launch_bounds__(256) void outv2_kernel(
    const float* __restrict__ eta, const float* __restrict__ qb,
    const float* __restrict__ Sbase, const _Float16* __restrict__ Mbuf,
    float* __restrict__ ob, int t0, int Tc) {
  const int j = blockIdx.x, bh = blockIdx.y, tid = threadIdx.x;
  const int nsub = Tc >> 4;
  const int ty = tid >> 4, tx = tid & 15;
  const int dv0 = ty * 4, dk0 = tx * 4;
  float S[4][4];
  const float* sb = Sbase + ((size_t)bh * nsub + j) * 4096;
#pragma unroll
  for (int r = 0; r < 4; ++r) {
    const float4 v = *reinterpret_cast<const float4*>(sb + (dv0 + r) * 64 + dk0);
    S[r][0] = v.x; S[r][1] = v.y; S[r][2] = v.z; S[r][3] = v.w;
  }
#pragma unroll 1
  for (int i = 0; i < 16; ++i) {
    const int tl = j * 16 + i, t = t0 + tl;
    const float ev = eta[(size_t)bh * Tn + t];
    const float4 q4 = *reinterpret_cast<const float4*>(qb + ((size_t)bh * Tn + t) * 64 + dk0);
    const _Float16* sp = Mbuf + ((size_t)bh * Tc + tl) * 4096;
    float part[4];
#pragma unroll
    for (int r = 0; r < 4; ++r) {
      const f16x4 h = *reinterpret_cast<const f16x4*>(sp + (dv0 + r) * 64 + dk0);
      S[r][0] += ev * (float)h[0];
      S[r][1] += ev * (float)h[1];
      S[r][2] += ev * (float)h[2];
      S[r][3] += ev * (float)h[3];
      part[r] = S[r][0] * q4.x + S[r][1] * q4.y + S[r][2] * q4.z + S[r][3] * q4.w;
    }
#pragma unroll
    for (int m = 1; m < 16; m <<= 1)
#pragma unroll
      for (int r = 0; r < 4; ++r) part[r] += __shfl_xor(part[r], m, 64);
    if (tx == 0) {
      float4 o4 = {part[0], part[1], part[2], part[3]};
      *reinterpret_cast<float4*>(ob + ((size_t)bh * Tn + t) * 64 + dv0) = o4;
    }
  }
}

// init carries from S0 / M0 (broadcast over batch)
__global__ __launch_bounds__(256) void init_carry_kernel(
    const float* __restrict__ S0, const float* __restrict__ M0,
    float* __restrict__ Scarry, float* __restrict__ Mcarry) {
  const int gid = blockIdx.x * 256 + threadIdx.x;   // 131072
  const int h = (gid >> 12) & 7, e = gid & 4095;
  Scarry[gid] = S0[h * 4096 + e];
  Mcarry[gid] = M0[h * 4096 + e];
}

// final: out = o_flat @ Wo^T via fp16 MFMA
__global__ __launch_bounds__(256) void out_gemm_kernel(
    const float* __restrict__ ob, const float* __restrict__ Wo,
    float* __restrict__ out) {
  __shared__ __align__(16) _Float16 Af[64 * LH];
  __shared__ __align__(16) _Float16 Bf[64 * LH];
  const int tid = threadIdx.x;
  const int m0 = blockIdx.x * 64;
  const int n0 = blockIdx.y * 64;
  const int wid = tid >> 6, lane = tid & 63;
  const int r = lane & 15, g = lane >> 4;
  f32x4 acc[4] = {};
  for (int kt = 0; kt < Dn; kt += 64) {
    const int h = kt >> 6;
#pragma unroll
    for (int i = 0; i < 4; ++i) {
      const int idx = tid + (i << 8);
      const int row = idx >> 4, c4 = (idx & 15) << 2;
      const int m = m0 + row, b = m >> 10, t = m & 1023;
      const float4 v = *reinterpret_cast<const float4*>(
          ob + ((size_t)(b * Hn + h) * Tn + t) * 64 + c4);
      f16x4 hv;
      hv[0] = (_Float16)v.x; hv[1] = (_Float16)v.y; hv[2] = (_Float16)v.z; hv[3] = (_Float16)v.w;
      *reinterpret_cast<f16x4*>(Af + row * LH + c4) = hv;
    }
    stage_tile_h(Bf, Wo + (size_t)n0 * Dn + kt, Dn, tid);
    __syncthreads();
    f16x4 a4[4];
#pragma unroll
    for (int kc = 0; kc < 4; ++kc)
      a4[kc] = *reinterpret_cast<const f16x4*>(Af + (16 * wid + r) * LH + kc * 16 + 4 * g);
#pragma unroll
    for (int jb = 0; jb < 4; ++jb)
#pragma unroll
      for (int kc = 0; kc < 4; ++kc)
        acc[jb] = mfma16(a4[kc],
                         *reinterpret_cast<const f16x4*>(Bf + (16 * jb + r) * LH + kc * 16 + 4 * g),
                         acc[jb]);
    __syncthreads();
  }
#pragma unroll
  for (int jb = 0; jb < 4; ++jb)
#pragma unroll
    for (int d = 0; d < 4; ++d) {
      const int m = m0 + 16 * wid + 4 * g + d;
      const int n = n0 + 16 * jb + r;
      out[(size_t)m * Dn + n] = acc[jb][d];
    }
}

// ---------- host ----------

extern "C" void kernel_launch(void* const* d_in, const int* in_sizes, int n_in,
                              void* d_out, int out_size, void* d_ws, size_t ws_size,
                              hipStream_t stream) {
  (void)in_sizes; (void)n_in; (void)out_size;
  const float* x  = (const float*)d_in[0];
  const float* Wq = (const float*)d_in[1];
  const float* Wk = (const float*)d_in[2];
  const float* Wv = (const float*)d_in[3];
  const float* Ww = (const float*)d_in[4];
  const float* Wp = (const float*)d_in[5];
  const float* Wo = (const float*)d_in[6];
  const float* S0 = (const float*)d_in[7];
  const float* M0 = (const float*)d_in[8];
  float* out = (float*)d_out;
  float* ws  = (float*)d_ws;

  size_t off = 0;
  float* qb  = ws + off; off += (size_t)BHn * Tn * 64;
  float* kb  = ws + off; off += (size_t)BHn * Tn * 64;
  float* vb  = ws + off; off += (size_t)BHn * Tn * 64;
  float* wb  = ws + off; off += (size_t)BHn * Tn * 64;
  float* Ub  = ws + off; off += (size_t)BHn * Tn * 64;
  float* ob  = ws + off; off += (size_t)BHn * Tn * 64;
  float* eta   = ws + off; off += (size_t)BHn * Tn;
  float* theta = ws + off; off += (size_t)BHn * Tn;
  float* rowm  = ws + off; off += (size_t)BHn * Tn;
  float* rowl  = ws + off; off += (size_t)BHn * Tn;
  float* Mcarry = ws + off; off += (size_t)BHn * 4096;
  float* Scarry = ws + off; off += (size_t)BHn * 4096;

  const size_t avail0 = ws_size / sizeof(float) - off;
  int Tc = 256;
  // need: Mbuf fp16 (BHn*Tc*2048 floats) + Gbuf + Sbase (2 * BHn*(Tc/16)*4096 floats)
  while (Tc > 16 && (size_t)BHn * Tc * 2048 + 2 * (size_t)BHn * (Tc / 16) * 4096 > avail0)
    Tc >>= 1;
  const int nsub = Tc >> 4;

  float* Gbuf  = ws + off; off += (size_t)BHn * nsub * 4096;
  float* Sbase = ws + off; off += (size_t)BHn * nsub * 4096;
  _Float16* Mbuf = (_Float16*)(ws + off);

  const int SOLVE_LDS = (4 * 64 * LDP + 128) * (int)sizeof(float);
  (void)hipFuncSetAttribute(reinterpret_cast<const void*>(solve_step_kernel),
                            hipFuncAttributeMaxDynamicSharedMemorySize, SOLVE_LDS);

  hipLaunchKernelGGL(init_carry_kernel, dim3(512), dim3(256), 0, stream, S0, M0, Scarry, Mcarry);
  hipLaunchKernelGGL(proj4_kernel, dim3(64, 8, 4), dim3(256), 0, stream,
                     x, Wq, Wk, Wv, Ww, qb, kb, vb, wb);
  hipLaunchKernelGGL(wp_kernel, dim3(256), dim3(256), 0, stream, x, Wp, eta, theta);
  hipLaunchKernelGGL(rowstats_kernel, dim3(16, 32), dim3(256), 0, stream, wb, kb, rowm, rowl);
  hipLaunchKernelGGL(copyU_kernel, dim3(2048), dim3(256), 0, stream, vb, Ub);
  hipLaunchKernelGGL(solve_diag0_kernel, dim3(32), dim3(256), 0, stream,
                     wb, kb, vb, rowm, rowl, Ub);
  for (int ib = 0; ib < 15; ++ib) {
    hipLaunchKernelGGL(solve_step_kernel, dim3(15 - ib, 32), dim3(256), SOLVE_LDS, stream,
                       wb, kb, rowm, rowl, Ub, ib);
  }

  for (int t0 = 0; t0 < Tn; t0 += Tc) {
    hipLaunchKernelGGL(mscan_kernel, dim3(512), dim3(256), 0, stream,
                       Ub, kb, theta, Mcarry, Mbuf, t0, Tc);
    hipLaunchKernelGGL(ns_kernel, dim3(BHn * Tc / 4), dim3(256), 0, stream, Mbuf);
    hipLaunchKernelGGL(gsum_kernel, dim3(nsub, BHn), dim3(256), 0, stream,
                       eta, Mbuf, Gbuf, t0, Tc);
    hipLaunchKernelGGL(sbase_kernel, dim3(512), dim3(256), 0, stream, Scarry, Gbuf, Sbase, Tc);
    hipLaunchKernelGGL(outv2_kernel, dim3(nsub, BHn), dim3(256), 0, stream,
                       eta, qb, Sbase, Mbuf, ob, t0, Tc);
  }

  hipLaunchKernelGGL(out_gemm_kernel, dim3(64, 8), dim3(256), 0, stream, ob, Wo, out);
}

// Round 6
// 1530.364 us; speedup vs baseline: 6.4015x; 1.1648x over previous
//
#include <hip/hip_runtime.h>
#include <hip/hip_bf16.h>
#include <math.h>

#define Bn 4
#define Tn 1024
#define Dn 512
#define Hn 8
#define BHn 32
#define LDP 65   // fp32 LDS stride (pad)
#define LDU 68   // fp32 LDS stride for Ua (16B-aligned rows)
#define LH 72    // fp16 LDS stride in halves: 144B rows, 8B-aligned frag slots

typedef _Float16 f16x8 __attribute__((ext_vector_type(8)));
typedef _Float16 f16x4 __attribute__((ext_vector_type(4)));
typedef _Float16 f16x2 __attribute__((ext_vector_type(2)));
typedef float    f32x4 __attribute__((ext_vector_type(4)));

// Newton-Schulz coefficients (6 iterations)
__constant__ float NS_Ac[6] = {3955.0f/1024.0f, 3735.0f/1024.0f, 3799.0f/1024.0f,
                               4019.0f/1024.0f, 2677.0f/1024.0f, 2172.0f/1024.0f};
__constant__ float NS_Bc[6] = {-8306.0f/1024.0f, -6681.0f/1024.0f, -6499.0f/1024.0f,
                               -6385.0f/1024.0f, -3029.0f/1024.0f, -1833.0f/1024.0f};
__constant__ float NS_Cc[6] = {5008.0f/1024.0f, 3463.0f/1024.0f, 3211.0f/1024.0f,
                               2906.0f/1024.0f, 1162.0f/1024.0f,  682.0f/1024.0f};

__device__ __forceinline__ f32x4 mfma16(f16x4 a, f16x4 b, f32x4 c) {
  return __builtin_amdgcn_mfma_f32_16x16x16f16(a, b, c, 0, 0, 0);
}

__device__ __forceinline__ f16x4 cvt4(f32x4 a) {
  f16x4 h;
  h[0] = (_Float16)a[0]; h[1] = (_Float16)a[1];
  h[2] = (_Float16)a[2]; h[3] = (_Float16)a[3];
  return h;
}

__device__ __forceinline__ f16x4 make_If(int r, int g) {
  const int dd = r - 4 * g;
  f16x4 If;
  If[0] = (dd == 0) ? (_Float16)1.f : (_Float16)0.f;
  If[1] = (dd == 1) ? (_Float16)1.f : (_Float16)0.f;
  If[2] = (dd == 2) ? (_Float16)1.f : (_Float16)0.f;
  If[3] = (dd == 3) ? (_Float16)1.f : (_Float16)0.f;
  return If;
}

// ---------- staging helpers ----------

// fp32 global tile -> fp16 LDS tile [64][LH]
__device__ __forceinline__ void stage_tile_h(_Float16* __restrict__ dst,
                                             const float* __restrict__ src,
                                             int srcStride, int tid) {
#pragma unroll
  for (int i = 0; i < 4; ++i) {
    const int idx = tid + (i << 8);
    const int row = idx >> 4;
    const int c4  = (idx & 15) << 2;
    const float4 v = *reinterpret_cast<const float4*>(src + (size_t)row * srcStride + c4);
    f16x4 h;
    h[0] = (_Float16)v.x; h[1] = (_Float16)v.y; h[2] = (_Float16)v.z; h[3] = (_Float16)v.w;
    *reinterpret_cast<f16x4*>(dst + row * LH + c4) = h;
  }
}

// fp32 global tile -> fp32 LDS tile stride LDU
__device__ __forceinline__ void stage_tile_u(float* __restrict__ dst,
                                             const float* __restrict__ src, int tid) {
#pragma unroll
  for (int i = 0; i < 4; ++i) {
    const int idx = tid + (i << 8);
    const int row = idx >> 4;
    const int c4  = (idx & 15) << 2;
    *reinterpret_cast<float4*>(dst + row * LDU + c4) =
        *reinterpret_cast<const float4*>(src + (size_t)row * 64 + c4);
  }
}

// unit-lower-triangular solve; Sc strict-lower fp32 [64][LDP], Ua [64][LDU]
__device__ __forceinline__ void tri_solve(const float* __restrict__ Sc,
                                          float* __restrict__ Ua, int tid) {
  if (tid < 64) {
    const int dv = tid;
    for (int r2 = 1; r2 < 64; ++r2) {
      float s = 0.f;
      for (int c = 0; c < r2; ++c) s = fmaf(Sc[r2 * LDP + c], Ua[c * LDU + dv], s);
      Ua[r2 * LDU + dv] -= s;
    }
  }
}

// ---------- kernels ----------

// q/k/v/w projections via fp16 MFMA: (4096 x 512) @ W^T, written as (b,h,t,e)
__global__ __launch_bounds__(256) void proj4_kernel(
    const float* __restrict__ x,
    const float* __restrict__ W0, const float* __restrict__ W1,
    const float* __restrict__ W2, const float* __restrict__ W3,
    float* __restrict__ o0, float* __restrict__ o1,
    float* __restrict__ o2, float* __restrict__ o3) {
  __shared__ __align__(16) _Float16 Af[64 * LH];
  __shared__ __align__(16) _Float16 Bf[64 * LH];
  const float* W; float* outp;
  switch (blockIdx.z) {
    case 0:  W = W0; outp = o0; break;
    case 1:  W = W1; outp = o1; break;
    case 2:  W = W2; outp = o2; break;
    default: W = W3; outp = o3; break;
  }
  const int tid = threadIdx.x;
  const int m0 = blockIdx.x * 64;
  const int n0 = blockIdx.y * 64;
  const int wid = tid >> 6, lane = tid & 63;
  const int r = lane & 15, g = lane >> 4;
  f32x4 acc[4] = {};
  for (int kt = 0; kt < Dn; kt += 64) {
    stage_tile_h(Af, x + (size_t)m0 * Dn + kt, Dn, tid);
    stage_tile_h(Bf, W + (size_t)n0 * Dn + kt, Dn, tid);
    __syncthreads();
    f16x4 a4[4];
#pragma unroll
    for (int kc = 0; kc < 4; ++kc)
      a4[kc] = *reinterpret_cast<const f16x4*>(Af + (16 * wid + r) * LH + kc * 16 + 4 * g);
#pragma unroll
    for (int jb = 0; jb < 4; ++jb)
#pragma unroll
      for (int kc = 0; kc < 4; ++kc)
        acc[jb] = mfma16(a4[kc],
                         *reinterpret_cast<const f16x4*>(Bf + (16 * jb + r) * LH + kc * 16 + 4 * g),
                         acc[jb]);
    __syncthreads();
  }
#pragma unroll
  for (int jb = 0; jb < 4; ++jb)
#pragma unroll
    for (int d = 0; d < 4; ++d) {
      const int m = m0 + 16 * wid + 4 * g + d;
      const int n = n0 + 16 * jb + r;
      const int b = m >> 10, t = m & 1023, h = n >> 6, e = n & 63;
      outp[(((size_t)(b * Hn + h)) * Tn + t) * 64 + e] = acc[jb][d];
    }
}

// eta/theta projection: sigmoid(x @ Wp^T), Wp is (16,512)
#define XSTR 516
__global__ __launch_bounds__(256) void wp_kernel(const float* __restrict__ x,
                                                 const float* __restrict__ Wp,
                                                 float* __restrict__ eta,
                                                 float* __restrict__ theta) {
  __shared__ float xs[16 * XSTR];
  __shared__ float wps[16 * XSTR];
  const int tid = threadIdx.x;
  const int r0 = blockIdx.x * 16;
#pragma unroll
  for (int i = 0; i < 8; ++i) {
    const int idx = tid + (i << 8);
    const int r = idx >> 7, c4 = (idx & 127) << 2;
    const float4 v = *reinterpret_cast<const float4*>(x + (size_t)(r0 + r) * Dn + c4);
    float* p = xs + r * XSTR + c4;
    p[0] = v.x; p[1] = v.y; p[2] = v.z; p[3] = v.w;
    const float4 wv = *reinterpret_cast<const float4*>(Wp + (size_t)r * Dn + c4);
    float* pw = wps + r * XSTR + c4;
    pw[0] = wv.x; pw[1] = wv.y; pw[2] = wv.z; pw[3] = wv.w;
  }
  __syncthreads();
  const int row = tid >> 4, col = tid & 15;
  float acc = 0.f;
#pragma unroll 8
  for (int k = 0; k < Dn; ++k) acc = fmaf(xs[row * XSTR + k], wps[col * XSTR + k], acc);
  const float sg = 1.f / (1.f + __expf(-acc));
  const int m = r0 + row, b = m >> 10, t = m & 1023, h = col >> 1;
  float* dst = (col & 1) ? theta : eta;
  dst[((size_t)(b * Hn + h)) * Tn + t] = sg;
}

// Per-row softmax stats via fp16 MFMA + wave-parallel flash update.
__global__ __launch_bounds__(256) void rowstats_kernel(
    const float* __restrict__ wb, const float* __restrict__ kb,
    float* __restrict__ rowm, float* __restrict__ rowl) {
  __shared__ __align__(16) _Float16 Wh[64 * LH];
  __shared__ __align__(16) _Float16 Kh[64 * LH];
  const int tb = blockIdx.x, bh = blockIdx.y, t0 = tb * 64;
  const int tid = threadIdx.x, wid = tid >> 6, lane = tid & 63;
  const int r = lane & 15, g = lane >> 4;
  stage_tile_h(Wh, wb + ((size_t)bh * Tn + t0) * 64, 64, tid);
  float rm[4], rl[4];
#pragma unroll
  for (int d = 0; d < 4; ++d) { rm[d] = -INFINITY; rl[d] = 0.f; }
  __syncthreads();
  f16x4 wfr[4];
#pragma unroll
  for (int kc = 0; kc < 4; ++kc)
    wfr[kc] = *reinterpret_cast<const f16x4*>(Wh + (16 * wid + r) * LH + kc * 16 + 4 * g);
  for (int sb = 0; sb <= tb; ++sb) {
    __syncthreads();                    // prior Kh reads complete
    stage_tile_h(Kh, kb + ((size_t)bh * Tn + sb * 64) * 64, 64, tid);
    __syncthreads();
    float sv[4][4];
    float tmax[4] = {-INFINITY, -INFINITY, -INFINITY, -INFINITY};
#pragma unroll
    for (int jb = 0; jb < 4; ++jb) {
      f32x4 acc = {0.f, 0.f, 0.f, 0.f};
#pragma unroll
      for (int kc = 0; kc < 4; ++kc)
        acc = mfma16(wfr[kc],
                     *reinterpret_cast<const f16x4*>(Kh + (16 * jb + r) * LH + kc * 16 + 4 * g),
                     acc);
      const int col = sb * 64 + 16 * jb + r;
#pragma unroll
      for (int d = 0; d < 4; ++d) {
        const int row = t0 + 16 * wid + 4 * g + d;
        const float s = (col < row) ? acc[d] * 0.125f : -INFINITY;
        sv[jb][d] = s;
        tmax[d] = fmaxf(tmax[d], s);
      }
    }
#pragma unroll
    for (int m = 1; m < 16; m <<= 1)
#pragma unroll
      for (int d = 0; d < 4; ++d) tmax[d] = fmaxf(tmax[d], __shfl_xor(tmax[d], m, 64));
#pragma unroll
    for (int d = 0; d < 4; ++d) {
      const float mnew  = fmaxf(rm[d], tmax[d]);
      const float msafe = (mnew == -INFINITY) ? 0.f : mnew;
      float s = __expf(sv[0][d] - msafe) + __expf(sv[1][d] - msafe) +
                __expf(sv[2][d] - msafe) + __expf(sv[3][d] - msafe);
#pragma unroll
      for (int m = 1; m < 16; m <<= 1) s += __shfl_xor(s, m, 64);
      const float scale = (rm[d] == -INFINITY) ? 0.f : __expf(rm[d] - msafe);
      rl[d] = rl[d] * scale + s;
      rm[d] = mnew;
    }
  }
  if (r == 0) {
#pragma unroll
    for (int d = 0; d < 4; ++d) {
      const int row = t0 + 16 * wid + 4 * g + d;
      rowm[(size_t)bh * Tn + row] = rm[d];
      rowl[(size_t)bh * Tn + row] = (rl[d] == 0.f) ? 1.f : rl[d];
    }
  }
}

// Ub := vb
__global__ __launch_bounds__(256) void copyU_kernel(const float* __restrict__ vb,
                                                    float* __restrict__ Ub) {
  const int gid = blockIdx.x * 256 + threadIdx.x;
  ((float4*)Ub)[gid] = ((const float4*)vb)[gid];
}

// diagonal solve of block 0: scores via MFMA, fp32 tri_solve
__global__ __launch_bounds__(256) void solve_diag0_kernel(
    const float* __restrict__ wb, const float* __restrict__ kb,
    const float* __restrict__ vb, const float* __restrict__ rowm,
    const float* __restrict__ rowl, float* __restrict__ Ub) {
  __shared__ __align__(16) _Float16 Wh[64 * LH];
  __shared__ __align__(16) _Float16 Kh[64 * LH];
  __shared__ float Sc[64 * LDP];
  __shared__ __align__(16) float Ua[64 * LDU];
  __shared__ float rmL[64], rlL[64];
  const int bh = blockIdx.x;
  const int tid = threadIdx.x, wid = tid >> 6, lane = tid & 63;
  const int r = lane & 15, g = lane >> 4;
  stage_tile_h(Wh, wb + (size_t)bh * Tn * 64, 64, tid);
  stage_tile_h(Kh, kb + (size_t)bh * Tn * 64, 64, tid);
  stage_tile_u(Ua, vb + (size_t)bh * Tn * 64, tid);
  if (tid < 64) { rmL[tid] = rowm[(size_t)bh * Tn + tid]; rlL[tid] = rowl[(size_t)bh * Tn + tid]; }
  __syncthreads();
  f16x4 wfr[4];
#pragma unroll
  for (int kc = 0; kc < 4; ++kc)
    wfr[kc] = *reinterpret_cast<const f16x4*>(Wh + (16 * wid + r) * LH + kc * 16 + 4 * g);
  float rmv[4], rlv[4];
#pragma unroll
  for (int d = 0; d < 4; ++d) {
    rmv[d] = rmL[16 * wid + 4 * g + d];
    rlv[d] = rlL[16 * wid + 4 * g + d];
  }
#pragma unroll
  for (int jb = 0; jb < 4; ++jb) {
    f32x4 acc = {0.f, 0.f, 0.f, 0.f};
#pragma unroll
    for (int kc = 0; kc < 4; ++kc)
      acc = mfma16(wfr[kc],
                   *reinterpret_cast<const f16x4*>(Kh + (16 * jb + r) * LH + kc * 16 + 4 * g),
                   acc);
#pragma unroll
    for (int d = 0; d < 4; ++d) {
      const int lr = 16 * wid + 4 * g + d, lc = 16 * jb + r;
      Sc[lr * LDP + lc] = (lc < lr) ? __expf(acc[d] * 0.125f - rmv[d]) / rlv[d] : 0.f;
    }
  }
  __syncthreads();
  tri_solve(Sc, Ua, tid);
  __syncthreads();
#pragma unroll
  for (int i = 0; i < 4; ++i) {
    const int idx = tid + (i << 8);
    const int row = idx >> 4, c4 = (idx & 15) << 2;
    *reinterpret_cast<float4*>(Ub + ((size_t)bh * Tn + row) * 64 + c4) =
        *reinterpret_cast<const float4*>(Ua + row * LDU + c4);
  }
}

// step ib (MFMA): block f computes U[f] -= P[f,ib] @ U[ib] via
// U^T[f] -= U^T[ib] (-P)^T with P built in-register; f==ib+1 also diag-solves.
__global__ __launch_bounds__(256) void solve_step_kernel(
    const float* __restrict__ wb, const float* __restrict__ kb,
    const float* __restrict__ rowm, const float* __restrict__ rowl,
    float* __restrict__ Ub, int ib) {
  __shared__ __align__(16) _Float16 Wh[64 * LH];
  __shared__ __align__(16) _Float16 Kh[64 * LH];
  __shared__ __align__(16) _Float16 UTh[64 * LH];
  __shared__ float Sc[64 * LDP];
  __shared__ __align__(16) float Ua[64 * LDU];
  __shared__ float rmL[64], rlL[64];
  const int f = ib + 1 + blockIdx.x, bh = blockIdx.y;
  const int tid = threadIdx.x, wid = tid >> 6, lane = tid & 63;
  const int r = lane & 15, g = lane >> 4;
  stage_tile_h(Wh, wb + ((size_t)bh * Tn + f * 64) * 64, 64, tid);
  stage_tile_h(Kh, kb + ((size_t)bh * Tn + ib * 64) * 64, 64, tid);
  {  // U[ib] -> transposed fp16 LDS [dv][t]
    const float* src = Ub + ((size_t)bh * Tn + ib * 64) * 64;
#pragma unroll
    for (int i2 = 0; i2 < 4; ++i2) {
      const int idx = tid + (i2 << 8);
      const int row = idx >> 4, c4 = (idx & 15) << 2;
      const float4 v = *reinterpret_cast<const float4*>(src + (size_t)row * 64 + c4);
      UTh[(c4 + 0) * LH + row] = (_Float16)v.x;
      UTh[(c4 + 1) * LH + row] = (_Float16)v.y;
      UTh[(c4 + 2) * LH + row] = (_Float16)v.z;
      UTh[(c4 + 3) * LH + row] = (_Float16)v.w;
    }
  }
  if (tid < 64) {
    rmL[tid] = rowm[(size_t)bh * Tn + f * 64 + tid];
    rlL[tid] = rowl[(size_t)bh * Tn + f * 64 + tid];
  }
  __syncthreads();
  f16x4 wfr[4];
#pragma unroll
  for (int kc = 0; kc < 4; ++kc)
    wfr[kc] = *reinterpret_cast<const f16x4*>(Wh + (16 * wid + r) * LH + kc * 16 + 4 * g);
  float rmv[4], rlv[4];
#pragma unroll
  for (int d = 0; d < 4; ++d) {
    rmv[d] = rmL[16 * wid + 4 * g + d];
    rlv[d] = rlL[16 * wid + 4 * g + d];
  }
  const f16x4 If = make_If(r, g);
  // P tiles: scores -> -P (acc layout = (-P)^T frags) -> transpose to (-P) row-frags
  f16x4 Pfr[4];
#pragma unroll
  for (int jb = 0; jb < 4; ++jb) {
    f32x4 acc = {0.f, 0.f, 0.f, 0.f};
#pragma unroll
    for (int kc = 0; kc < 4; ++kc)
      acc = mfma16(wfr[kc],
                   *reinterpret_cast<const f16x4*>(Kh + (16 * jb + r) * LH + kc * 16 + 4 * g),
                   acc);
    f16x4 pf;
#pragma unroll
    for (int d = 0; d < 4; ++d)
      pf[d] = (_Float16)(-__expf(acc[d] * 0.125f - rmv[d]) / rlv[d]);
    Pfr[jb] = cvt4(mfma16(pf, If, (f32x4){0.f, 0.f, 0.f, 0.f}));
  }
  // acc2[i] = U^T[f] tile (i,wid) + sum_kc U^T[ib]fr[i][kc] * (-P)fr[wid-row][kc]
  const float* uf = Ub + ((size_t)bh * Tn + f * 64) * 64;
  f32x4 acc2[4];
#pragma unroll
  for (int i = 0; i < 4; ++i) {
    const float4 v = *reinterpret_cast<const float4*>(uf + (size_t)(16 * wid + r) * 64 + 16 * i + 4 * g);
    acc2[i][0] = v.x; acc2[i][1] = v.y; acc2[i][2] = v.z; acc2[i][3] = v.w;
#pragma unroll
    for (int kc = 0; kc < 4; ++kc)
      acc2[i] = mfma16(*reinterpret_cast<const f16x4*>(UTh + (16 * i + r) * LH + kc * 16 + 4 * g),
                       Pfr[kc], acc2[i]);
  }
  if (f == ib + 1) {                     // block-uniform branch
    __syncthreads();                     // Kh/UTh reads complete
    stage_tile_h(Kh, kb + ((size_t)bh * Tn + f * 64) * 64, 64, tid);
    // acc2 -> Ua (fp32): lane holds Unew[16wid+r][16i+4g+d]
#pragma unroll
    for (int i = 0; i < 4; ++i) {
      float4 v = {acc2[i][0], acc2[i][1], acc2[i][2], acc2[i][3]};
      *reinterpret_cast<float4*>(Ua + (16 * wid + r) * LDU + 16 * i + 4 * g) = v;
    }
    __syncthreads();
    // self scores -> Sc (masked, normalized)
#pragma unroll
    for (int jb = 0; jb < 4; ++jb) {
      f32x4 acc = {0.f, 0.f, 0.f, 0.f};
#pragma unroll
      for (int kc = 0; kc < 4; ++kc)
        acc = mfma16(wfr[kc],
                     *reinterpret_cast<const f16x4*>(Kh + (16 * jb + r) * LH + kc * 16 + 4 * g),
                     acc);
#pragma unroll
      for (int d = 0; d < 4; ++d) {
        const int lr = 16 * wid + 4 * g + d, lc = 16 * jb + r;
        Sc[lr * LDP + lc] = (lc < lr) ? __expf(acc[d] * 0.125f - rmv[d]) / rlv[d] : 0.f;
      }
    }
    __syncthreads();
    tri_solve(Sc, Ua, tid);
    __syncthreads();
#pragma unroll
    for (int i2 = 0; i2 < 4; ++i2) {
      const int idx = tid + (i2 << 8);
      const int row = idx >> 4, c4 = (idx & 15) << 2;
      *reinterpret_cast<float4*>(Ub + ((size_t)bh * Tn + f * 64 + row) * 64 + c4) =
          *reinterpret_cast<const float4*>(Ua + row * LDU + c4);
    }
  } else {
#pragma unroll
    for (int i = 0; i < 4; ++i) {
      float4 v = {acc2[i][0], acc2[i][1], acc2[i][2], acc2[i][3]};
      *reinterpret_cast<float4*>(Ub + ((size_t)bh * Tn + f * 64 + 16 * wid + r) * 64 + 16 * i + 4 * g) = v;
    }
  }
}

// Momentum scan over a time chunk; 1 element/thread, writes fp16 M snapshots
__global__ __launch_bounds__(256) void mscan_kernel(
    const float* __restrict__ Ub, const float* __restrict__ kb,
    const float* __restrict__ theta, float* __restrict__ Mcarry,
    _Float16* __restrict__ Mbuf, int t0, int Tc) {
  const int gid = blockIdx.x * 256 + threadIdx.x;   // BHn*4096
  const int bh = gid >> 12, e = gid & 4095;
  const int dv = e >> 6, dk = e & 63;
  float M = Mcarry[gid];
  const float* Urow = Ub + (size_t)bh * Tn * 64;
  const float* krow = kb + (size_t)bh * Tn * 64;
  const float* th   = theta + (size_t)bh * Tn;
  for (int tl = 0; tl < Tc; ++tl) {
    const int t = t0 + tl;
    const float thv = th[t];
    const float g = Urow[(size_t)t * 64 + dv] * krow[(size_t)t * 64 + dk];
    M = thv * M + (1.f - thv) * g;
    Mbuf[((size_t)bh * Tc + tl) * 4096 + e] = (_Float16)M;
  }
  Mcarry[gid] = M;
}

// Newton-Schulz (6 iters), ONE WAVE per 64x64 matrix, register-resident.
__global__ __launch_bounds__(256, 3) void ns_kernel(_Float16* __restrict__ Mbuf) {
  __shared__ __align__(16) _Float16 Ms[4][64 * LH];
  const int tid  = threadIdx.x;
  const int wid  = tid >> 6, lane = tid & 63;
  const int r    = lane & 15, g = lane >> 4;
  _Float16* src = Mbuf + ((size_t)blockIdx.x * 4 + wid) * 4096;
  _Float16* lds = Ms[wid];
  const int lrow = (lane >> 3), lcol = (lane & 7) * 8;

  float ss = 0.f;
#pragma unroll
  for (int c = 0; c < 8; ++c) {
    const f16x8 h = *reinterpret_cast<const f16x8*>(src + c * 512 + lane * 8);
#pragma unroll
    for (int j = 0; j < 8; ++j) { const float f = (float)h[j]; ss += f * f; }
    *reinterpret_cast<f16x8*>(lds + (c * 8 + lrow) * LH + lcol) = h;
  }
#pragma unroll
  for (int off = 32; off > 0; off >>= 1) ss += __shfl_xor(ss, off, 64);
  const float inv = 1.f / (sqrtf(ss) + 1e-7f);

  f16x4 Xf[4][4];
#pragma unroll
  for (int i = 0; i < 4; ++i)
#pragma unroll
    for (int kc = 0; kc < 4; ++kc) {
      f16x4 h = *reinterpret_cast<const f16x4*>(lds + (i * 16 + r) * LH + kc * 16 + 4 * g);
#pragma unroll
      for (int d = 0; d < 4; ++d) h[d] = (_Float16)((float)h[d] * inv);
      Xf[i][kc] = h;
    }

  const f16x4 If = make_If(r, g);
  float Iw[4];
  Iw[0] = (float)If[0]; Iw[1] = (float)If[1]; Iw[2] = (float)If[2]; Iw[3] = (float)If[3];

  f16x4 Ff[4][4];
  f32x4 acc[4][4];

#pragma unroll 1
  for (int it = 0; it < 6; ++it) {
    const float ca = NS_Ac[it], cb = NS_Bc[it], cc = NS_Cc[it];
#pragma unroll
    for (int i = 0; i < 4; ++i)
#pragma unroll
      for (int j = 0; j < 4; ++j) {
        f32x4 a = {0.f, 0.f, 0.f, 0.f};
#pragma unroll
        for (int kc = 0; kc < 4; ++kc) a = mfma16(Xf[i][kc], Xf[j][kc], a);
        acc[i][j] = a;
      }
#pragma unroll
    for (int i = 0; i < 4; ++i)
#pragma unroll
      for (int j = 0; j < 4; ++j) Ff[j][i] = cvt4(acc[i][j]);
#pragma unroll
    for (int i = 0; i < 4; ++i) {
      {
        const f32x4 t = mfma16(Xf[i][i], If, (f32x4){0.f, 0.f, 0.f, 0.f});
        Xf[i][i] = cvt4(t);
      }
#pragma unroll
      for (int j = i + 1; j < 4; ++j) {
        const f32x4 t1 = mfma16(Xf[i][j], If, (f32x4){0.f, 0.f, 0.f, 0.f});
        const f32x4 t2 = mfma16(Xf[j][i], If, (f32x4){0.f, 0.f, 0.f, 0.f});
        Xf[j][i] = cvt4(t1);
        Xf[i][j] = cvt4(t2);
      }
    }
    const float bc = cb / cc;
#pragma unroll
    for (int i = 0; i < 4; ++i)
#pragma unroll
      for (int j = 0; j < 4; ++j) {
        f32x4 a = acc[i][j];
        a[0] *= bc; a[1] *= bc; a[2] *= bc; a[3] *= bc;
#pragma unroll
        for (int kc = 0; kc < 4; ++kc) a = mfma16(Ff[i][kc], Ff[j][kc], a);
        a[0] *= cc; a[1] *= cc; a[2] *= cc; a[3] *= cc;
        acc[i][j] = a;
      }
#pragma unroll
    for (int i = 0; i < 4; ++i) {
#pragma unroll
      for (int d = 0; d < 4; ++d) acc[i][i][d] = fmaf(ca, Iw[d], acc[i][i][d]);
    }
#pragma unroll
    for (int i = 0; i < 4; ++i)
#pragma unroll
      for (int j = 0; j < 4; ++j) Ff[j][i] = cvt4(acc[i][j]);
#pragma unroll
    for (int i = 0; i < 4; ++i)
#pragma unroll
      for (int j = 0; j < 4; ++j) {
        f32x4 a = {0.f, 0.f, 0.f, 0.f};
#pragma unroll
        for (int kc = 0; kc < 4; ++kc) a = mfma16(Xf[i][kc], Ff[j][kc], a);
        acc[i][j] = a;
      }
#pragma unroll
    for (int i = 0; i < 4; ++i)
#pragma unroll
      for (int j = 0; j < 4; ++j) Xf[j][i] = cvt4(acc[i][j]);
  }

#pragma unroll
  for (int i = 0; i < 4; ++i)
#pragma unroll
    for (int kc = 0; kc < 4; ++kc)
      *reinterpret_cast<f16x4*>(lds + (i * 16 + r) * LH + kc * 16 + 4 * g) = Xf[i][kc];
#pragma unroll
  for (int c = 0; c < 8; ++c) {
    const f16x8 h = *reinterpret_cast<const f16x8*>(lds + (c * 8 + lrow) * LH + lcol);
    *reinterpret_cast<f16x8*>(src + c * 512 + lane * 8) = h;
  }
}

// P1: G_j = sum over 16-step subchunk of eta_s * Sp_s
__global__ __launch_bounds__(256) void gsum_kernel(
    const float* __restrict__ eta, const _Float16* __restrict__ Mbuf,
    float* __restrict__ Gbuf, int t0, int Tc) {
  const int j = blockIdx.x, bh = blockIdx.y, tid = threadIdx.x;
  const int nsub = Tc >> 4;
  float acc[16] = {};
#pragma unroll 1
  for (int i = 0; i < 16; ++i) {
    const int tl = j * 16 + i;
    const float ev = eta[(size_t)bh * Tn + t0 + tl];
    const _Float16* sp = Mbuf + ((size_t)bh * Tc + tl) * 4096;
    const f16x8 h0 = *reinterpret_cast<const f16x8*>(sp + tid * 8);
    const f16x8 h1 = *reinterpret_cast<const f16x8*>(sp + 2048 + tid * 8);
#pragma unroll
    for (int u = 0; u < 8; ++u) {
      acc[u]     += ev * (float)h0[u];
      acc[8 + u] += ev * (float)h1[u];
    }
  }
  float* g = Gbuf + ((size_t)bh * nsub + j) * 4096;
#pragma unroll
  for (int u = 0; u < 2; ++u) {
    float4 w0 = {acc[u*4], acc[u*4+1], acc[u*4+2], acc[u*4+3]};
    *reinterpret_cast<float4*>(g + tid * 8 + u * 4) = w0;
    float4 w1 = {acc[8+u*4], acc[8+u*4+1], acc[8+u*4+2], acc[8+u*4+3]};
    *reinterpret_cast<float4*>(g + 2048 + tid * 8 + u * 4) = w1;
  }
}

// P2: scan G over subchunks -> Sbase_j; updates Scarry
__global__ __launch_bounds__(256) void sbase_kernel(
    float* __restrict__ Scarry, const float* __restrict__ Gbuf,
    float* __restrict__ Sbase, int Tc) {
  const int gid = blockIdx.x * 256 + threadIdx.x;   // BHn*4096
  const int bh = gid >> 12, e = gid & 4095;
  const int nsub = Tc >> 4;
  float S = Scarry[gid];
  for (int j = 0; j < nsub; ++j) {
    const size_t idx = ((size_t)bh * nsub + j) * 4096 + e;
    Sbase[idx] = S;
    S += Gbuf[idx];
  }
  Scarry[gid] = S;
}

// P3: S in registers, 16 steps, shfl_xor reduce. Zero LDS/barriers.
__global__ __launch_bounds__(256) void outv2_kernel(
    const float* __restrict__ eta, const float* __restrict__ qb,
    const float* __restrict__ Sbase, const _Float16* __restrict__ Mbuf,
    float* __restrict__ ob, int t0, int Tc) {
  const int j = blockIdx.x, bh = blockIdx.y, tid = threadIdx.x;
  const int nsub = Tc >> 4;
  const int ty = tid >> 4, tx = tid & 15;
  const int dv0 = ty * 4, dk0 = tx * 4;
  float S[4][4];
  const float* sb = Sbase + ((size_t)bh * nsub + j) * 4096;
#pragma unroll
  for (int r = 0; r < 4; ++r) {
    const float4 v = *reinterpret_cast<const float4*>(sb + (dv0 + r) * 64 + dk0);
    S[r][0] = v.x; S[r][1] = v.y; S[r][2] = v.z; S[r][3] = v.w;
  }
#pragma unroll 1
  for (int i = 0; i < 16; ++i) {
    const int tl = j * 16 + i, t = t0 + tl;
    const float ev = eta[(size_t)bh * Tn + t];
    const float4 q4 = *reinterpret_cast<const float4*>(qb + ((size_t)bh * Tn + t) * 64 + dk0);
    const _Float16* sp = Mbuf + ((size_t)bh * Tc + tl) * 4096;
    float part[4];
#pragma unroll
    for (int r = 0; r < 4; ++r) {
      const f16x4 h = *reinterpret_cast<const f16x4*>(sp + (dv0 + r) * 64 + dk0);
      S[r][0] += ev * (float)h[0];
      S[r][1] += ev * (float)h[1];
      S[r][2] += ev * (float)h[2];
      S[r][3] += ev * (float)h[3];
      part[r] = S[r][0] * q4.x + S[r][1] * q4.y + S[r][2] * q4.z + S[r][3] * q4.w;
    }
#pragma unroll
    for (int m = 1; m < 16; m <<= 1)
#pragma unroll
      for (int r = 0; r < 4; ++r) part[r] += __shfl_xor(part[r], m, 64);
    if (tx == 0) {
      float4 o4 = {part[0], part[1], part[2], part[3]};
      *reinterpret_cast<float4*>(ob + ((size_t)bh * Tn + t) * 64 + dv0) = o4;
    }
  }
}

// init carries from S0 / M0 (broadcast over batch)
__global__ __launch_bounds__(256) void init_carry_kernel(
    const float* __restrict__ S0, const float* __restrict__ M0,
    float* __restrict__ Scarry, float* __restrict__ Mcarry) {
  const int gid = blockIdx.x * 256 + threadIdx.x;   // 131072
  const int h = (gid >> 12) & 7, e = gid & 4095;
  Scarry[gid] = S0[h * 4096 + e];
  Mcarry[gid] = M0[h * 4096 + e];
}

// final: out = o_flat @ Wo^T via fp16 MFMA
__global__ __launch_bounds__(256) void out_gemm_kernel(
    const float* __restrict__ ob, const float* __restrict__ Wo,
    float* __restrict__ out) {
  __shared__ __align__(16) _Float16 Af[64 * LH];
  __shared__ __align__(16) _Float16 Bf[64 * LH];
  const int tid = threadIdx.x;
  const int m0 = blockIdx.x * 64;
  const int n0 = blockIdx.y * 64;
  const int wid = tid >> 6, lane = tid & 63;
  const int r = lane & 15, g = lane >> 4;
  f32x4 acc[4] = {};
  for (int kt = 0; kt < Dn; kt += 64) {
    const int h = kt >> 6;
#pragma unroll
    for (int i = 0; i < 4; ++i) {
      const int idx = tid + (i << 8);
      const int row = idx >> 4, c4 = (idx & 15) << 2;
      const int m = m0 + row, b = m >> 10, t = m & 1023;
      const float4 v = *reinterpret_cast<const float4*>(
          ob + ((size_t)(b * Hn + h) * Tn + t) * 64 + c4);
      f16x4 hv;
      hv[0] = (_Float16)v.x; hv[1] = (_Float16)v.y; hv[2] = (_Float16)v.z; hv[3] = (_Float16)v.w;
      *reinterpret_cast<f16x4*>(Af + row * LH + c4) = hv;
    }
    stage_tile_h(Bf, Wo + (size_t)n0 * Dn + kt, Dn, tid);
    __syncthreads();
    f16x4 a4[4];
#pragma unroll
    for (int kc = 0; kc < 4; ++kc)
      a4[kc] = *reinterpret_cast<const f16x4*>(Af + (16 * wid + r) * LH + kc * 16 + 4 * g);
#pragma unroll
    for (int jb = 0; jb < 4; ++jb)
#pragma unroll
      for (int kc = 0; kc < 4; ++kc)
        acc[jb] = mfma16(a4[kc],
                         *reinterpret_cast<const f16x4*>(Bf + (16 * jb + r) * LH + kc * 16 + 4 * g),
                         acc[jb]);
    __syncthreads();
  }
#pragma unroll
  for (int jb = 0; jb < 4; ++jb)
#pragma unroll
    for (int d = 0; d < 4; ++d) {
      const int m = m0 + 16 * wid + 4 * g + d;
      const int n = n0 + 16 * jb + r;
      out[(size_t)m * Dn + n] = acc[jb][d];
    }
}

// ---------- host ----------

extern "C" void kernel_launch(void* const* d_in, const int* in_sizes, int n_in,
                              void* d_out, int out_size, void* d_ws, size_t ws_size,
                              hipStream_t stream) {
  (void)in_sizes; (void)n_in; (void)out_size;
  const float* x  = (const float*)d_in[0];
  const float* Wq = (const float*)d_in[1];
  const float* Wk = (const float*)d_in[2];
  const float* Wv = (const float*)d_in[3];
  const float* Ww = (const float*)d_in[4];
  const float* Wp = (const float*)d_in[5];
  const float* Wo = (const float*)d_in[6];
  const float* S0 = (const float*)d_in[7];
  const float* M0 = (const float*)d_in[8];
  float* out = (float*)d_out;
  float* ws  = (float*)d_ws;

  size_t off = 0;
  float* qb  = ws + off; off += (size_t)BHn * Tn * 64;
  float* kb  = ws + off; off += (size_t)BHn * Tn * 64;
  float* vb  = ws + off; off += (size_t)BHn * Tn * 64;
  float* wb  = ws + off; off += (size_t)BHn * Tn * 64;
  float* Ub  = ws + off; off += (size_t)BHn * Tn * 64;
  float* ob  = ws + off; off += (size_t)BHn * Tn * 64;
  float* eta   = ws + off; off += (size_t)BHn * Tn;
  float* theta = ws + off; off += (size_t)BHn * Tn;
  float* rowm  = ws + off; off += (size_t)BHn * Tn;
  float* rowl  = ws + off; off += (size_t)BHn * Tn;
  float* Mcarry = ws + off; off += (size_t)BHn * 4096;
  float* Scarry = ws + off; off += (size_t)BHn * 4096;

  const size_t avail0 = ws_size / sizeof(float) - off;
  int Tc = 256;
  while (Tc > 16 && (size_t)BHn * Tc * 2048 + 2 * (size_t)BHn * (Tc / 16) * 4096 > avail0)
    Tc >>= 1;
  const int nsub = Tc >> 4;

  float* Gbuf  = ws + off; off += (size_t)BHn * nsub * 4096;
  float* Sbase = ws + off; off += (size_t)BHn * nsub * 4096;
  _Float16* Mbuf = (_Float16*)(ws + off);

  hipLaunchKernelGGL(init_carry_kernel, dim3(512), dim3(256), 0, stream, S0, M0, Scarry, Mcarry);
  hipLaunchKernelGGL(proj4_kernel, dim3(64, 8, 4), dim3(256), 0, stream,
                     x, Wq, Wk, Wv, Ww, qb, kb, vb, wb);
  hipLaunchKernelGGL(wp_kernel, dim3(256), dim3(256), 0, stream, x, Wp, eta, theta);
  hipLaunchKernelGGL(rowstats_kernel, dim3(16, 32), dim3(256), 0, stream, wb, kb, rowm, rowl);
  hipLaunchKernelGGL(copyU_kernel, dim3(2048), dim3(256), 0, stream, vb, Ub);
  hipLaunchKernelGGL(solve_diag0_kernel, dim3(32), dim3(256), 0, stream,
                     wb, kb, vb, rowm, rowl, Ub);
  for (int ib = 0; ib < 15; ++ib) {
    hipLaunchKernelGGL(solve_step_kernel, dim3(15 - ib, 32), dim3(256), 0, stream,
                       wb, kb, rowm, rowl, Ub, ib);
  }

  for (int t0 = 0; t0 < Tn; t0 += Tc) {
    hipLaunchKernelGGL(mscan_kernel, dim3(512), dim3(256), 0, stream,
                       Ub, kb, theta, Mcarry, Mbuf, t0, Tc);
    hipLaunchKernelGGL(ns_kernel, dim3(BHn * Tc / 4), dim3(256), 0, stream, Mbuf);
    hipLaunchKernelGGL(gsum_kernel, dim3(nsub, BHn), dim3(256), 0, stream,
                       eta, Mbuf, Gbuf, t0, Tc);
    hipLaunchKernelGGL(sbase_kernel, dim3(512), dim3(256), 0, stream, Scarry, Gbuf, Sbase, Tc);
    hipLaunchKernelGGL(outv2_kernel, dim3(nsub, BHn), dim3(256), 0, stream,
                       eta, qb, Sbase, Mbuf, ob, t0, Tc);
  }

  hipLaunchKernelGGL(out_gemm_kernel, dim3(64, 8), dim3(256), 0, stream, ob, Wo, out);
}